// Round 3
// baseline (3915.456 us; speedup 1.0000x reference)
//
#include <hip/hip_runtime.h>
#include <hip/hip_bf16.h>
#include <math.h>

#define DEV __device__ __forceinline__

DEV float wsum64(float v){
  #pragma unroll
  for (int off = 32; off; off >>= 1) v += __shfl_xor(v, off, 64);
  return v;
}
DEV float geluf(float x){
  return 0.5f*x*(1.f + tanhf(0.7978845608028654f*(x + 0.044715f*x*x*x)));
}
DEV float gelu_bwdf(float x){
  float x2 = x*x;
  float t = tanhf(0.79788456f*x*(1.f + 0.044715f*x2));
  return 0.5f*x*((1.f - t*t)*(0.79788456f + 0.1070322243f*x2)) + 0.5f*(1.f + t);
}
DEV float sigmf(float x){ return 1.f/(1.f + expf(-x)); }

// ---------------------------------------------------------------------------
// Stem s11: x[512,3,96,96] -> conv7x7 s2 p3 -> BN -> ReLU -> pool2 -> xs[512,8,24,24]
__global__ __launch_bounds__(192) void k_s11(const float* __restrict__ x,
    const float* __restrict__ w, const float* __restrict__ bias,
    const float* __restrict__ bn, float* __restrict__ xs){
  __shared__ float st[3*37*2*53];   // 11766 floats
  __shared__ float wl[49*3*8];      // 1176
  int bx = blockIdx.x;
  int bd = bx / 3, g = bx - bd*3;
  int t = threadIdx.x;
  for (int e = t; e < 1176; e += 192){
    int tap = e / 24, r = e - tap*24, ci = r >> 3, c = r & 7;
    wl[e] = w[(c*3 + ci)*49 + tap];
  }
  const float* xb = x + (size_t)bd*3*9216;
  for (int e = t; e < 3*37*102; e += 192){
    int ci = e / 3774, r2 = e - ci*3774;
    int ihl = r2 / 102, pi = r2 - ihl*102;
    int ih = ihl + 32*g - 3, iw = pi - 3;
    float v = 0.f;
    if (ih>=0 && ih<96 && iw>=0 && iw<96) v = xb[(size_t)ci*9216 + ih*96 + iw];
    st[((ci*37 + ihl)*2 + (pi&1))*53 + (pi>>1)] = v;
  }
  __syncthreads();
  int pr = t / 24, pc = t - pr*24;
  float a00[8], a01[8], a10[8], a11[8];
  #pragma unroll
  for (int c=0;c<8;c++){ a00[c]=0.f; a01[c]=0.f; a10[c]=0.f; a11[c]=0.f; }
  for (int ci=0; ci<3; ci++){
    for (int kh=0; kh<7; kh++){
      int rb0 = (ci*37 + 4*pr + kh)*106 + 2*pc;
      int rb1 = rb0 + 212;
      #pragma unroll
      for (int kw=0; kw<7; kw++){
        int off = (kw&1)*53 + (kw>>1);
        float v00 = st[rb0+off], v01 = st[rb0+off+1];
        float v10 = st[rb1+off], v11 = st[rb1+off+1];
        const float4* wp = (const float4*)&wl[((kh*7+kw)*3 + ci)*8];
        float wv[8];
        *(float4*)&wv[0] = wp[0]; *(float4*)&wv[4] = wp[1];
        #pragma unroll
        for (int c=0;c<8;c++){
          a00[c] += v00*wv[c]; a01[c] += v01*wv[c];
          a10[c] += v10*wv[c]; a11[c] += v11*wv[c];
        }
      }
    }
  }
  int pos = (g*8 + pr)*24 + pc;
  #pragma unroll
  for (int c=0;c<8;c++){
    float gg=bn[c], be=bn[8+c], m=bn[16+c], vv=bn[24+c];
    float s = gg*rsqrtf(vv + 1e-5f);
    float bi = bias[c];
    float mx = 0.f;
    mx = fmaxf(mx, (a00[c]+bi-m)*s+be);
    mx = fmaxf(mx, (a01[c]+bi-m)*s+be);
    mx = fmaxf(mx, (a10[c]+bi-m)*s+be);
    mx = fmaxf(mx, (a11[c]+bi-m)*s+be);
    xs[((size_t)bd*8 + c)*576 + pos] = mx;
  }
}

// Stem s12: same structure on frame-diffs (4 groups of 3 channels, diff at staging).
__global__ __launch_bounds__(192) void k_s12(const float* __restrict__ x,
    const float* __restrict__ w, const float* __restrict__ bias,
    const float* __restrict__ bn, float* __restrict__ xd){
  __shared__ float st[3*37*2*53];
  __shared__ float wl[49*12*8];     // 4704
  int bx = blockIdx.x;
  int bd = bx / 3, g = bx - bd*3;
  int b = bd >> 8, dd = bd & 255;
  int t = threadIdx.x;
  for (int e = t; e < 4704; e += 192){
    int tap = e / 96, r = e - tap*96, ci = r >> 3, c = r & 7;
    wl[e] = w[(c*12 + ci)*49 + tap];
  }
  int fa[4], fb[4];
  fa[0] = dd>=2 ? dd-1 : 0;     fb[0] = dd>=2 ? dd-2 : 0;
  fa[1] = dd;                   fb[1] = dd>=1 ? dd-1 : 0;
  fa[2] = dd<=254 ? dd+1 : 255; fb[2] = dd;
  fa[3] = dd<=253 ? dd+2 : 255; fb[3] = dd<=254 ? dd+1 : 255;
  int pr = t / 24, pc = t - pr*24;
  float a00[8], a01[8], a10[8], a11[8];
  #pragma unroll
  for (int c=0;c<8;c++){ a00[c]=0.f; a01[c]=0.f; a10[c]=0.f; a11[c]=0.f; }
  for (int g4=0; g4<4; g4++){
    if (fa[g4] == fb[g4]) continue;   // zero diff, uniform per block
    __syncthreads();
    const float* xa = x + ((size_t)(b*256 + fa[g4]))*3*9216;
    const float* xbp= x + ((size_t)(b*256 + fb[g4]))*3*9216;
    for (int e = t; e < 3*37*102; e += 192){
      int ci = e / 3774, r2 = e - ci*3774;
      int ihl = r2 / 102, pi = r2 - ihl*102;
      int ih = ihl + 32*g - 3, iw = pi - 3;
      float v = 0.f;
      if (ih>=0 && ih<96 && iw>=0 && iw<96){
        size_t off = (size_t)ci*9216 + ih*96 + iw;
        v = xa[off] - xbp[off];
      }
      st[((ci*37 + ihl)*2 + (pi&1))*53 + (pi>>1)] = v;
    }
    __syncthreads();
    for (int ci=0; ci<3; ci++){
      int gch = g4*3 + ci;
      for (int kh=0; kh<7; kh++){
        int rb0 = (ci*37 + 4*pr + kh)*106 + 2*pc;
        int rb1 = rb0 + 212;
        #pragma unroll
        for (int kw=0; kw<7; kw++){
          int off = (kw&1)*53 + (kw>>1);
          float v00 = st[rb0+off], v01 = st[rb0+off+1];
          float v10 = st[rb1+off], v11 = st[rb1+off+1];
          const float4* wp = (const float4*)&wl[((kh*7+kw)*12 + gch)*8];
          float wv[8];
          *(float4*)&wv[0] = wp[0]; *(float4*)&wv[4] = wp[1];
          #pragma unroll
          for (int c=0;c<8;c++){
            a00[c] += v00*wv[c]; a01[c] += v01*wv[c];
            a10[c] += v10*wv[c]; a11[c] += v11*wv[c];
          }
        }
      }
    }
  }
  int pos = (g*8 + pr)*24 + pc;
  #pragma unroll
  for (int c=0;c<8;c++){
    float gg=bn[c], be=bn[8+c], m=bn[16+c], vv=bn[24+c];
    float s = gg*rsqrtf(vv + 1e-5f);
    float bi = bias[c];
    float mx = 0.f;
    mx = fmaxf(mx, (a00[c]+bi-m)*s+be);
    mx = fmaxf(mx, (a01[c]+bi-m)*s+be);
    mx = fmaxf(mx, (a10[c]+bi-m)*s+be);
    mx = fmaxf(mx, (a11[c]+bi-m)*s+be);
    xd[((size_t)bd*8 + c)*576 + pos] = mx;
  }
}

// s21/s22: in = 0.5*(A+B) [512,8,24,24] -> conv7x7 s1 p3 -> BN relu pool -> [512,16,12,12]
__global__ __launch_bounds__(256) void k_s2x(const float* __restrict__ inA,
    const float* __restrict__ inB, const float* __restrict__ w,
    const float* __restrict__ bias, const float* __restrict__ bn,
    float* __restrict__ outp){
  __shared__ float st[8*30*33];     // 7920
  __shared__ float wl[49*8*16];     // 6272
  int bd = blockIdx.x;
  int t = threadIdx.x;
  for (int e = t; e < 6272; e += 256){
    int tap = e >> 7, r = e & 127, ci = r >> 4, c = r & 15;
    wl[e] = w[(c*8 + ci)*49 + tap];
  }
  const float* pa = inA + (size_t)bd*8*576;
  const float* pb = inB + (size_t)bd*8*576;
  for (int e = t; e < 7920; e += 256){
    int ci = e / 990, r2 = e - ci*990;
    int r = r2 / 33, cc = r2 - r*33;
    int ih = r - 3, iw = cc - 3;
    float v = 0.f;
    if (ih>=0 && ih<24 && iw>=0 && iw<24){
      int off = ci*576 + ih*24 + iw;
      v = 0.5f*(pa[off] + pb[off]);
    }
    st[(ci*30 + r)*33 + cc] = v;
  }
  __syncthreads();
  if (t < 144){
    int pr = t / 12, pc = t - pr*12;
    float a00[16], a01[16], a10[16], a11[16];
    #pragma unroll
    for (int c=0;c<16;c++){ a00[c]=0.f; a01[c]=0.f; a10[c]=0.f; a11[c]=0.f; }
    for (int ci=0; ci<8; ci++){
      for (int kh=0; kh<7; kh++){
        int rb = (ci*30 + 2*pr + kh)*33 + 2*pc;
        #pragma unroll
        for (int kw=0; kw<7; kw++){
          float v00 = st[rb+kw],    v01 = st[rb+kw+1];
          float v10 = st[rb+33+kw], v11 = st[rb+34+kw];
          const float4* wp = (const float4*)&wl[((kh*7+kw)*8 + ci)*16];
          float wv[16];
          *(float4*)&wv[0]  = wp[0]; *(float4*)&wv[4]  = wp[1];
          *(float4*)&wv[8]  = wp[2]; *(float4*)&wv[12] = wp[3];
          #pragma unroll
          for (int c=0;c<16;c++){
            a00[c] += v00*wv[c]; a01[c] += v01*wv[c];
            a10[c] += v10*wv[c]; a11[c] += v11*wv[c];
          }
        }
      }
    }
    #pragma unroll
    for (int c=0;c<16;c++){
      float gg=bn[c], be=bn[16+c], m=bn[32+c], vv=bn[48+c];
      float s = gg*rsqrtf(vv + 1e-5f);
      float bi = bias[c];
      float mx = 0.f;
      mx = fmaxf(mx, (a00[c]+bi-m)*s+be);
      mx = fmaxf(mx, (a01[c]+bi-m)*s+be);
      mx = fmaxf(mx, (a10[c]+bi-m)*s+be);
      mx = fmaxf(mx, (a11[c]+bi-m)*s+be);
      outp[((size_t)bd*16 + c)*144 + pr*12 + pc] = mx;
    }
  }
}

// s3 conv3x3 p1 + BN + attention-mask pooled signal. block per bd. -> sig[512,64]
__global__ __launch_bounds__(256) void k_s3(const float* __restrict__ p1,
    const float* __restrict__ p2, const float* __restrict__ w,
    const float* __restrict__ bias, const float* __restrict__ bn,
    float* __restrict__ sig){
  __shared__ float ins[16*14*14];
  __shared__ float wT[144*64];
  __shared__ float redS[64*4];
  __shared__ float redF[64*4];
  int bd = blockIdx.x;
  int t = threadIdx.x;
  for (int i = t; i < 16*196; i += 256){
    int ci = i/196, r = i - ci*196, y = r/14, xx = r - y*14;
    float v = 0.f;
    if (y>=1 && y<=12 && xx>=1 && xx<=12){
      size_t idx = ((size_t)bd*16 + ci)*144 + (y-1)*12 + (xx-1);
      v = 0.5f*(p1[idx] + p2[idx]);
    }
    ins[i] = v;
  }
  for (int i = t; i < 9216; i += 256){
    int c = i & 63, k = i >> 6;
    wT[i] = w[c*144 + k];
  }
  __syncthreads();
  int c = t & 63, pg = t >> 6;
  float acc[36];
  #pragma unroll
  for (int pp=0;pp<36;pp++) acc[pp]=0.f;
  for (int k=0; k<144; k++){
    int ci = k/9, kk = k - ci*9, kh = kk/3, kw = kk - kh*3;
    float wv = wT[k*64 + c];
    const float* ip = &ins[ci*196];
    #pragma unroll
    for (int pp=0;pp<36;pp++){
      int y = pg*3 + pp/12, xx = pp%12;
      acc[pp] += ip[(y+kh)*14 + (xx+kw)] * wv;
    }
  }
  float g=bn[c], be=bn[64+c], m=bn[128+c], vv=bn[192+c];
  float s = g*rsqrtf(vv + 1e-5f);
  float bi = bias[c];
  float sS = 0.f, sF = 0.f;
  #pragma unroll
  for (int pp=0;pp<36;pp++){
    float f = (acc[pp] + bi - m)*s + be;
    float sg = sigmf(f);
    sS += sg; sF += f*sg;
  }
  redS[c*4+pg] = sS; redF[c*4+pg] = sF;
  __syncthreads();
  if (t < 64){
    float S = redS[t*4]+redS[t*4+1]+redS[t*4+2]+redS[t*4+3];
    float F = redF[t*4]+redF[t*4+1]+redF[t*4+2]+redF[t*4+3];
    sig[(size_t)bd*64 + t] = 0.5f*F/S;
  }
}

// c1 1x1 conv: sig[b,t,64] -> h[b,256,256] (channel-major). block=(b,o). grid 512.
__global__ __launch_bounds__(256) void k_c1(const float* __restrict__ sig,
    const float* __restrict__ w, const float* __restrict__ bias,
    float* __restrict__ h){
  int b = blockIdx.x >> 8, o = blockIdx.x & 255, tt = threadIdx.x;
  __shared__ float wl[64];
  if (tt < 64) wl[tt] = w[o*64 + tt];
  __syncthreads();
  const float4* sp = (const float4*)(sig + ((size_t)(b*256 + tt))*64);
  const float4* wp = (const float4*)wl;
  float a = bias[o];
  #pragma unroll
  for (int i=0;i<16;i++){
    float4 s4 = sp[i]; float4 w4 = wp[i];
    a += s4.x*w4.x + s4.y*w4.y + s4.z*w4.z + s4.w*w4.w;
  }
  h[((size_t)b*256 + o)*256 + tt] = fmaxf(a, 0.f);
}

// conv1d 256->256 k3 p1 + relu. mode: 0=none 1=acc:=out 2=acc+=out. grid 256.
__global__ __launch_bounds__(256) void k_conv1d(const float* __restrict__ hin,
    const float* __restrict__ w, const float* __restrict__ bias,
    float* __restrict__ hout, float* __restrict__ accb, int mode){
  __shared__ float ins[256*34];
  __shared__ float ws[16*256*4];   // padded stride-4 taps
  int bx = blockIdx.x;
  int b = bx >> 7;
  int rem = bx & 127;
  int og = rem >> 3;
  int tg = rem & 7;
  int tid = threadIdx.x;
  int t0 = tg*32;
  for (int idx = tid; idx < 256*34; idx += 256){
    int ii = idx/34, jj = idx - ii*34;
    int tglob = t0 - 1 + jj;
    float v = 0.f;
    if (tglob >= 0 && tglob < 256) v = hin[((size_t)b*256 + ii)*256 + tglob];
    ins[idx] = v;
  }
  for (int idx = tid; idx < 12288; idx += 256){
    int q = idx/3;
    ws[q*4 + (idx - q*3)] = w[(size_t)og*12288 + idx];
  }
  __syncthreads();
  int ol = tid >> 5, tl = tid & 31;
  int o1 = og*16 + ol, o2 = o1 + 8;
  float a1 = bias[o1], a2 = bias[o2];
  const float4* w1q = (const float4*)(ws + (size_t)ol*1024);
  const float4* w2q = (const float4*)(ws + (size_t)(ol+8)*1024);
  for (int i=0;i<256;i++){
    float v0 = ins[i*34 + tl];
    float v1 = ins[i*34 + tl + 1];
    float v2 = ins[i*34 + tl + 2];
    float4 wa = w1q[i];
    float4 wb = w2q[i];
    a1 += wa.x*v0 + wa.y*v1 + wa.z*v2;
    a2 += wb.x*v0 + wb.y*v1 + wb.z*v2;
  }
  a1 = fmaxf(a1, 0.f); a2 = fmaxf(a2, 0.f);
  size_t i1 = ((size_t)b*256 + o1)*256 + t0 + tl;
  size_t i2 = ((size_t)b*256 + o2)*256 + t0 + tl;
  hout[i1] = a1; hout[i2] = a2;
  if (mode == 1){ accb[i1] = a1; accb[i2] = a2; }
  else if (mode == 2){ accb[i1] += a1; accb[i2] += a2; }
}

// acc[b,c,t] -> transpose + LN(ln_g,ln_b) -> hid[(b t),c]. grid 512.
__global__ __launch_bounds__(256) void k_ln_tr(const float* __restrict__ acc,
    const float* __restrict__ g, const float* __restrict__ be,
    float* __restrict__ hid){
  int b = blockIdx.x >> 8, tt = blockIdx.x & 255, c = threadIdx.x;
  __shared__ float rs[4];
  __shared__ float rq[4];
  float v = acc[((size_t)b*256 + c)*256 + tt];
  float s1 = wsum64(v), s2 = wsum64(v*v);
  int wv = c >> 6, ln = c & 63;
  if (ln == 0){ rs[wv]=s1; rq[wv]=s2; }
  __syncthreads();
  float mu = (rs[0]+rs[1]+rs[2]+rs[3])*(1.f/256.f);
  float msq = (rq[0]+rq[1]+rq[2]+rq[3])*(1.f/256.f);
  float var = msq - mu*mu;
  hid[(size_t)blockIdx.x*256 + c] = (v-mu)*rsqrtf(var + 1e-5f)*g[c] + be[c];
}

// projections hid @ {wq,wk,wv}. grid 1536.
__global__ __launch_bounds__(256) void k_proj(const float* __restrict__ hid,
    const float* __restrict__ wq, const float* __restrict__ wk,
    const float* __restrict__ wv, float* __restrict__ xq,
    float* __restrict__ xk, float* __restrict__ xv){
  int m = blockIdx.x >> 9, row = blockIdx.x & 511, c = threadIdx.x;
  const float* W = (m==0) ? wq : ((m==1) ? wk : wv);
  float* O = (m==0) ? xq : ((m==1) ? xk : xv);
  __shared__ float hrow[256];
  hrow[c] = hid[(size_t)row*256 + c];
  __syncthreads();
  float a = 0.f;
  for (int k=0;k<256;k++) a += hrow[k]*W[(size_t)k*256 + c];
  O[(size_t)row*256 + c] = a;
}

// eta_lr (scaled): 0.1*sigmoid(hid.lr_w + lr_b)/64. grid 8 (b*4+h).
__global__ __launch_bounds__(256) void k_eta(const float* __restrict__ hid,
    const float* __restrict__ lrw, const float* __restrict__ lrb,
    float* __restrict__ etalr){
  int b = blockIdx.x >> 2, h = blockIdx.x & 3, l = threadIdx.x;
  const float* hp = hid + ((size_t)(b*256 + l))*256;
  float a = lrb[h];
  for (int k=0;k<256;k++) a += hp[k]*lrw[h*256 + k];
  etalr[(size_t)blockIdx.x*256 + l] = 0.1f*sigmf(a)*(1.f/64.f);
}

// TTT-MLP scan, register-resident fast weights. One block per (b,h).
// Thread j=(iw,cl): w1r[d]=W1[d][j]; w2c[dd]=W2[iw*64+dd][cl]; w2rT[c]=W2[j][c].
__global__ __launch_bounds__(256,1) void k_ttt(
    const float* __restrict__ xq, const float* __restrict__ xk,
    const float* __restrict__ xv, const float* __restrict__ etalr,
    const float* __restrict__ tib, const float* __restrict__ lnw,
    const float* __restrict__ lnb, const float* __restrict__ W1g,
    const float* __restrict__ B1g, const float* __restrict__ W2g,
    const float* __restrict__ B2g, float* __restrict__ out){
  __shared__ __align__(16) float k_pk[256];    // [d=64][i=4]
  __shared__ __align__(16) float q_pk[256];
  __shared__ __align__(16) float x2_pk[1024];  // [d=256][i=4]
  __shared__ __align__(16) float x2b_pk[1024];
  __shared__ __align__(16) float gz2_pk[256];  // [c=64][i=4]
  __shared__ float pzs[64*17];                 // partial dots [cl][i*4+ow], pad 17
  __shared__ float a2w[64];                    // per-wave A2 partials [w][i*4+r]
  __shared__ __align__(16) float coefs[16];
  __shared__ __align__(16) float coef2s[16];
  __shared__ __align__(16) float els[4];
  __shared__ float toks_s[4];

  int b = blockIdx.x >> 2, h = blockIdx.x & 3;
  int j = threadIdx.x;
  int iw = j >> 6, cl = j & 63;

  float w1r[64], w2c[64], w2rT[64];
  const float* W1b = W1g + (size_t)h*16384;
  const float* W2b = W2g + (size_t)h*16384;
  #pragma unroll
  for (int d=0; d<64; d++) w1r[d] = W1b[d*256 + j];
  #pragma unroll
  for (int dd=0; dd<64; dd++) w2c[dd] = W2b[(iw*64+dd)*64 + cl];
  #pragma unroll
  for (int c=0; c<16; c++){
    float4 t4 = *(const float4*)&W2b[j*64 + c*4];
    w2rT[c*4+0]=t4.x; w2rT[c*4+1]=t4.y; w2rT[c*4+2]=t4.z; w2rT[c*4+3]=t4.w;
  }
  float b1r = B1g[h*256 + j];
  float b2r = B2g[h*64 + cl];
  float gr = lnw[h*64 + cl], br = lnb[h*64 + cl];
  if (j < 4) toks_s[j] = fmaxf(1.f/(float)(j+1) + tib[j], 0.f);
  __syncthreads();
  float tok3 = toks_s[3];
  float tik = toks_s[iw];

  const float* xqp = xq + (size_t)b*65536 + h*64;
  const float* xkp = xk + (size_t)b*65536 + h*64;
  const float* xvp = xv + (size_t)b*65536 + h*64;
  const float* ep  = etalr + (size_t)(b*4 + h)*256;

  for (int n=0; n<64; n++){
    // --- stage q,k,v ---
    int l = n*4 + iw;
    float qv = xqp[(size_t)l*256 + cl];
    float kv = xkp[(size_t)l*256 + cl];
    float vv = xvp[(size_t)l*256 + cl];
    k_pk[cl*4+iw] = kv;
    q_pk[cl*4+iw] = qv;
    if (j < 4) els[j] = ep[n*4 + j];
    __syncthreads();                               // A
    // --- A1 row iw (tril coef) ---
    {
      float4 k4a = *(const float4*)&k_pk[cl*4];
      float a0 = wsum64(qv*k4a.x);
      float a1 = wsum64(qv*k4a.y);
      float a2 = wsum64(qv*k4a.z);
      float a3 = wsum64(qv*k4a.w);
      if (cl == 0){
        float4 e4 = *(const float4*)&els[0];
        coefs[iw*4+0] = tik*e4.x*(a0+1.f);
        coefs[iw*4+1] = (iw>=1) ? tik*e4.y*(a1+1.f) : 0.f;
        coefs[iw*4+2] = (iw>=2) ? tik*e4.z*(a2+1.f) : 0.f;
        coefs[iw*4+3] = (iw>=3) ? tik*e4.w*(a3+1.f) : 0.f;
      }
    }
    // --- Z1 = k@W1+b1, qW1 = q@W1+b1 ---
    float z1v0=b1r, z1v1=b1r, z1v2=b1r, z1v3=b1r;
    float qw0=b1r, qw1=b1r, qw2=b1r, qw3=b1r;
    #pragma unroll
    for (int d=0; d<64; d++){
      float4 k4 = *(const float4*)&k_pk[d*4];
      float4 q4 = *(const float4*)&q_pk[d*4];
      float w = w1r[d];
      z1v0 += k4.x*w; z1v1 += k4.y*w; z1v2 += k4.z*w; z1v3 += k4.w*w;
      qw0  += q4.x*w; qw1  += q4.y*w; qw2  += q4.z*w; qw3  += q4.w*w;
    }
    float x2o0 = geluf(z1v0), x2o1 = geluf(z1v1), x2o2 = geluf(z1v2), x2o3 = geluf(z1v3);
    { float4 t4; t4.x=x2o0; t4.y=x2o1; t4.z=x2o2; t4.w=x2o3;
      *(float4*)&x2_pk[j*4] = t4; }
    __syncthreads();                               // B
    // --- Z2 partial: thread (iw,cl) covers d in [iw*64, iw*64+64) ---
    {
      float p0=0.f,p1=0.f,p2=0.f,p3=0.f;
      #pragma unroll
      for (int dd=0; dd<64; dd++){
        float4 x4 = *(const float4*)&x2_pk[(iw*64+dd)*4];
        float w = w2c[dd];
        p0 += x4.x*w; p1 += x4.y*w; p2 += x4.z*w; p3 += x4.w*w;
      }
      pzs[cl*17 + 0*4 + iw] = p0;
      pzs[cl*17 + 1*4 + iw] = p1;
      pzs[cl*17 + 2*4 + iw] = p2;
      pzs[cl*17 + 3*4 + iw] = p3;
    }
    __syncthreads();                               // C
    float z2 = b2r + pzs[cl*17+iw*4] + pzs[cl*17+iw*4+1]
                   + pzs[cl*17+iw*4+2] + pzs[cl*17+iw*4+3];
    // --- fused LN-L2 backward (wave = minibatch row iw) ---
    float mu = wsum64(z2)*(1.f/64.f);
    float df = z2 - mu;
    float var = wsum64(df*df)*(1.f/64.f);
    float stdv = sqrtf(var + 1e-6f);
    float xhat = df/stdv;
    float tgt = vv - kv;
    float gxh = (gr*xhat + br - tgt)*gr;
    float sg1 = wsum64(gxh);
    float sg2 = wsum64(gxh*xhat);
    float gz2 = (64.f*gxh - sg1 - xhat*sg2)*(1.f/(64.f*stdv));
    gz2_pk[cl*4+iw] = gz2;
    __syncthreads();                               // D
    // --- gZ1 = (gZ2@W2^T)*gelu'(Z1); Z1b; X2b ---
    float gd0=0.f,gd1=0.f,gd2=0.f,gd3=0.f;
    #pragma unroll
    for (int c=0; c<64; c++){
      float4 g4 = *(const float4*)&gz2_pk[c*4];
      float w = w2rT[c];
      gd0 += g4.x*w; gd1 += g4.y*w; gd2 += g4.z*w; gd3 += g4.w*w;
    }
    float gz10 = gd0*gelu_bwdf(z1v0);
    float gz11 = gd1*gelu_bwdf(z1v1);
    float gz12 = gd2*gelu_bwdf(z1v2);
    float gz13 = gd3*gelu_bwdf(z1v3);
    float4 cf0 = *(const float4*)&coefs[0];
    float4 cf1 = *(const float4*)&coefs[4];
    float4 cf2 = *(const float4*)&coefs[8];
    float4 cf3 = *(const float4*)&coefs[12];
    float zb0 = qw0 - (cf0.x*gz10 + cf0.y*gz11 + cf0.z*gz12 + cf0.w*gz13);
    float zb1 = qw1 - (cf1.x*gz10 + cf1.y*gz11 + cf1.z*gz12 + cf1.w*gz13);
    float zb2 = qw2 - (cf2.x*gz10 + cf2.y*gz11 + cf2.z*gz12 + cf2.w*gz13);
    float zb3 = qw3 - (cf3.x*gz10 + cf3.y*gz11 + cf3.z*gz12 + cf3.w*gz13);
    float xb0 = geluf(zb0), xb1 = geluf(zb1), xb2 = geluf(zb2), xb3 = geluf(zb3);
    { float4 t4; t4.x=xb0; t4.y=xb1; t4.z=xb2; t4.w=xb3;
      *(float4*)&x2b_pk[j*4] = t4; }
    // --- A2 (masked r<=i), per-thread products + wave reduce ---
    {
      float s00 = wsum64(xb0*x2o0);
      float s10 = wsum64(xb1*x2o0);
      float s11 = wsum64(xb1*x2o1);
      float s20 = wsum64(xb2*x2o0);
      float s21 = wsum64(xb2*x2o1);
      float s22 = wsum64(xb2*x2o2);
      float s30 = wsum64(xb3*x2o0);
      float s31 = wsum64(xb3*x2o1);
      float s32 = wsum64(xb3*x2o2);
      float s33 = wsum64(xb3*x2o3);
      if (cl == 0){
        a2w[iw*16+0]  = s00;
        a2w[iw*16+4]  = s10; a2w[iw*16+5]  = s11;
        a2w[iw*16+8]  = s20; a2w[iw*16+9]  = s21; a2w[iw*16+10] = s22;
        a2w[iw*16+12] = s30; a2w[iw*16+13] = s31; a2w[iw*16+14] = s32; a2w[iw*16+15] = s33;
      }
    }
    __syncthreads();                               // E
    if (j < 16){
      int i2 = j >> 2, r2 = j & 3;
      float s = a2w[j] + a2w[16+j] + a2w[32+j] + a2w[48+j];
      coef2s[j] = (r2 <= i2) ? toks_s[i2]*els[r2]*(s + 1.f) : 0.f;
    }
    // --- Z2b partial ---
    {
      float p0=0.f,p1=0.f,p2=0.f,p3=0.f;
      #pragma unroll
      for (int dd=0; dd<64; dd++){
        float4 x4 = *(const float4*)&x2b_pk[(iw*64+dd)*4];
        float w = w2c[dd];
        p0 += x4.x*w; p1 += x4.y*w; p2 += x4.z*w; p3 += x4.w*w;
      }
      pzs[cl*17 + 0*4 + iw] = p0;
      pzs[cl*17 + 1*4 + iw] = p1;
      pzs[cl*17 + 2*4 + iw] = p2;
      pzs[cl*17 + 3*4 + iw] = p3;
    }
    __syncthreads();                               // F
    float z2b = b2r + pzs[cl*17+iw*4] + pzs[cl*17+iw*4+1]
                    + pzs[cl*17+iw*4+2] + pzs[cl*17+iw*4+3];
    float4 g4r = *(const float4*)&gz2_pk[cl*4];
    {
      float4 c2 = *(const float4*)&coef2s[iw*4];
      z2b -= c2.x*g4r.x + c2.y*g4r.y + c2.z*g4r.z + c2.w*g4r.w;
    }
    float mu2 = wsum64(z2b)*(1.f/64.f);
    float df2 = z2b - mu2;
    float var2 = wsum64(df2*df2)*(1.f/64.f);
    float lnv = gr*df2*rsqrtf(var2 + 1e-6f) + br;
    out[((size_t)b*256 + n*4 + iw)*256 + h*64 + cl] = qv + lnv;
    // --- state updates ---
    float4 e4 = *(const float4*)&els[0];
    float le0 = tok3*e4.x, le1 = tok3*e4.y, le2 = tok3*e4.z, le3 = tok3*e4.w;
    float lg10 = le0*gz10, lg11 = le1*gz11, lg12 = le2*gz12, lg13 = le3*gz13;
    #pragma unroll
    for (int d=0; d<64; d++){
      float4 k4 = *(const float4*)&k_pk[d*4];
      w1r[d] -= lg10*k4.x + lg11*k4.y + lg12*k4.z + lg13*k4.w;
    }
    b1r -= lg10 + lg11 + lg12 + lg13;
    float lz0 = le0*g4r.x, lz1 = le1*g4r.y, lz2 = le2*g4r.z, lz3 = le3*g4r.w;
    #pragma unroll
    for (int dd=0; dd<64; dd++){
      float4 x4 = *(const float4*)&x2b_pk[(iw*64+dd)*4];
      w2c[dd] -= lz0*x4.x + lz1*x4.y + lz2*x4.z + lz3*x4.w;
    }
    float lx0 = le0*xb0, lx1 = le1*xb1, lx2 = le2*xb2, lx3 = le3*xb3;
    #pragma unroll
    for (int c=0; c<64; c++){
      float4 g4 = *(const float4*)&gz2_pk[c*4];
      w2rT[c] -= lx0*g4.x + lx1*g4.y + lx2*g4.z + lx3*g4.w;
    }
    b2r -= lz0 + lz1 + lz2 + lz3;
    __syncthreads();                               // G
  }
}

// Fused head: LN(post) -> @wo -> LN(ln) -> fc1 -> fc2 -> fc3. grid 512 rows.
__global__ __launch_bounds__(256) void k_head(const float* __restrict__ hid2,
    const float* __restrict__ pg, const float* __restrict__ pb,
    const float* __restrict__ wo, const float* __restrict__ lg,
    const float* __restrict__ lb, const float* __restrict__ fcw,
    const float* __restrict__ fcb, const float* __restrict__ fc2w,
    const float* __restrict__ fc2b, const float* __restrict__ fc3w,
    const float* __restrict__ fc3b, float* __restrict__ outp){
  int row = blockIdx.x, c = threadIdx.x;
  __shared__ float t1[256];
  __shared__ float t3[256];
  __shared__ float t4[128];
  __shared__ float t5[64];
  __shared__ float rs[4];
  __shared__ float rq[4];
  int wv = c >> 6, ln = c & 63;
  float v = hid2[(size_t)row*256 + c];
  float s1 = wsum64(v), s2 = wsum64(v*v);
  if (ln == 0){ rs[wv]=s1; rq[wv]=s2; }
  __syncthreads();
  float mu = (rs[0]+rs[1]+rs[2]+rs[3])*(1.f/256.f);
  float msq = (rq[0]+rq[1]+rq[2]+rq[3])*(1.f/256.f);
  float var = msq - mu*mu;
  t1[c] = (v-mu)*rsqrtf(var + 1e-5f)*pg[c] + pb[c];
  __syncthreads();
  float a = 0.f;
  for (int k=0;k<256;k++) a += t1[k]*wo[(size_t)k*256 + c];
  float u1 = wsum64(a), u2 = wsum64(a*a);
  if (ln == 0){ rs[wv]=u1; rq[wv]=u2; }
  __syncthreads();
  mu = (rs[0]+rs[1]+rs[2]+rs[3])*(1.f/256.f);
  msq = (rq[0]+rq[1]+rq[2]+rq[3])*(1.f/256.f);
  var = msq - mu*mu;
  t3[c] = (a-mu)*rsqrtf(var + 1e-5f)*lg[c] + lb[c];
  __syncthreads();
  if (c < 128){
    float s = fcb[c];
    for (int k=0;k<256;k++) s += t3[k]*fcw[(size_t)k*128 + c];
    t4[c] = s;
  }
  __syncthreads();
  if (c < 64){
    float s = fc2b[c];
    for (int k=0;k<128;k++) s += t4[k]*fc2w[(size_t)k*64 + c];
    t5[c] = s;
  }
  __syncthreads();
  if (c < 64){
    float p = t5[c]*fc3w[c];
    p = wsum64(p);
    if (c == 0) outp[row] = p + fc3b[0];
  }
}

extern "C" void kernel_launch(void* const* d_in, const int* in_sizes, int n_in,
                              void* d_out, int out_size, void* d_ws, size_t ws_size,
                              hipStream_t stream){
  (void)in_sizes; (void)n_in; (void)out_size; (void)ws_size;
  const float* x       = (const float*)d_in[0];
  const float* s11_w   = (const float*)d_in[1];
  const float* s11_b   = (const float*)d_in[2];
  const float* bn11    = (const float*)d_in[3];
  const float* s12_w   = (const float*)d_in[4];
  const float* s12_b   = (const float*)d_in[5];
  const float* bn12    = (const float*)d_in[6];
  const float* s21_w   = (const float*)d_in[7];
  const float* s21_b   = (const float*)d_in[8];
  const float* bn21    = (const float*)d_in[9];
  const float* s22_w   = (const float*)d_in[10];
  const float* s22_b   = (const float*)d_in[11];
  const float* bn22    = (const float*)d_in[12];
  const float* s3_w    = (const float*)d_in[13];
  const float* s3_b    = (const float*)d_in[14];
  const float* bn3     = (const float*)d_in[15];
  const float* c1_w    = (const float*)d_in[16];
  const float* c1_b    = (const float*)d_in[17];
  const float* cb_w    = (const float*)d_in[18];
  const float* cb_b    = (const float*)d_in[19];
  const float* ln_g    = (const float*)d_in[20];
  const float* ln_b    = (const float*)d_in[21];
  const float* wq      = (const float*)d_in[22];
  const float* wk      = (const float*)d_in[23];
  const float* wv      = (const float*)d_in[24];
  const float* wo      = (const float*)d_in[25];
  const float* lr_w    = (const float*)d_in[26];
  const float* lr_b    = (const float*)d_in[27];
  const float* tib     = (const float*)d_in[28];
  const float* tlnw    = (const float*)d_in[29];
  const float* tlnb    = (const float*)d_in[30];
  const float* W1      = (const float*)d_in[31];
  const float* B1      = (const float*)d_in[32];
  const float* W2      = (const float*)d_in[33];
  const float* B2      = (const float*)d_in[34];
  const float* post_g  = (const float*)d_in[35];
  const float* post_b  = (const float*)d_in[36];
  const float* fc_w    = (const float*)d_in[37];
  const float* fc_b    = (const float*)d_in[38];
  const float* fc2_w   = (const float*)d_in[39];
  const float* fc2_b   = (const float*)d_in[40];
  const float* fc3_w   = (const float*)d_in[41];
  const float* fc3_b   = (const float*)d_in[42];

  float* ws = (float*)d_ws;
  float* xs   = ws;                       // 2359296
  float* xd   = ws + 2359296;             // 2359296
  float* p1   = ws + 4718592;             // 1179648
  float* p2   = ws + 5898240;             // 1179648
  float* sig  = ws + 7077888;             // 32768
  float* buf0 = ws + 7110656;             // 131072
  float* buf1 = ws + 7241728;             // 131072
  float* accb = ws + 7372800;             // 131072
  float* hid  = ws + 7503872;             // 131072
  float* xqb  = ws + 7634944;             // 131072
  float* xkb  = ws + 7766016;             // 131072
  float* xvb  = ws + 7897088;             // 131072
  float* eta  = ws + 8028160;             // 2048
  float* hid2 = ws + 8030208;             // 131072

  k_s11<<<1536, 192, 0, stream>>>(x, s11_w, s11_b, bn11, xs);
  k_s12<<<1536, 192, 0, stream>>>(x, s12_w, s12_b, bn12, xd);
  k_s2x<<<512, 256, 0, stream>>>(xs, xd, s21_w, s21_b, bn21, p1);
  k_s2x<<<512, 256, 0, stream>>>(xd, xd, s22_w, s22_b, bn22, p2);
  k_s3<<<512, 256, 0, stream>>>(p1, p2, s3_w, s3_b, bn3, sig);
  k_c1<<<512, 256, 0, stream>>>(sig, c1_w, c1_b, buf0);
  {
    float* cin = buf0; float* cout = buf1;
    for (int l=0; l<8; l++){
      int mode = (l == 1) ? 1 : ((l & 1) ? 2 : 0);
      k_conv1d<<<256, 256, 0, stream>>>(cin, cb_w + (size_t)l*196608,
                                        cb_b + l*256, cout, accb, mode);
      float* tmp = cin; cin = cout; cout = tmp;
    }
  }
  k_ln_tr<<<512, 256, 0, stream>>>(accb, ln_g, ln_b, hid);
  k_proj<<<1536, 256, 0, stream>>>(hid, wq, wk, wv, xqb, xkb, xvb);
  k_eta<<<8, 256, 0, stream>>>(hid, lr_w, lr_b, eta);
  k_ttt<<<8, 256, 0, stream>>>(xqb, xkb, xvb, eta, tib, tlnw, tlnb,
                               W1, B1, W2, B2, hid2);
  k_head<<<512, 256, 0, stream>>>(hid2, post_g, post_b, wo, ln_g, ln_b,
                                  fc_w, fc_b, fc2_w, fc2_b, fc3_w, fc3_b,
                                  (float*)d_out);
}

// Round 4
// 3580.875 us; speedup vs baseline: 1.0934x; 1.0934x over previous
//
#include <hip/hip_runtime.h>
#include <hip/hip_bf16.h>
#include <math.h>

#define DEV __device__ __forceinline__

DEV float wsum64(float v){
  #pragma unroll
  for (int off = 32; off; off >>= 1) v += __shfl_xor(v, off, 64);
  return v;
}
DEV float geluf(float x){
  return 0.5f*x*(1.f + tanhf(0.7978845608028654f*(x + 0.044715f*x*x*x)));
}
DEV float gelu_bwdf(float x){
  float x2 = x*x;
  float t = tanhf(0.79788456f*x*(1.f + 0.044715f*x2));
  return 0.5f*x*((1.f - t*t)*(0.79788456f + 0.1070322243f*x2)) + 0.5f*(1.f + t);
}
DEV float sigmf(float x){ return 1.f/(1.f + expf(-x)); }

// ---------------------------------------------------------------------------
// Stem s11: x[512,3,96,96] -> conv7x7 s2 p3 -> BN -> ReLU -> pool2 -> xs[512,8,24,24]
__global__ __launch_bounds__(192) void k_s11(const float* __restrict__ x,
    const float* __restrict__ w, const float* __restrict__ bias,
    const float* __restrict__ bn, float* __restrict__ xs){
  __shared__ float st[3*37*2*53];   // 11766 floats
  __shared__ float wl[49*3*8];      // 1176
  int bx = blockIdx.x;
  int bd = bx / 3, g = bx - bd*3;
  int t = threadIdx.x;
  for (int e = t; e < 1176; e += 192){
    int tap = e / 24, r = e - tap*24, ci = r >> 3, c = r & 7;
    wl[e] = w[(c*3 + ci)*49 + tap];
  }
  const float* xb = x + (size_t)bd*3*9216;
  for (int e = t; e < 3*37*102; e += 192){
    int ci = e / 3774, r2 = e - ci*3774;
    int ihl = r2 / 102, pi = r2 - ihl*102;
    int ih = ihl + 32*g - 3, iw = pi - 3;
    float v = 0.f;
    if (ih>=0 && ih<96 && iw>=0 && iw<96) v = xb[(size_t)ci*9216 + ih*96 + iw];
    st[((ci*37 + ihl)*2 + (pi&1))*53 + (pi>>1)] = v;
  }
  __syncthreads();
  int pr = t / 24, pc = t - pr*24;
  float a00[8], a01[8], a10[8], a11[8];
  #pragma unroll
  for (int c=0;c<8;c++){ a00[c]=0.f; a01[c]=0.f; a10[c]=0.f; a11[c]=0.f; }
  for (int ci=0; ci<3; ci++){
    for (int kh=0; kh<7; kh++){
      int rb0 = (ci*37 + 4*pr + kh)*106 + 2*pc;
      int rb1 = rb0 + 212;
      #pragma unroll
      for (int kw=0; kw<7; kw++){
        int off = (kw&1)*53 + (kw>>1);
        float v00 = st[rb0+off], v01 = st[rb0+off+1];
        float v10 = st[rb1+off], v11 = st[rb1+off+1];
        const float4* wp = (const float4*)&wl[((kh*7+kw)*3 + ci)*8];
        float wv[8];
        *(float4*)&wv[0] = wp[0]; *(float4*)&wv[4] = wp[1];
        #pragma unroll
        for (int c=0;c<8;c++){
          a00[c] += v00*wv[c]; a01[c] += v01*wv[c];
          a10[c] += v10*wv[c]; a11[c] += v11*wv[c];
        }
      }
    }
  }
  int pos = (g*8 + pr)*24 + pc;
  #pragma unroll
  for (int c=0;c<8;c++){
    float gg=bn[c], be=bn[8+c], m=bn[16+c], vv=bn[24+c];
    float s = gg*rsqrtf(vv + 1e-5f);
    float bi = bias[c];
    float mx = 0.f;
    mx = fmaxf(mx, (a00[c]+bi-m)*s+be);
    mx = fmaxf(mx, (a01[c]+bi-m)*s+be);
    mx = fmaxf(mx, (a10[c]+bi-m)*s+be);
    mx = fmaxf(mx, (a11[c]+bi-m)*s+be);
    xs[((size_t)bd*8 + c)*576 + pos] = mx;
  }
}

// Stem s12: same structure on frame-diffs (4 groups of 3 channels, diff at staging).
__global__ __launch_bounds__(192) void k_s12(const float* __restrict__ x,
    const float* __restrict__ w, const float* __restrict__ bias,
    const float* __restrict__ bn, float* __restrict__ xd){
  __shared__ float st[3*37*2*53];
  __shared__ float wl[49*12*8];     // 4704
  int bx = blockIdx.x;
  int bd = bx / 3, g = bx - bd*3;
  int b = bd >> 8, dd = bd & 255;
  int t = threadIdx.x;
  for (int e = t; e < 4704; e += 192){
    int tap = e / 96, r = e - tap*96, ci = r >> 3, c = r & 7;
    wl[e] = w[(c*12 + ci)*49 + tap];
  }
  int fa[4], fb[4];
  fa[0] = dd>=2 ? dd-1 : 0;     fb[0] = dd>=2 ? dd-2 : 0;
  fa[1] = dd;                   fb[1] = dd>=1 ? dd-1 : 0;
  fa[2] = dd<=254 ? dd+1 : 255; fb[2] = dd;
  fa[3] = dd<=253 ? dd+2 : 255; fb[3] = dd<=254 ? dd+1 : 255;
  int pr = t / 24, pc = t - pr*24;
  float a00[8], a01[8], a10[8], a11[8];
  #pragma unroll
  for (int c=0;c<8;c++){ a00[c]=0.f; a01[c]=0.f; a10[c]=0.f; a11[c]=0.f; }
  for (int g4=0; g4<4; g4++){
    if (fa[g4] == fb[g4]) continue;   // zero diff, uniform per block
    __syncthreads();
    const float* xa = x + ((size_t)(b*256 + fa[g4]))*3*9216;
    const float* xbp= x + ((size_t)(b*256 + fb[g4]))*3*9216;
    for (int e = t; e < 3*37*102; e += 192){
      int ci = e / 3774, r2 = e - ci*3774;
      int ihl = r2 / 102, pi = r2 - ihl*102;
      int ih = ihl + 32*g - 3, iw = pi - 3;
      float v = 0.f;
      if (ih>=0 && ih<96 && iw>=0 && iw<96){
        size_t off = (size_t)ci*9216 + ih*96 + iw;
        v = xa[off] - xbp[off];
      }
      st[((ci*37 + ihl)*2 + (pi&1))*53 + (pi>>1)] = v;
    }
    __syncthreads();
    for (int ci=0; ci<3; ci++){
      int gch = g4*3 + ci;
      for (int kh=0; kh<7; kh++){
        int rb0 = (ci*37 + 4*pr + kh)*106 + 2*pc;
        int rb1 = rb0 + 212;
        #pragma unroll
        for (int kw=0; kw<7; kw++){
          int off = (kw&1)*53 + (kw>>1);
          float v00 = st[rb0+off], v01 = st[rb0+off+1];
          float v10 = st[rb1+off], v11 = st[rb1+off+1];
          const float4* wp = (const float4*)&wl[((kh*7+kw)*12 + gch)*8];
          float wv[8];
          *(float4*)&wv[0] = wp[0]; *(float4*)&wv[4] = wp[1];
          #pragma unroll
          for (int c=0;c<8;c++){
            a00[c] += v00*wv[c]; a01[c] += v01*wv[c];
            a10[c] += v10*wv[c]; a11[c] += v11*wv[c];
          }
        }
      }
    }
  }
  int pos = (g*8 + pr)*24 + pc;
  #pragma unroll
  for (int c=0;c<8;c++){
    float gg=bn[c], be=bn[8+c], m=bn[16+c], vv=bn[24+c];
    float s = gg*rsqrtf(vv + 1e-5f);
    float bi = bias[c];
    float mx = 0.f;
    mx = fmaxf(mx, (a00[c]+bi-m)*s+be);
    mx = fmaxf(mx, (a01[c]+bi-m)*s+be);
    mx = fmaxf(mx, (a10[c]+bi-m)*s+be);
    mx = fmaxf(mx, (a11[c]+bi-m)*s+be);
    xd[((size_t)bd*8 + c)*576 + pos] = mx;
  }
}

// s21/s22: in = 0.5*(A+B) [512,8,24,24] -> conv7x7 s1 p3 -> BN relu pool -> [512,16,12,12]
__global__ __launch_bounds__(256) void k_s2x(const float* __restrict__ inA,
    const float* __restrict__ inB, const float* __restrict__ w,
    const float* __restrict__ bias, const float* __restrict__ bn,
    float* __restrict__ outp){
  __shared__ float st[8*30*33];     // 7920
  __shared__ float wl[49*8*16];     // 6272
  int bd = blockIdx.x;
  int t = threadIdx.x;
  for (int e = t; e < 6272; e += 256){
    int tap = e >> 7, r = e & 127, ci = r >> 4, c = r & 15;
    wl[e] = w[(c*8 + ci)*49 + tap];
  }
  const float* pa = inA + (size_t)bd*8*576;
  const float* pb = inB + (size_t)bd*8*576;
  for (int e = t; e < 7920; e += 256){
    int ci = e / 990, r2 = e - ci*990;
    int r = r2 / 33, cc = r2 - r*33;
    int ih = r - 3, iw = cc - 3;
    float v = 0.f;
    if (ih>=0 && ih<24 && iw>=0 && iw<24){
      int off = ci*576 + ih*24 + iw;
      v = 0.5f*(pa[off] + pb[off]);
    }
    st[(ci*30 + r)*33 + cc] = v;
  }
  __syncthreads();
  if (t < 144){
    int pr = t / 12, pc = t - pr*12;
    float a00[16], a01[16], a10[16], a11[16];
    #pragma unroll
    for (int c=0;c<16;c++){ a00[c]=0.f; a01[c]=0.f; a10[c]=0.f; a11[c]=0.f; }
    for (int ci=0; ci<8; ci++){
      for (int kh=0; kh<7; kh++){
        int rb = (ci*30 + 2*pr + kh)*33 + 2*pc;
        #pragma unroll
        for (int kw=0; kw<7; kw++){
          float v00 = st[rb+kw],    v01 = st[rb+kw+1];
          float v10 = st[rb+33+kw], v11 = st[rb+34+kw];
          const float4* wp = (const float4*)&wl[((kh*7+kw)*8 + ci)*16];
          float wv[16];
          *(float4*)&wv[0]  = wp[0]; *(float4*)&wv[4]  = wp[1];
          *(float4*)&wv[8]  = wp[2]; *(float4*)&wv[12] = wp[3];
          #pragma unroll
          for (int c=0;c<16;c++){
            a00[c] += v00*wv[c]; a01[c] += v01*wv[c];
            a10[c] += v10*wv[c]; a11[c] += v11*wv[c];
          }
        }
      }
    }
    #pragma unroll
    for (int c=0;c<16;c++){
      float gg=bn[c], be=bn[16+c], m=bn[32+c], vv=bn[48+c];
      float s = gg*rsqrtf(vv + 1e-5f);
      float bi = bias[c];
      float mx = 0.f;
      mx = fmaxf(mx, (a00[c]+bi-m)*s+be);
      mx = fmaxf(mx, (a01[c]+bi-m)*s+be);
      mx = fmaxf(mx, (a10[c]+bi-m)*s+be);
      mx = fmaxf(mx, (a11[c]+bi-m)*s+be);
      outp[((size_t)bd*16 + c)*144 + pr*12 + pc] = mx;
    }
  }
}

// s3 conv3x3 p1 + BN + attention-mask pooled signal. block per bd. -> sig[512,64]
__global__ __launch_bounds__(256) void k_s3(const float* __restrict__ p1,
    const float* __restrict__ p2, const float* __restrict__ w,
    const float* __restrict__ bias, const float* __restrict__ bn,
    float* __restrict__ sig){
  __shared__ float ins[16*14*14];
  __shared__ float wT[144*64];
  __shared__ float redS[64*4];
  __shared__ float redF[64*4];
  int bd = blockIdx.x;
  int t = threadIdx.x;
  for (int i = t; i < 16*196; i += 256){
    int ci = i/196, r = i - ci*196, y = r/14, xx = r - y*14;
    float v = 0.f;
    if (y>=1 && y<=12 && xx>=1 && xx<=12){
      size_t idx = ((size_t)bd*16 + ci)*144 + (y-1)*12 + (xx-1);
      v = 0.5f*(p1[idx] + p2[idx]);
    }
    ins[i] = v;
  }
  for (int i = t; i < 9216; i += 256){
    int c = i & 63, k = i >> 6;
    wT[i] = w[c*144 + k];
  }
  __syncthreads();
  int c = t & 63, pg = t >> 6;
  float acc[36];
  #pragma unroll
  for (int pp=0;pp<36;pp++) acc[pp]=0.f;
  for (int k=0; k<144; k++){
    int ci = k/9, kk = k - ci*9, kh = kk/3, kw = kk - kh*3;
    float wv = wT[k*64 + c];
    const float* ip = &ins[ci*196];
    #pragma unroll
    for (int pp=0;pp<36;pp++){
      int y = pg*3 + pp/12, xx = pp%12;
      acc[pp] += ip[(y+kh)*14 + (xx+kw)] * wv;
    }
  }
  float g=bn[c], be=bn[64+c], m=bn[128+c], vv=bn[192+c];
  float s = g*rsqrtf(vv + 1e-5f);
  float bi = bias[c];
  float sS = 0.f, sF = 0.f;
  #pragma unroll
  for (int pp=0;pp<36;pp++){
    float f = (acc[pp] + bi - m)*s + be;
    float sg = sigmf(f);
    sS += sg; sF += f*sg;
  }
  redS[c*4+pg] = sS; redF[c*4+pg] = sF;
  __syncthreads();
  if (t < 64){
    float S = redS[t*4]+redS[t*4+1]+redS[t*4+2]+redS[t*4+3];
    float F = redF[t*4]+redF[t*4+1]+redF[t*4+2]+redF[t*4+3];
    sig[(size_t)bd*64 + t] = 0.5f*F/S;
  }
}

// c1 1x1 conv: sig[b,t,64] -> h[b,256,256] (channel-major). block=(b,o). grid 512.
__global__ __launch_bounds__(256) void k_c1(const float* __restrict__ sig,
    const float* __restrict__ w, const float* __restrict__ bias,
    float* __restrict__ h){
  int b = blockIdx.x >> 8, o = blockIdx.x & 255, tt = threadIdx.x;
  __shared__ float wl[64];
  if (tt < 64) wl[tt] = w[o*64 + tt];
  __syncthreads();
  const float4* sp = (const float4*)(sig + ((size_t)(b*256 + tt))*64);
  const float4* wp = (const float4*)wl;
  float a = bias[o];
  #pragma unroll
  for (int i=0;i<16;i++){
    float4 s4 = sp[i]; float4 w4 = wp[i];
    a += s4.x*w4.x + s4.y*w4.y + s4.z*w4.z + s4.w*w4.w;
  }
  h[((size_t)b*256 + o)*256 + tt] = fmaxf(a, 0.f);
}

// conv1d 256->256 k3 p1 + relu. mode: 0=none 1=acc:=out 2=acc+=out. grid 256.
__global__ __launch_bounds__(256) void k_conv1d(const float* __restrict__ hin,
    const float* __restrict__ w, const float* __restrict__ bias,
    float* __restrict__ hout, float* __restrict__ accb, int mode){
  __shared__ float ins[256*34];
  __shared__ float ws[16*256*4];   // padded stride-4 taps
  int bx = blockIdx.x;
  int b = bx >> 7;
  int rem = bx & 127;
  int og = rem >> 3;
  int tg = rem & 7;
  int tid = threadIdx.x;
  int t0 = tg*32;
  for (int idx = tid; idx < 256*34; idx += 256){
    int ii = idx/34, jj = idx - ii*34;
    int tglob = t0 - 1 + jj;
    float v = 0.f;
    if (tglob >= 0 && tglob < 256) v = hin[((size_t)b*256 + ii)*256 + tglob];
    ins[idx] = v;
  }
  for (int idx = tid; idx < 12288; idx += 256){
    int q = idx/3;
    ws[q*4 + (idx - q*3)] = w[(size_t)og*12288 + idx];
  }
  __syncthreads();
  int ol = tid >> 5, tl = tid & 31;
  int o1 = og*16 + ol, o2 = o1 + 8;
  float a1 = bias[o1], a2 = bias[o2];
  const float4* w1q = (const float4*)(ws + (size_t)ol*1024);
  const float4* w2q = (const float4*)(ws + (size_t)(ol+8)*1024);
  for (int i=0;i<256;i++){
    float v0 = ins[i*34 + tl];
    float v1 = ins[i*34 + tl + 1];
    float v2 = ins[i*34 + tl + 2];
    float4 wa = w1q[i];
    float4 wb = w2q[i];
    a1 += wa.x*v0 + wa.y*v1 + wa.z*v2;
    a2 += wb.x*v0 + wb.y*v1 + wb.z*v2;
  }
  a1 = fmaxf(a1, 0.f); a2 = fmaxf(a2, 0.f);
  size_t i1 = ((size_t)b*256 + o1)*256 + t0 + tl;
  size_t i2 = ((size_t)b*256 + o2)*256 + t0 + tl;
  hout[i1] = a1; hout[i2] = a2;
  if (mode == 1){ accb[i1] = a1; accb[i2] = a2; }
  else if (mode == 2){ accb[i1] += a1; accb[i2] += a2; }
}

// acc[b,c,t] -> transpose + LN(ln_g,ln_b) -> hid[(b t),c]. grid 512.
__global__ __launch_bounds__(256) void k_ln_tr(const float* __restrict__ acc,
    const float* __restrict__ g, const float* __restrict__ be,
    float* __restrict__ hid){
  int b = blockIdx.x >> 8, tt = blockIdx.x & 255, c = threadIdx.x;
  __shared__ float rs[4];
  __shared__ float rq[4];
  float v = acc[((size_t)b*256 + c)*256 + tt];
  float s1 = wsum64(v), s2 = wsum64(v*v);
  int wv = c >> 6, ln = c & 63;
  if (ln == 0){ rs[wv]=s1; rq[wv]=s2; }
  __syncthreads();
  float mu = (rs[0]+rs[1]+rs[2]+rs[3])*(1.f/256.f);
  float msq = (rq[0]+rq[1]+rq[2]+rq[3])*(1.f/256.f);
  float var = msq - mu*mu;
  hid[(size_t)blockIdx.x*256 + c] = (v-mu)*rsqrtf(var + 1e-5f)*g[c] + be[c];
}

// projections hid @ {wq,wk,wv}. grid 1536.
__global__ __launch_bounds__(256) void k_proj(const float* __restrict__ hid,
    const float* __restrict__ wq, const float* __restrict__ wk,
    const float* __restrict__ wv, float* __restrict__ xq,
    float* __restrict__ xk, float* __restrict__ xv){
  int m = blockIdx.x >> 9, row = blockIdx.x & 511, c = threadIdx.x;
  const float* W = (m==0) ? wq : ((m==1) ? wk : wv);
  float* O = (m==0) ? xq : ((m==1) ? xk : xv);
  __shared__ float hrow[256];
  hrow[c] = hid[(size_t)row*256 + c];
  __syncthreads();
  float a = 0.f;
  for (int k=0;k<256;k++) a += hrow[k]*W[(size_t)k*256 + c];
  O[(size_t)row*256 + c] = a;
}

// eta_lr (scaled): 0.1*sigmoid(hid.lr_w + lr_b)/64. grid 8 (b*4+h).
__global__ __launch_bounds__(256) void k_eta(const float* __restrict__ hid,
    const float* __restrict__ lrw, const float* __restrict__ lrb,
    float* __restrict__ etalr){
  int b = blockIdx.x >> 2, h = blockIdx.x & 3, l = threadIdx.x;
  const float* hp = hid + ((size_t)(b*256 + l))*256;
  float a = lrb[h];
  for (int k=0;k<256;k++) a += hp[k]*lrw[h*256 + k];
  etalr[(size_t)blockIdx.x*256 + l] = 0.1f*sigmf(a)*(1.f/64.f);
}

// TTT-MLP scan. One block per (b,h). Hybrid: W1 column + W2 row in registers
// (128 VGPRs), W2 also published to LDS (pitch 65, conflict-free both ways).
__global__ __launch_bounds__(256) void k_ttt(
    const float* __restrict__ xq, const float* __restrict__ xk,
    const float* __restrict__ xv, const float* __restrict__ etalr,
    const float* __restrict__ tib, const float* __restrict__ lnw,
    const float* __restrict__ lnb, const float* __restrict__ W1g,
    const float* __restrict__ B1g, const float* __restrict__ W2g,
    const float* __restrict__ B2g, float* __restrict__ out){
  __shared__ __align__(16) float k_pk[256];    // [d=64][i=4]
  __shared__ __align__(16) float q_pk[256];
  __shared__ __align__(16) float x2_pk[1024];  // [d=256][i=4]
  __shared__ __align__(16) float x2b_pk[1024];
  __shared__ __align__(16) float gz2_pk[256];  // [c=64][i=4]
  __shared__ float W2L[256*65];                // [r][c], pitch 65
  __shared__ float pzs[64*17];                 // partial dots [cl][i*4+ow]
  __shared__ float a2w[64];                    // per-wave A2 partials
  __shared__ __align__(16) float coefs[16];
  __shared__ __align__(16) float coef2s[16];
  __shared__ __align__(16) float els[4];
  __shared__ float toks_s[4];

  int b = blockIdx.x >> 2, h = blockIdx.x & 3;
  int j = threadIdx.x;
  int iw = j >> 6, cl = j & 63;

  float w1r[64], w2rT[64];
  const float* W1b = W1g + (size_t)h*16384;
  const float* W2b = W2g + (size_t)h*16384;
  #pragma unroll
  for (int d=0; d<64; d++) w1r[d] = W1b[d*256 + j];
  #pragma unroll
  for (int c4=0; c4<16; c4++){
    float4 t4 = *(const float4*)&W2b[j*64 + c4*4];
    w2rT[c4*4+0]=t4.x; w2rT[c4*4+1]=t4.y; w2rT[c4*4+2]=t4.z; w2rT[c4*4+3]=t4.w;
  }
  #pragma unroll
  for (int c=0; c<64; c++) W2L[j*65 + c] = w2rT[c];
  float b1r = B1g[h*256 + j];
  float b2r = B2g[h*64 + cl];
  float gr = lnw[h*64 + cl], br = lnb[h*64 + cl];
  if (j < 4) toks_s[j] = fmaxf(1.f/(float)(j+1) + tib[j], 0.f);
  __syncthreads();
  float tok3 = toks_s[3];
  float tik = toks_s[iw];

  const float* xqp = xq + (size_t)b*65536 + h*64;
  const float* xkp = xk + (size_t)b*65536 + h*64;
  const float* xvp = xv + (size_t)b*65536 + h*64;
  const float* ep  = etalr + (size_t)(b*4 + h)*256;

  float qv = xqp[(size_t)iw*256 + cl];
  float kv = xkp[(size_t)iw*256 + cl];
  float vv = xvp[(size_t)iw*256 + cl];
  float elv = (j < 4) ? ep[j] : 0.f;

  for (int n=0; n<64; n++){
    k_pk[cl*4+iw] = kv;
    q_pk[cl*4+iw] = qv;
    if (j < 4) els[j] = elv;
    __syncthreads();                               // A
    // --- A1 row iw (tril coef) ---
    {
      float4 k4a = *(const float4*)&k_pk[cl*4];
      float a0 = wsum64(qv*k4a.x);
      float a1 = wsum64(qv*k4a.y);
      float a2 = wsum64(qv*k4a.z);
      float a3 = wsum64(qv*k4a.w);
      if (cl == 0){
        float4 e4 = *(const float4*)&els[0];
        coefs[iw*4+0] = tik*e4.x*(a0+1.f);
        coefs[iw*4+1] = (iw>=1) ? tik*e4.y*(a1+1.f) : 0.f;
        coefs[iw*4+2] = (iw>=2) ? tik*e4.z*(a2+1.f) : 0.f;
        coefs[iw*4+3] = (iw>=3) ? tik*e4.w*(a3+1.f) : 0.f;
      }
    }
    // --- Z1 = k@W1+b1, qW1 = q@W1+b1 (register W1 column) ---
    float z1v0=b1r, z1v1=b1r, z1v2=b1r, z1v3=b1r;
    float qw0=b1r, qw1=b1r, qw2=b1r, qw3=b1r;
    #pragma unroll
    for (int d=0; d<64; d++){
      float4 k4 = *(const float4*)&k_pk[d*4];
      float4 q4 = *(const float4*)&q_pk[d*4];
      float w = w1r[d];
      z1v0 += k4.x*w; z1v1 += k4.y*w; z1v2 += k4.z*w; z1v3 += k4.w*w;
      qw0  += q4.x*w; qw1  += q4.y*w; qw2  += q4.z*w; qw3  += q4.w*w;
    }
    float x2o0 = geluf(z1v0), x2o1 = geluf(z1v1), x2o2 = geluf(z1v2), x2o3 = geluf(z1v3);
    { float4 t4; t4.x=x2o0; t4.y=x2o1; t4.z=x2o2; t4.w=x2o3;
      *(float4*)&x2_pk[j*4] = t4; }
    __syncthreads();                               // B
    // --- prefetch next step's q/k/v/eta (hidden under compute) ---
    float qn=0.f, kn=0.f, vn=0.f, eln=0.f;
    if (n < 63){
      int l2 = (n+1)*4 + iw;
      qn = xqp[(size_t)l2*256 + cl];
      kn = xkp[(size_t)l2*256 + cl];
      vn = xvp[(size_t)l2*256 + cl];
      if (j < 4) eln = ep[(n+1)*4 + j];
    }
    // --- Z2 partial: thread (iw,cl) covers d in [iw*64, iw*64+64) ---
    {
      float p0=0.f,p1=0.f,p2=0.f,p3=0.f;
      #pragma unroll
      for (int dd=0; dd<64; dd++){
        float4 x4 = *(const float4*)&x2_pk[(iw*64+dd)*4];
        float w = W2L[(iw*64+dd)*65 + cl];
        p0 += x4.x*w; p1 += x4.y*w; p2 += x4.z*w; p3 += x4.w*w;
      }
      pzs[cl*17 + 0*4 + iw] = p0;
      pzs[cl*17 + 1*4 + iw] = p1;
      pzs[cl*17 + 2*4 + iw] = p2;
      pzs[cl*17 + 3*4 + iw] = p3;
    }
    __syncthreads();                               // C
    float z2 = b2r + pzs[cl*17+iw*4] + pzs[cl*17+iw*4+1]
                   + pzs[cl*17+iw*4+2] + pzs[cl*17+iw*4+3];
    // --- fused LN-L2 backward (wave = minibatch row iw) ---
    float mu = wsum64(z2)*(1.f/64.f);
    float df = z2 - mu;
    float var = wsum64(df*df)*(1.f/64.f);
    float stdv = sqrtf(var + 1e-6f);
    float xhat = df/stdv;
    float tgt = vv - kv;
    float gxh = (gr*xhat + br - tgt)*gr;
    float sg1 = wsum64(gxh);
    float sg2 = wsum64(gxh*xhat);
    float gz2 = (64.f*gxh - sg1 - xhat*sg2)*(1.f/(64.f*stdv));
    gz2_pk[cl*4+iw] = gz2;
    __syncthreads();                               // D
    // --- gZ1 = (gZ2@W2^T)*gelu'(Z1) via register W2 row ---
    float gd0=0.f,gd1=0.f,gd2=0.f,gd3=0.f;
    #pragma unroll
    for (int c=0; c<64; c++){
      float4 g4 = *(const float4*)&gz2_pk[c*4];
      float w = w2rT[c];
      gd0 += g4.x*w; gd1 += g4.y*w; gd2 += g4.z*w; gd3 += g4.w*w;
    }
    float gz10 = gd0*gelu_bwdf(z1v0);
    float gz11 = gd1*gelu_bwdf(z1v1);
    float gz12 = gd2*gelu_bwdf(z1v2);
    float gz13 = gd3*gelu_bwdf(z1v3);
    float4 cf0 = *(const float4*)&coefs[0];
    float4 cf1 = *(const float4*)&coefs[4];
    float4 cf2 = *(const float4*)&coefs[8];
    float4 cf3 = *(const float4*)&coefs[12];
    float zb0 = qw0 - (cf0.x*gz10 + cf0.y*gz11 + cf0.z*gz12 + cf0.w*gz13);
    float zb1 = qw1 - (cf1.x*gz10 + cf1.y*gz11 + cf1.z*gz12 + cf1.w*gz13);
    float zb2 = qw2 - (cf2.x*gz10 + cf2.y*gz11 + cf2.z*gz12 + cf2.w*gz13);
    float zb3 = qw3 - (cf3.x*gz10 + cf3.y*gz11 + cf3.z*gz12 + cf3.w*gz13);
    float xb0 = geluf(zb0), xb1 = geluf(zb1), xb2 = geluf(zb2), xb3 = geluf(zb3);
    { float4 t4; t4.x=xb0; t4.y=xb1; t4.z=xb2; t4.w=xb3;
      *(float4*)&x2b_pk[j*4] = t4; }
    // --- A2 (masked r<=i), per-thread products + wave reduce ---
    {
      float s00 = wsum64(xb0*x2o0);
      float s10 = wsum64(xb1*x2o0);
      float s11 = wsum64(xb1*x2o1);
      float s20 = wsum64(xb2*x2o0);
      float s21 = wsum64(xb2*x2o1);
      float s22 = wsum64(xb2*x2o2);
      float s30 = wsum64(xb3*x2o0);
      float s31 = wsum64(xb3*x2o1);
      float s32 = wsum64(xb3*x2o2);
      float s33 = wsum64(xb3*x2o3);
      if (cl == 0){
        a2w[iw*16+0]  = s00;
        a2w[iw*16+4]  = s10; a2w[iw*16+5]  = s11;
        a2w[iw*16+8]  = s20; a2w[iw*16+9]  = s21; a2w[iw*16+10] = s22;
        a2w[iw*16+12] = s30; a2w[iw*16+13] = s31; a2w[iw*16+14] = s32; a2w[iw*16+15] = s33;
      }
    }
    __syncthreads();                               // E
    if (j < 16){
      int i2 = j >> 2, r2 = j & 3;
      float s = a2w[j] + a2w[16+j] + a2w[32+j] + a2w[48+j];
      coef2s[j] = (r2 <= i2) ? toks_s[i2]*els[r2]*(s + 1.f) : 0.f;
    }
    // --- Z2b partial ---
    {
      float p0=0.f,p1=0.f,p2=0.f,p3=0.f;
      #pragma unroll
      for (int dd=0; dd<64; dd++){
        float4 x4 = *(const float4*)&x2b_pk[(iw*64+dd)*4];
        float w = W2L[(iw*64+dd)*65 + cl];
        p0 += x4.x*w; p1 += x4.y*w; p2 += x4.z*w; p3 += x4.w*w;
      }
      pzs[cl*17 + 0*4 + iw] = p0;
      pzs[cl*17 + 1*4 + iw] = p1;
      pzs[cl*17 + 2*4 + iw] = p2;
      pzs[cl*17 + 3*4 + iw] = p3;
    }
    __syncthreads();                               // F
    float z2b = b2r + pzs[cl*17+iw*4] + pzs[cl*17+iw*4+1]
                    + pzs[cl*17+iw*4+2] + pzs[cl*17+iw*4+3];
    float4 g4r = *(const float4*)&gz2_pk[cl*4];
    {
      float4 c2 = *(const float4*)&coef2s[iw*4];
      z2b -= c2.x*g4r.x + c2.y*g4r.y + c2.z*g4r.z + c2.w*g4r.w;
    }
    float mu2 = wsum64(z2b)*(1.f/64.f);
    float df2 = z2b - mu2;
    float var2 = wsum64(df2*df2)*(1.f/64.f);
    float lnv = gr*df2*rsqrtf(var2 + 1e-6f) + br;
    out[((size_t)b*256 + n*4 + iw)*256 + h*64 + cl] = qv + lnv;
    // --- state updates ---
    float4 e4 = *(const float4*)&els[0];
    float le0 = tok3*e4.x, le1 = tok3*e4.y, le2 = tok3*e4.z, le3 = tok3*e4.w;
    float lg10 = le0*gz10, lg11 = le1*gz11, lg12 = le2*gz12, lg13 = le3*gz13;
    #pragma unroll
    for (int d=0; d<64; d++){
      float4 k4 = *(const float4*)&k_pk[d*4];
      w1r[d] -= lg10*k4.x + lg11*k4.y + lg12*k4.z + lg13*k4.w;
    }
    b1r -= lg10 + lg11 + lg12 + lg13;
    // W2 row update in registers, publish to LDS
    float lx0 = le0*xb0, lx1 = le1*xb1, lx2 = le2*xb2, lx3 = le3*xb3;
    #pragma unroll
    for (int c=0; c<64; c++){
      float4 g4 = *(const float4*)&gz2_pk[c*4];
      float wnew = w2rT[c] - (lx0*g4.x + lx1*g4.y + lx2*g4.z + lx3*g4.w);
      w2rT[c] = wnew;
      W2L[j*65 + c] = wnew;
    }
    b2r -= le0*g4r.x + le1*g4r.y + le2*g4r.z + le3*g4r.w;
    __syncthreads();                               // G
    qv = qn; kv = kn; vv = vn; elv = eln;
  }
}

// Fused head: LN(post) -> @wo -> LN(ln) -> fc1 -> fc2 -> fc3. grid 512 rows.
__global__ __launch_bounds__(256) void k_head(const float* __restrict__ hid2,
    const float* __restrict__ pg, const float* __restrict__ pb,
    const float* __restrict__ wo, const float* __restrict__ lg,
    const float* __restrict__ lb, const float* __restrict__ fcw,
    const float* __restrict__ fcb, const float* __restrict__ fc2w,
    const float* __restrict__ fc2b, const float* __restrict__ fc3w,
    const float* __restrict__ fc3b, float* __restrict__ outp){
  int row = blockIdx.x, c = threadIdx.x;
  __shared__ float t1[256];
  __shared__ float t3[256];
  __shared__ float t4[128];
  __shared__ float t5[64];
  __shared__ float rs[4];
  __shared__ float rq[4];
  int wv = c >> 6, ln = c & 63;
  float v = hid2[(size_t)row*256 + c];
  float s1 = wsum64(v), s2 = wsum64(v*v);
  if (ln == 0){ rs[wv]=s1; rq[wv]=s2; }
  __syncthreads();
  float mu = (rs[0]+rs[1]+rs[2]+rs[3])*(1.f/256.f);
  float msq = (rq[0]+rq[1]+rq[2]+rq[3])*(1.f/256.f);
  float var = msq - mu*mu;
  t1[c] = (v-mu)*rsqrtf(var + 1e-5f)*pg[c] + pb[c];
  __syncthreads();
  float a = 0.f;
  for (int k=0;k<256;k++) a += t1[k]*wo[(size_t)k*256 + c];
  float u1 = wsum64(a), u2 = wsum64(a*a);
  if (ln == 0){ rs[wv]=u1; rq[wv]=u2; }
  __syncthreads();
  mu = (rs[0]+rs[1]+rs[2]+rs[3])*(1.f/256.f);
  msq = (rq[0]+rq[1]+rq[2]+rq[3])*(1.f/256.f);
  var = msq - mu*mu;
  t3[c] = (a-mu)*rsqrtf(var + 1e-5f)*lg[c] + lb[c];
  __syncthreads();
  if (c < 128){
    float s = fcb[c];
    for (int k=0;k<256;k++) s += t3[k]*fcw[(size_t)k*128 + c];
    t4[c] = s;
  }
  __syncthreads();
  if (c < 64){
    float s = fc2b[c];
    for (int k=0;k<128;k++) s += t4[k]*fc2w[(size_t)k*64 + c];
    t5[c] = s;
  }
  __syncthreads();
  if (c < 64){
    float p = t5[c]*fc3w[c];
    p = wsum64(p);
    if (c == 0) outp[row] = p + fc3b[0];
  }
}

extern "C" void kernel_launch(void* const* d_in, const int* in_sizes, int n_in,
                              void* d_out, int out_size, void* d_ws, size_t ws_size,
                              hipStream_t stream){
  (void)in_sizes; (void)n_in; (void)out_size; (void)ws_size;
  const float* x       = (const float*)d_in[0];
  const float* s11_w   = (const float*)d_in[1];
  const float* s11_b   = (const float*)d_in[2];
  const float* bn11    = (const float*)d_in[3];
  const float* s12_w   = (const float*)d_in[4];
  const float* s12_b   = (const float*)d_in[5];
  const float* bn12    = (const float*)d_in[6];
  const float* s21_w   = (const float*)d_in[7];
  const float* s21_b   = (const float*)d_in[8];
  const float* bn21    = (const float*)d_in[9];
  const float* s22_w   = (const float*)d_in[10];
  const float* s22_b   = (const float*)d_in[11];
  const float* bn22    = (const float*)d_in[12];
  const float* s3_w    = (const float*)d_in[13];
  const float* s3_b    = (const float*)d_in[14];
  const float* bn3     = (const float*)d_in[15];
  const float* c1_w    = (const float*)d_in[16];
  const float* c1_b    = (const float*)d_in[17];
  const float* cb_w    = (const float*)d_in[18];
  const float* cb_b    = (const float*)d_in[19];
  const float* ln_g    = (const float*)d_in[20];
  const float* ln_b    = (const float*)d_in[21];
  const float* wq      = (const float*)d_in[22];
  const float* wk      = (const float*)d_in[23];
  const float* wv      = (const float*)d_in[24];
  const float* wo      = (const float*)d_in[25];
  const float* lr_w    = (const float*)d_in[26];
  const float* lr_b    = (const float*)d_in[27];
  const float* tib     = (const float*)d_in[28];
  const float* tlnw    = (const float*)d_in[29];
  const float* tlnb    = (const float*)d_in[30];
  const float* W1      = (const float*)d_in[31];
  const float* B1      = (const float*)d_in[32];
  const float* W2      = (const float*)d_in[33];
  const float* B2      = (const float*)d_in[34];
  const float* post_g  = (const float*)d_in[35];
  const float* post_b  = (const float*)d_in[36];
  const float* fc_w    = (const float*)d_in[37];
  const float* fc_b    = (const float*)d_in[38];
  const float* fc2_w   = (const float*)d_in[39];
  const float* fc2_b   = (const float*)d_in[40];
  const float* fc3_w   = (const float*)d_in[41];
  const float* fc3_b   = (const float*)d_in[42];

  float* ws = (float*)d_ws;
  float* xs   = ws;                       // 2359296
  float* xd   = ws + 2359296;             // 2359296
  float* p1   = ws + 4718592;             // 1179648
  float* p2   = ws + 5898240;             // 1179648
  float* sig  = ws + 7077888;             // 32768
  float* buf0 = ws + 7110656;             // 131072
  float* buf1 = ws + 7241728;             // 131072
  float* accb = ws + 7372800;             // 131072
  float* hid  = ws + 7503872;             // 131072
  float* xqb  = ws + 7634944;             // 131072
  float* xkb  = ws + 7766016;             // 131072
  float* xvb  = ws + 7897088;             // 131072
  float* eta  = ws + 8028160;             // 2048
  float* hid2 = ws + 8030208;             // 131072

  k_s11<<<1536, 192, 0, stream>>>(x, s11_w, s11_b, bn11, xs);
  k_s12<<<1536, 192, 0, stream>>>(x, s12_w, s12_b, bn12, xd);
  k_s2x<<<512, 256, 0, stream>>>(xs, xd, s21_w, s21_b, bn21, p1);
  k_s2x<<<512, 256, 0, stream>>>(xd, xd, s22_w, s22_b, bn22, p2);
  k_s3<<<512, 256, 0, stream>>>(p1, p2, s3_w, s3_b, bn3, sig);
  k_c1<<<512, 256, 0, stream>>>(sig, c1_w, c1_b, buf0);
  {
    float* cin = buf0; float* cout = buf1;
    for (int l=0; l<8; l++){
      int mode = (l == 1) ? 1 : ((l & 1) ? 2 : 0);
      k_conv1d<<<256, 256, 0, stream>>>(cin, cb_w + (size_t)l*196608,
                                        cb_b + l*256, cout, accb, mode);
      float* tmp = cin; cin = cout; cout = tmp;
    }
  }
  k_ln_tr<<<512, 256, 0, stream>>>(accb, ln_g, ln_b, hid);
  k_proj<<<1536, 256, 0, stream>>>(hid, wq, wk, wv, xqb, xkb, xvb);
  k_eta<<<8, 256, 0, stream>>>(hid, lr_w, lr_b, eta);
  k_ttt<<<8, 256, 0, stream>>>(xqb, xkb, xvb, eta, tib, tlnw, tlnb,
                               W1, B1, W2, B2, hid2);
  k_head<<<512, 256, 0, stream>>>(hid2, post_g, post_b, wo, ln_g, ln_b,
                                  fc_w, fc_b, fc2_w, fc2_b, fc3_w, fc3_b,
                                  (float*)d_out);
}

// Round 5
// 3295.054 us; speedup vs baseline: 1.1883x; 1.0867x over previous
//
#include <hip/hip_runtime.h>
#include <hip/hip_bf16.h>
#include <math.h>

#define DEV __device__ __forceinline__

DEV float wsum64(float v){
  #pragma unroll
  for (int off = 32; off; off >>= 1) v += __shfl_xor(v, off, 64);
  return v;
}
DEV float geluf(float x){
  return 0.5f*x*(1.f + tanhf(0.7978845608028654f*(x + 0.044715f*x*x*x)));
}
DEV float gelu_bwdf(float x){
  float x2 = x*x;
  float t = tanhf(0.79788456f*x*(1.f + 0.044715f*x2));
  return 0.5f*x*((1.f - t*t)*(0.79788456f + 0.1070322243f*x2)) + 0.5f*(1.f + t);
}
DEV float sigmf(float x){ return 1.f/(1.f + expf(-x)); }

// ---------------------------------------------------------------------------
// Stem s11: x[512,3,96,96] -> conv7x7 s2 p3 -> BN -> ReLU -> pool2 -> xs[512,8,24,24]
__global__ __launch_bounds__(192) void k_s11(const float* __restrict__ x,
    const float* __restrict__ w, const float* __restrict__ bias,
    const float* __restrict__ bn, float* __restrict__ xs){
  __shared__ float st[3*37*2*53];   // 11766 floats
  __shared__ float wl[49*3*8];      // 1176
  int bx = blockIdx.x;
  int bd = bx / 3, g = bx - bd*3;
  int t = threadIdx.x;
  for (int e = t; e < 1176; e += 192){
    int tap = e / 24, r = e - tap*24, ci = r >> 3, c = r & 7;
    wl[e] = w[(c*3 + ci)*49 + tap];
  }
  const float* xb = x + (size_t)bd*3*9216;
  for (int e = t; e < 3*37*102; e += 192){
    int ci = e / 3774, r2 = e - ci*3774;
    int ihl = r2 / 102, pi = r2 - ihl*102;
    int ih = ihl + 32*g - 3, iw = pi - 3;
    float v = 0.f;
    if (ih>=0 && ih<96 && iw>=0 && iw<96) v = xb[(size_t)ci*9216 + ih*96 + iw];
    st[((ci*37 + ihl)*2 + (pi&1))*53 + (pi>>1)] = v;
  }
  __syncthreads();
  int pr = t / 24, pc = t - pr*24;
  float a00[8], a01[8], a10[8], a11[8];
  #pragma unroll
  for (int c=0;c<8;c++){ a00[c]=0.f; a01[c]=0.f; a10[c]=0.f; a11[c]=0.f; }
  for (int ci=0; ci<3; ci++){
    for (int kh=0; kh<7; kh++){
      int rb0 = (ci*37 + 4*pr + kh)*106 + 2*pc;
      int rb1 = rb0 + 212;
      #pragma unroll
      for (int kw=0; kw<7; kw++){
        int off = (kw&1)*53 + (kw>>1);
        float v00 = st[rb0+off], v01 = st[rb0+off+1];
        float v10 = st[rb1+off], v11 = st[rb1+off+1];
        const float4* wp = (const float4*)&wl[((kh*7+kw)*3 + ci)*8];
        float wv[8];
        *(float4*)&wv[0] = wp[0]; *(float4*)&wv[4] = wp[1];
        #pragma unroll
        for (int c=0;c<8;c++){
          a00[c] += v00*wv[c]; a01[c] += v01*wv[c];
          a10[c] += v10*wv[c]; a11[c] += v11*wv[c];
        }
      }
    }
  }
  int pos = (g*8 + pr)*24 + pc;
  #pragma unroll
  for (int c=0;c<8;c++){
    float gg=bn[c], be=bn[8+c], m=bn[16+c], vv=bn[24+c];
    float s = gg*rsqrtf(vv + 1e-5f);
    float bi = bias[c];
    float mx = 0.f;
    mx = fmaxf(mx, (a00[c]+bi-m)*s+be);
    mx = fmaxf(mx, (a01[c]+bi-m)*s+be);
    mx = fmaxf(mx, (a10[c]+bi-m)*s+be);
    mx = fmaxf(mx, (a11[c]+bi-m)*s+be);
    xs[((size_t)bd*8 + c)*576 + pos] = mx;
  }
}

// Stem s12: same structure on frame-diffs (4 groups of 3 channels, diff at staging).
__global__ __launch_bounds__(192) void k_s12(const float* __restrict__ x,
    const float* __restrict__ w, const float* __restrict__ bias,
    const float* __restrict__ bn, float* __restrict__ xd){
  __shared__ float st[3*37*2*53];
  __shared__ float wl[49*12*8];     // 4704
  int bx = blockIdx.x;
  int bd = bx / 3, g = bx - bd*3;
  int b = bd >> 8, dd = bd & 255;
  int t = threadIdx.x;
  for (int e = t; e < 4704; e += 192){
    int tap = e / 96, r = e - tap*96, ci = r >> 3, c = r & 7;
    wl[e] = w[(c*12 + ci)*49 + tap];
  }
  int fa[4], fb[4];
  fa[0] = dd>=2 ? dd-1 : 0;     fb[0] = dd>=2 ? dd-2 : 0;
  fa[1] = dd;                   fb[1] = dd>=1 ? dd-1 : 0;
  fa[2] = dd<=254 ? dd+1 : 255; fb[2] = dd;
  fa[3] = dd<=253 ? dd+2 : 255; fb[3] = dd<=254 ? dd+1 : 255;
  int pr = t / 24, pc = t - pr*24;
  float a00[8], a01[8], a10[8], a11[8];
  #pragma unroll
  for (int c=0;c<8;c++){ a00[c]=0.f; a01[c]=0.f; a10[c]=0.f; a11[c]=0.f; }
  for (int g4=0; g4<4; g4++){
    if (fa[g4] == fb[g4]) continue;   // zero diff, uniform per block
    __syncthreads();
    const float* xa = x + ((size_t)(b*256 + fa[g4]))*3*9216;
    const float* xbp= x + ((size_t)(b*256 + fb[g4]))*3*9216;
    for (int e = t; e < 3*37*102; e += 192){
      int ci = e / 3774, r2 = e - ci*3774;
      int ihl = r2 / 102, pi = r2 - ihl*102;
      int ih = ihl + 32*g - 3, iw = pi - 3;
      float v = 0.f;
      if (ih>=0 && ih<96 && iw>=0 && iw<96){
        size_t off = (size_t)ci*9216 + ih*96 + iw;
        v = xa[off] - xbp[off];
      }
      st[((ci*37 + ihl)*2 + (pi&1))*53 + (pi>>1)] = v;
    }
    __syncthreads();
    for (int ci=0; ci<3; ci++){
      int gch = g4*3 + ci;
      for (int kh=0; kh<7; kh++){
        int rb0 = (ci*37 + 4*pr + kh)*106 + 2*pc;
        int rb1 = rb0 + 212;
        #pragma unroll
        for (int kw=0; kw<7; kw++){
          int off = (kw&1)*53 + (kw>>1);
          float v00 = st[rb0+off], v01 = st[rb0+off+1];
          float v10 = st[rb1+off], v11 = st[rb1+off+1];
          const float4* wp = (const float4*)&wl[((kh*7+kw)*12 + gch)*8];
          float wv[8];
          *(float4*)&wv[0] = wp[0]; *(float4*)&wv[4] = wp[1];
          #pragma unroll
          for (int c=0;c<8;c++){
            a00[c] += v00*wv[c]; a01[c] += v01*wv[c];
            a10[c] += v10*wv[c]; a11[c] += v11*wv[c];
          }
        }
      }
    }
  }
  int pos = (g*8 + pr)*24 + pc;
  #pragma unroll
  for (int c=0;c<8;c++){
    float gg=bn[c], be=bn[8+c], m=bn[16+c], vv=bn[24+c];
    float s = gg*rsqrtf(vv + 1e-5f);
    float bi = bias[c];
    float mx = 0.f;
    mx = fmaxf(mx, (a00[c]+bi-m)*s+be);
    mx = fmaxf(mx, (a01[c]+bi-m)*s+be);
    mx = fmaxf(mx, (a10[c]+bi-m)*s+be);
    mx = fmaxf(mx, (a11[c]+bi-m)*s+be);
    xd[((size_t)bd*8 + c)*576 + pos] = mx;
  }
}

// s21/s22: in = 0.5*(A+B) [512,8,24,24] -> conv7x7 s1 p3 -> BN relu pool -> [512,16,12,12]
__global__ __launch_bounds__(256) void k_s2x(const float* __restrict__ inA,
    const float* __restrict__ inB, const float* __restrict__ w,
    const float* __restrict__ bias, const float* __restrict__ bn,
    float* __restrict__ outp){
  __shared__ float st[8*30*33];     // 7920
  __shared__ float wl[49*8*16];     // 6272
  int bd = blockIdx.x;
  int t = threadIdx.x;
  for (int e = t; e < 6272; e += 256){
    int tap = e >> 7, r = e & 127, ci = r >> 4, c = r & 15;
    wl[e] = w[(c*8 + ci)*49 + tap];
  }
  const float* pa = inA + (size_t)bd*8*576;
  const float* pb = inB + (size_t)bd*8*576;
  for (int e = t; e < 7920; e += 256){
    int ci = e / 990, r2 = e - ci*990;
    int r = r2 / 33, cc = r2 - r*33;
    int ih = r - 3, iw = cc - 3;
    float v = 0.f;
    if (ih>=0 && ih<24 && iw>=0 && iw<24){
      int off = ci*576 + ih*24 + iw;
      v = 0.5f*(pa[off] + pb[off]);
    }
    st[(ci*30 + r)*33 + cc] = v;
  }
  __syncthreads();
  if (t < 144){
    int pr = t / 12, pc = t - pr*12;
    float a00[16], a01[16], a10[16], a11[16];
    #pragma unroll
    for (int c=0;c<16;c++){ a00[c]=0.f; a01[c]=0.f; a10[c]=0.f; a11[c]=0.f; }
    for (int ci=0; ci<8; ci++){
      for (int kh=0; kh<7; kh++){
        int rb = (ci*30 + 2*pr + kh)*33 + 2*pc;
        #pragma unroll
        for (int kw=0; kw<7; kw++){
          float v00 = st[rb+kw],    v01 = st[rb+kw+1];
          float v10 = st[rb+33+kw], v11 = st[rb+34+kw];
          const float4* wp = (const float4*)&wl[((kh*7+kw)*8 + ci)*16];
          float wv[16];
          *(float4*)&wv[0]  = wp[0]; *(float4*)&wv[4]  = wp[1];
          *(float4*)&wv[8]  = wp[2]; *(float4*)&wv[12] = wp[3];
          #pragma unroll
          for (int c=0;c<16;c++){
            a00[c] += v00*wv[c]; a01[c] += v01*wv[c];
            a10[c] += v10*wv[c]; a11[c] += v11*wv[c];
          }
        }
      }
    }
    #pragma unroll
    for (int c=0;c<16;c++){
      float gg=bn[c], be=bn[16+c], m=bn[32+c], vv=bn[48+c];
      float s = gg*rsqrtf(vv + 1e-5f);
      float bi = bias[c];
      float mx = 0.f;
      mx = fmaxf(mx, (a00[c]+bi-m)*s+be);
      mx = fmaxf(mx, (a01[c]+bi-m)*s+be);
      mx = fmaxf(mx, (a10[c]+bi-m)*s+be);
      mx = fmaxf(mx, (a11[c]+bi-m)*s+be);
      outp[((size_t)bd*16 + c)*144 + pr*12 + pc] = mx;
    }
  }
}

// s3 conv3x3 p1 + BN + attention-mask pooled signal. block per bd. -> sig[512,64]
__global__ __launch_bounds__(256) void k_s3(const float* __restrict__ p1,
    const float* __restrict__ p2, const float* __restrict__ w,
    const float* __restrict__ bias, const float* __restrict__ bn,
    float* __restrict__ sig){
  __shared__ float ins[16*14*14];
  __shared__ float wT[144*64];
  __shared__ float redS[64*4];
  __shared__ float redF[64*4];
  int bd = blockIdx.x;
  int t = threadIdx.x;
  for (int i = t; i < 16*196; i += 256){
    int ci = i/196, r = i - ci*196, y = r/14, xx = r - y*14;
    float v = 0.f;
    if (y>=1 && y<=12 && xx>=1 && xx<=12){
      size_t idx = ((size_t)bd*16 + ci)*144 + (y-1)*12 + (xx-1);
      v = 0.5f*(p1[idx] + p2[idx]);
    }
    ins[i] = v;
  }
  for (int i = t; i < 9216; i += 256){
    int c = i & 63, k = i >> 6;
    wT[i] = w[c*144 + k];
  }
  __syncthreads();
  int c = t & 63, pg = t >> 6;
  float acc[36];
  #pragma unroll
  for (int pp=0;pp<36;pp++) acc[pp]=0.f;
  for (int k=0; k<144; k++){
    int ci = k/9, kk = k - ci*9, kh = kk/3, kw = kk - kh*3;
    float wv = wT[k*64 + c];
    const float* ip = &ins[ci*196];
    #pragma unroll
    for (int pp=0;pp<36;pp++){
      int y = pg*3 + pp/12, xx = pp%12;
      acc[pp] += ip[(y+kh)*14 + (xx+kw)] * wv;
    }
  }
  float g=bn[c], be=bn[64+c], m=bn[128+c], vv=bn[192+c];
  float s = g*rsqrtf(vv + 1e-5f);
  float bi = bias[c];
  float sS = 0.f, sF = 0.f;
  #pragma unroll
  for (int pp=0;pp<36;pp++){
    float f = (acc[pp] + bi - m)*s + be;
    float sg = sigmf(f);
    sS += sg; sF += f*sg;
  }
  redS[c*4+pg] = sS; redF[c*4+pg] = sF;
  __syncthreads();
  if (t < 64){
    float S = redS[t*4]+redS[t*4+1]+redS[t*4+2]+redS[t*4+3];
    float F = redF[t*4]+redF[t*4+1]+redF[t*4+2]+redF[t*4+3];
    sig[(size_t)bd*64 + t] = 0.5f*F/S;
  }
}

// c1 1x1 conv: sig[b,t,64] -> h[b,256,256] (channel-major). block=(b,o). grid 512.
__global__ __launch_bounds__(256) void k_c1(const float* __restrict__ sig,
    const float* __restrict__ w, const float* __restrict__ bias,
    float* __restrict__ h){
  int b = blockIdx.x >> 8, o = blockIdx.x & 255, tt = threadIdx.x;
  __shared__ float wl[64];
  if (tt < 64) wl[tt] = w[o*64 + tt];
  __syncthreads();
  const float4* sp = (const float4*)(sig + ((size_t)(b*256 + tt))*64);
  const float4* wp = (const float4*)wl;
  float a = bias[o];
  #pragma unroll
  for (int i=0;i<16;i++){
    float4 s4 = sp[i]; float4 w4 = wp[i];
    a += s4.x*w4.x + s4.y*w4.y + s4.z*w4.z + s4.w*w4.w;
  }
  h[((size_t)b*256 + o)*256 + tt] = fmaxf(a, 0.f);
}

// conv1d 256->256 k3 p1 + relu. mode: 0=none 1=acc:=out 2=acc+=out. grid 256.
__global__ __launch_bounds__(256) void k_conv1d(const float* __restrict__ hin,
    const float* __restrict__ w, const float* __restrict__ bias,
    float* __restrict__ hout, float* __restrict__ accb, int mode){
  __shared__ float ins[256*34];
  __shared__ float ws[16*256*4];   // padded stride-4 taps
  int bx = blockIdx.x;
  int b = bx >> 7;
  int rem = bx & 127;
  int og = rem >> 3;
  int tg = rem & 7;
  int tid = threadIdx.x;
  int t0 = tg*32;
  for (int idx = tid; idx < 256*34; idx += 256){
    int ii = idx/34, jj = idx - ii*34;
    int tglob = t0 - 1 + jj;
    float v = 0.f;
    if (tglob >= 0 && tglob < 256) v = hin[((size_t)b*256 + ii)*256 + tglob];
    ins[idx] = v;
  }
  for (int idx = tid; idx < 12288; idx += 256){
    int q = idx/3;
    ws[q*4 + (idx - q*3)] = w[(size_t)og*12288 + idx];
  }
  __syncthreads();
  int ol = tid >> 5, tl = tid & 31;
  int o1 = og*16 + ol, o2 = o1 + 8;
  float a1 = bias[o1], a2 = bias[o2];
  const float4* w1q = (const float4*)(ws + (size_t)ol*1024);
  const float4* w2q = (const float4*)(ws + (size_t)(ol+8)*1024);
  for (int i=0;i<256;i++){
    float v0 = ins[i*34 + tl];
    float v1 = ins[i*34 + tl + 1];
    float v2 = ins[i*34 + tl + 2];
    float4 wa = w1q[i];
    float4 wb = w2q[i];
    a1 += wa.x*v0 + wa.y*v1 + wa.z*v2;
    a2 += wb.x*v0 + wb.y*v1 + wb.z*v2;
  }
  a1 = fmaxf(a1, 0.f); a2 = fmaxf(a2, 0.f);
  size_t i1 = ((size_t)b*256 + o1)*256 + t0 + tl;
  size_t i2 = ((size_t)b*256 + o2)*256 + t0 + tl;
  hout[i1] = a1; hout[i2] = a2;
  if (mode == 1){ accb[i1] = a1; accb[i2] = a2; }
  else if (mode == 2){ accb[i1] += a1; accb[i2] += a2; }
}

// acc[b,c,t] -> transpose + LN(ln_g,ln_b) -> hid[(b t),c]. grid 512.
__global__ __launch_bounds__(256) void k_ln_tr(const float* __restrict__ acc,
    const float* __restrict__ g, const float* __restrict__ be,
    float* __restrict__ hid){
  int b = blockIdx.x >> 8, tt = blockIdx.x & 255, c = threadIdx.x;
  __shared__ float rs[4];
  __shared__ float rq[4];
  float v = acc[((size_t)b*256 + c)*256 + tt];
  float s1 = wsum64(v), s2 = wsum64(v*v);
  int wv = c >> 6, ln = c & 63;
  if (ln == 0){ rs[wv]=s1; rq[wv]=s2; }
  __syncthreads();
  float mu = (rs[0]+rs[1]+rs[2]+rs[3])*(1.f/256.f);
  float msq = (rq[0]+rq[1]+rq[2]+rq[3])*(1.f/256.f);
  float var = msq - mu*mu;
  hid[(size_t)blockIdx.x*256 + c] = (v-mu)*rsqrtf(var + 1e-5f)*g[c] + be[c];
}

// projections hid @ {wq,wk,wv}. grid 1536.
__global__ __launch_bounds__(256) void k_proj(const float* __restrict__ hid,
    const float* __restrict__ wq, const float* __restrict__ wk,
    const float* __restrict__ wv, float* __restrict__ xq,
    float* __restrict__ xk, float* __restrict__ xv){
  int m = blockIdx.x >> 9, row = blockIdx.x & 511, c = threadIdx.x;
  const float* W = (m==0) ? wq : ((m==1) ? wk : wv);
  float* O = (m==0) ? xq : ((m==1) ? xk : xv);
  __shared__ float hrow[256];
  hrow[c] = hid[(size_t)row*256 + c];
  __syncthreads();
  float a = 0.f;
  for (int k=0;k<256;k++) a += hrow[k]*W[(size_t)k*256 + c];
  O[(size_t)row*256 + c] = a;
}

// eta_lr (scaled): 0.1*sigmoid(hid.lr_w + lr_b)/64. grid 8 (b*4+h).
__global__ __launch_bounds__(256) void k_eta(const float* __restrict__ hid,
    const float* __restrict__ lrw, const float* __restrict__ lrb,
    float* __restrict__ etalr){
  int b = blockIdx.x >> 2, h = blockIdx.x & 3, l = threadIdx.x;
  const float* hp = hid + ((size_t)(b*256 + l))*256;
  float a = lrb[h];
  for (int k=0;k<256;k++) a += hp[k]*lrw[h*256 + k];
  etalr[(size_t)blockIdx.x*256 + l] = 0.1f*sigmf(a)*(1.f/64.f);
}

// TTT-MLP scan. One block per (b,h). LDS-resident weights (no big reg arrays):
// W1s[d][j] (owner-column access), W2L[r][c] pitch 65 (conflict-free cols/rows),
// packed [d][i] float4 activations, split-K Z2/Z2b, shuffle-reduced A1/A2.
__global__ __launch_bounds__(256) void k_ttt(
    const float* __restrict__ xq, const float* __restrict__ xk,
    const float* __restrict__ xv, const float* __restrict__ etalr,
    const float* __restrict__ tib, const float* __restrict__ lnw,
    const float* __restrict__ lnb, const float* __restrict__ W1g,
    const float* __restrict__ B1g, const float* __restrict__ W2g,
    const float* __restrict__ B2g, float* __restrict__ out){
  __shared__ float W1s[64*256];                // [d][j]
  __shared__ float W2L[256*65];                // [r][c], pitch 65
  __shared__ __align__(16) float k_pk[256];    // [d=64][i=4]
  __shared__ __align__(16) float q_pk[256];
  __shared__ __align__(16) float x2_pk[1024];  // [d=256][i=4]
  __shared__ __align__(16) float x2b_pk[1024];
  __shared__ __align__(16) float gz2_pk[256];  // [c=64][i=4]
  __shared__ float pzs[64*17];                 // partial dots [cl][i*4+iw]
  __shared__ float a2w[64];
  __shared__ __align__(16) float coefs[16];
  __shared__ __align__(16) float coef2s[16];
  __shared__ __align__(16) float els[4];
  __shared__ float toks_s[4];

  int b = blockIdx.x >> 2, h = blockIdx.x & 3;
  int j = threadIdx.x;
  int iw = j >> 6, cl = j & 63;

  const float* W1b = W1g + (size_t)h*16384;
  const float* W2b = W2g + (size_t)h*16384;
  for (int i=j; i<16384; i+=256) W1s[i] = W1b[i];
  for (int i=j; i<16384; i+=256){
    int r = i >> 6, c = i & 63;
    W2L[r*65 + c] = W2b[i];
  }
  float b1r = B1g[h*256 + j];
  float b2r = B2g[h*64 + cl];
  float gr = lnw[h*64 + cl], br = lnb[h*64 + cl];
  if (j < 4) toks_s[j] = fmaxf(1.f/(float)(j+1) + tib[j], 0.f);
  __syncthreads();
  float tok3 = toks_s[3];
  float tik = toks_s[iw];

  const float* xqp = xq + (size_t)b*65536 + h*64;
  const float* xkp = xk + (size_t)b*65536 + h*64;
  const float* xvp = xv + (size_t)b*65536 + h*64;
  const float* ep  = etalr + (size_t)(b*4 + h)*256;

  float qv = xqp[(size_t)iw*256 + cl];
  float kv = xkp[(size_t)iw*256 + cl];
  float vv = xvp[(size_t)iw*256 + cl];
  float elv = (j < 4) ? ep[j] : 0.f;

  for (int n=0; n<64; n++){
    k_pk[cl*4+iw] = kv;
    q_pk[cl*4+iw] = qv;
    if (j < 4) els[j] = elv;
    __syncthreads();                               // A
    // --- A1 row iw (tril coef) ---
    {
      float4 k4a = *(const float4*)&k_pk[cl*4];
      float a0 = wsum64(qv*k4a.x);
      float a1 = wsum64(qv*k4a.y);
      float a2 = wsum64(qv*k4a.z);
      float a3 = wsum64(qv*k4a.w);
      if (cl == 0){
        float4 e4 = *(const float4*)&els[0];
        coefs[iw*4+0] = tik*e4.x*(a0+1.f);
        coefs[iw*4+1] = (iw>=1) ? tik*e4.y*(a1+1.f) : 0.f;
        coefs[iw*4+2] = (iw>=2) ? tik*e4.z*(a2+1.f) : 0.f;
        coefs[iw*4+3] = (iw>=3) ? tik*e4.w*(a3+1.f) : 0.f;
      }
    }
    // --- Z1 = k@W1+b1, qW1 = q@W1+b1 (LDS W1 column, conflict-free) ---
    float z1v0=b1r, z1v1=b1r, z1v2=b1r, z1v3=b1r;
    float qw0=b1r, qw1=b1r, qw2=b1r, qw3=b1r;
    #pragma unroll
    for (int d=0; d<64; d++){
      float4 k4 = *(const float4*)&k_pk[d*4];
      float4 q4 = *(const float4*)&q_pk[d*4];
      float w = W1s[d*256 + j];
      z1v0 += k4.x*w; z1v1 += k4.y*w; z1v2 += k4.z*w; z1v3 += k4.w*w;
      qw0  += q4.x*w; qw1  += q4.y*w; qw2  += q4.z*w; qw3  += q4.w*w;
    }
    float x2o0 = geluf(z1v0), x2o1 = geluf(z1v1), x2o2 = geluf(z1v2), x2o3 = geluf(z1v3);
    { float4 t4; t4.x=x2o0; t4.y=x2o1; t4.z=x2o2; t4.w=x2o3;
      *(float4*)&x2_pk[j*4] = t4; }
    __syncthreads();                               // B
    // --- prefetch next step's q/k/v/eta (hidden under compute) ---
    float qn=0.f, kn=0.f, vn=0.f, eln=0.f;
    if (n < 63){
      int l2 = (n+1)*4 + iw;
      qn = xqp[(size_t)l2*256 + cl];
      kn = xkp[(size_t)l2*256 + cl];
      vn = xvp[(size_t)l2*256 + cl];
      if (j < 4) eln = ep[(n+1)*4 + j];
    }
    // --- Z2 partial: thread (iw,cl) covers d in [iw*64, iw*64+64) ---
    {
      float p0=0.f,p1=0.f,p2=0.f,p3=0.f;
      #pragma unroll
      for (int dd=0; dd<64; dd++){
        float4 x4 = *(const float4*)&x2_pk[(iw*64+dd)*4];
        float w = W2L[(iw*64+dd)*65 + cl];
        p0 += x4.x*w; p1 += x4.y*w; p2 += x4.z*w; p3 += x4.w*w;
      }
      pzs[cl*17 + 0*4 + iw] = p0;
      pzs[cl*17 + 1*4 + iw] = p1;
      pzs[cl*17 + 2*4 + iw] = p2;
      pzs[cl*17 + 3*4 + iw] = p3;
    }
    __syncthreads();                               // C
    float z2 = b2r + pzs[cl*17+iw*4] + pzs[cl*17+iw*4+1]
                   + pzs[cl*17+iw*4+2] + pzs[cl*17+iw*4+3];
    // --- fused LN-L2 backward (wave = minibatch row iw) ---
    float mu = wsum64(z2)*(1.f/64.f);
    float df = z2 - mu;
    float var = wsum64(df*df)*(1.f/64.f);
    float stdv = sqrtf(var + 1e-6f);
    float xhat = df/stdv;
    float tgt = vv - kv;
    float gxh = (gr*xhat + br - tgt)*gr;
    float sg1 = wsum64(gxh);
    float sg2 = wsum64(gxh*xhat);
    float gz2 = (64.f*gxh - sg1 - xhat*sg2)*(1.f/(64.f*stdv));
    gz2_pk[cl*4+iw] = gz2;
    __syncthreads();                               // D
    // --- gZ1 = (gZ2@W2^T)*gelu'(Z1) via LDS W2 row j (conflict-free) ---
    float gd0=0.f,gd1=0.f,gd2=0.f,gd3=0.f;
    #pragma unroll
    for (int c=0; c<64; c++){
      float4 g4 = *(const float4*)&gz2_pk[c*4];
      float w = W2L[j*65 + c];
      gd0 += g4.x*w; gd1 += g4.y*w; gd2 += g4.z*w; gd3 += g4.w*w;
    }
    float gz10 = gd0*gelu_bwdf(z1v0);
    float gz11 = gd1*gelu_bwdf(z1v1);
    float gz12 = gd2*gelu_bwdf(z1v2);
    float gz13 = gd3*gelu_bwdf(z1v3);
    float4 cf0 = *(const float4*)&coefs[0];
    float4 cf1 = *(const float4*)&coefs[4];
    float4 cf2 = *(const float4*)&coefs[8];
    float4 cf3 = *(const float4*)&coefs[12];
    float zb0 = qw0 - (cf0.x*gz10 + cf0.y*gz11 + cf0.z*gz12 + cf0.w*gz13);
    float zb1 = qw1 - (cf1.x*gz10 + cf1.y*gz11 + cf1.z*gz12 + cf1.w*gz13);
    float zb2 = qw2 - (cf2.x*gz10 + cf2.y*gz11 + cf2.z*gz12 + cf2.w*gz13);
    float zb3 = qw3 - (cf3.x*gz10 + cf3.y*gz11 + cf3.z*gz12 + cf3.w*gz13);
    float xb0 = geluf(zb0), xb1 = geluf(zb1), xb2 = geluf(zb2), xb3 = geluf(zb3);
    { float4 t4; t4.x=xb0; t4.y=xb1; t4.z=xb2; t4.w=xb3;
      *(float4*)&x2b_pk[j*4] = t4; }
    // --- A2 (masked r<=i), per-thread products + wave reduce ---
    {
      float s00 = wsum64(xb0*x2o0);
      float s10 = wsum64(xb1*x2o0);
      float s11 = wsum64(xb1*x2o1);
      float s20 = wsum64(xb2*x2o0);
      float s21 = wsum64(xb2*x2o1);
      float s22 = wsum64(xb2*x2o2);
      float s30 = wsum64(xb3*x2o0);
      float s31 = wsum64(xb3*x2o1);
      float s32 = wsum64(xb3*x2o2);
      float s33 = wsum64(xb3*x2o3);
      if (cl == 0){
        a2w[iw*16+0]  = s00;
        a2w[iw*16+4]  = s10; a2w[iw*16+5]  = s11;
        a2w[iw*16+8]  = s20; a2w[iw*16+9]  = s21; a2w[iw*16+10] = s22;
        a2w[iw*16+12] = s30; a2w[iw*16+13] = s31; a2w[iw*16+14] = s32; a2w[iw*16+15] = s33;
      }
    }
    __syncthreads();                               // E
    if (j < 16){
      int i2 = j >> 2, r2 = j & 3;
      float s = a2w[j] + a2w[16+j] + a2w[32+j] + a2w[48+j];
      coef2s[j] = (r2 <= i2) ? toks_s[i2]*els[r2]*(s + 1.f) : 0.f;
    }
    // --- Z2b partial ---
    {
      float p0=0.f,p1=0.f,p2=0.f,p3=0.f;
      #pragma unroll
      for (int dd=0; dd<64; dd++){
        float4 x4 = *(const float4*)&x2b_pk[(iw*64+dd)*4];
        float w = W2L[(iw*64+dd)*65 + cl];
        p0 += x4.x*w; p1 += x4.y*w; p2 += x4.z*w; p3 += x4.w*w;
      }
      pzs[cl*17 + 0*4 + iw] = p0;
      pzs[cl*17 + 1*4 + iw] = p1;
      pzs[cl*17 + 2*4 + iw] = p2;
      pzs[cl*17 + 3*4 + iw] = p3;
    }
    __syncthreads();                               // F
    float z2b = b2r + pzs[cl*17+iw*4] + pzs[cl*17+iw*4+1]
                    + pzs[cl*17+iw*4+2] + pzs[cl*17+iw*4+3];
    float4 g4r = *(const float4*)&gz2_pk[cl*4];
    {
      float4 c2 = *(const float4*)&coef2s[iw*4];
      z2b -= c2.x*g4r.x + c2.y*g4r.y + c2.z*g4r.z + c2.w*g4r.w;
    }
    float mu2 = wsum64(z2b)*(1.f/64.f);
    float df2 = z2b - mu2;
    float var2 = wsum64(df2*df2)*(1.f/64.f);
    float lnv = gr*df2*rsqrtf(var2 + 1e-6f) + br;
    out[((size_t)b*256 + n*4 + iw)*256 + h*64 + cl] = qv + lnv;
    // --- state updates (owner-only; all cross-thread reads were pre-F) ---
    float4 e4 = *(const float4*)&els[0];
    float le0 = tok3*e4.x, le1 = tok3*e4.y, le2 = tok3*e4.z, le3 = tok3*e4.w;
    float lg10 = le0*gz10, lg11 = le1*gz11, lg12 = le2*gz12, lg13 = le3*gz13;
    #pragma unroll
    for (int d=0; d<64; d++){
      float4 k4 = *(const float4*)&k_pk[d*4];
      W1s[d*256 + j] -= lg10*k4.x + lg11*k4.y + lg12*k4.z + lg13*k4.w;
    }
    b1r -= lg10 + lg11 + lg12 + lg13;
    float lx0 = le0*xb0, lx1 = le1*xb1, lx2 = le2*xb2, lx3 = le3*xb3;
    #pragma unroll
    for (int c=0; c<64; c++){
      float4 g4 = *(const float4*)&gz2_pk[c*4];
      W2L[j*65 + c] -= lx0*g4.x + lx1*g4.y + lx2*g4.z + lx3*g4.w;
    }
    b2r -= le0*g4r.x + le1*g4r.y + le2*g4r.z + le3*g4r.w;
    __syncthreads();                               // G
    qv = qn; kv = kn; vv = vn; elv = eln;
  }
}

// Fused head: LN(post) -> @wo -> LN(ln) -> fc1 -> fc2 -> fc3. grid 512 rows.
__global__ __launch_bounds__(256) void k_head(const float* __restrict__ hid2,
    const float* __restrict__ pg, const float* __restrict__ pb,
    const float* __restrict__ wo, const float* __restrict__ lg,
    const float* __restrict__ lb, const float* __restrict__ fcw,
    const float* __restrict__ fcb, const float* __restrict__ fc2w,
    const float* __restrict__ fc2b, const float* __restrict__ fc3w,
    const float* __restrict__ fc3b, float* __restrict__ outp){
  int row = blockIdx.x, c = threadIdx.x;
  __shared__ float t1[256];
  __shared__ float t3[256];
  __shared__ float t4[128];
  __shared__ float t5[64];
  __shared__ float rs[4];
  __shared__ float rq[4];
  int wv = c >> 6, ln = c & 63;
  float v = hid2[(size_t)row*256 + c];
  float s1 = wsum64(v), s2 = wsum64(v*v);
  if (ln == 0){ rs[wv]=s1; rq[wv]=s2; }
  __syncthreads();
  float mu = (rs[0]+rs[1]+rs[2]+rs[3])*(1.f/256.f);
  float msq = (rq[0]+rq[1]+rq[2]+rq[3])*(1.f/256.f);
  float var = msq - mu*mu;
  t1[c] = (v-mu)*rsqrtf(var + 1e-5f)*pg[c] + pb[c];
  __syncthreads();
  float a = 0.f;
  for (int k=0;k<256;k++) a += t1[k]*wo[(size_t)k*256 + c];
  float u1 = wsum64(a), u2 = wsum64(a*a);
  if (ln == 0){ rs[wv]=u1; rq[wv]=u2; }
  __syncthreads();
  mu = (rs[0]+rs[1]+rs[2]+rs[3])*(1.f/256.f);
  msq = (rq[0]+rq[1]+rq[2]+rq[3])*(1.f/256.f);
  var = msq - mu*mu;
  t3[c] = (a-mu)*rsqrtf(var + 1e-5f)*lg[c] + lb[c];
  __syncthreads();
  if (c < 128){
    float s = fcb[c];
    for (int k=0;k<256;k++) s += t3[k]*fcw[(size_t)k*128 + c];
    t4[c] = s;
  }
  __syncthreads();
  if (c < 64){
    float s = fc2b[c];
    for (int k=0;k<128;k++) s += t4[k]*fc2w[(size_t)k*64 + c];
    t5[c] = s;
  }
  __syncthreads();
  if (c < 64){
    float p = t5[c]*fc3w[c];
    p = wsum64(p);
    if (c == 0) outp[row] = p + fc3b[0];
  }
}

extern "C" void kernel_launch(void* const* d_in, const int* in_sizes, int n_in,
                              void* d_out, int out_size, void* d_ws, size_t ws_size,
                              hipStream_t stream){
  (void)in_sizes; (void)n_in; (void)out_size; (void)ws_size;
  const float* x       = (const float*)d_in[0];
  const float* s11_w   = (const float*)d_in[1];
  const float* s11_b   = (const float*)d_in[2];
  const float* bn11    = (const float*)d_in[3];
  const float* s12_w   = (const float*)d_in[4];
  const float* s12_b   = (const float*)d_in[5];
  const float* bn12    = (const float*)d_in[6];
  const float* s21_w   = (const float*)d_in[7];
  const float* s21_b   = (const float*)d_in[8];
  const float* bn21    = (const float*)d_in[9];
  const float* s22_w   = (const float*)d_in[10];
  const float* s22_b   = (const float*)d_in[11];
  const float* bn22    = (const float*)d_in[12];
  const float* s3_w    = (const float*)d_in[13];
  const float* s3_b    = (const float*)d_in[14];
  const float* bn3     = (const float*)d_in[15];
  const float* c1_w    = (const float*)d_in[16];
  const float* c1_b    = (const float*)d_in[17];
  const float* cb_w    = (const float*)d_in[18];
  const float* cb_b    = (const float*)d_in[19];
  const float* ln_g    = (const float*)d_in[20];
  const float* ln_b    = (const float*)d_in[21];
  const float* wq      = (const float*)d_in[22];
  const float* wk      = (const float*)d_in[23];
  const float* wv      = (const float*)d_in[24];
  const float* wo      = (const float*)d_in[25];
  const float* lr_w    = (const float*)d_in[26];
  const float* lr_b    = (const float*)d_in[27];
  const float* tib     = (const float*)d_in[28];
  const float* tlnw    = (const float*)d_in[29];
  const float* tlnb    = (const float*)d_in[30];
  const float* W1      = (const float*)d_in[31];
  const float* B1      = (const float*)d_in[32];
  const float* W2      = (const float*)d_in[33];
  const float* B2      = (const float*)d_in[34];
  const float* post_g  = (const float*)d_in[35];
  const float* post_b  = (const float*)d_in[36];
  const float* fc_w    = (const float*)d_in[37];
  const float* fc_b    = (const float*)d_in[38];
  const float* fc2_w   = (const float*)d_in[39];
  const float* fc2_b   = (const float*)d_in[40];
  const float* fc3_w   = (const float*)d_in[41];
  const float* fc3_b   = (const float*)d_in[42];

  float* ws = (float*)d_ws;
  float* xs   = ws;                       // 2359296
  float* xd   = ws + 2359296;             // 2359296
  float* p1   = ws + 4718592;             // 1179648
  float* p2   = ws + 5898240;             // 1179648
  float* sig  = ws + 7077888;             // 32768
  float* buf0 = ws + 7110656;             // 131072
  float* buf1 = ws + 7241728;             // 131072
  float* accb = ws + 7372800;             // 131072
  float* hid  = ws + 7503872;             // 131072
  float* xqb  = ws + 7634944;             // 131072
  float* xkb  = ws + 7766016;             // 131072
  float* xvb  = ws + 7897088;             // 131072
  float* eta  = ws + 8028160;             // 2048
  float* hid2 = ws + 8030208;             // 131072

  k_s11<<<1536, 192, 0, stream>>>(x, s11_w, s11_b, bn11, xs);
  k_s12<<<1536, 192, 0, stream>>>(x, s12_w, s12_b, bn12, xd);
  k_s2x<<<512, 256, 0, stream>>>(xs, xd, s21_w, s21_b, bn21, p1);
  k_s2x<<<512, 256, 0, stream>>>(xd, xd, s22_w, s22_b, bn22, p2);
  k_s3<<<512, 256, 0, stream>>>(p1, p2, s3_w, s3_b, bn3, sig);
  k_c1<<<512, 256, 0, stream>>>(sig, c1_w, c1_b, buf0);
  {
    float* cin = buf0; float* cout = buf1;
    for (int l=0; l<8; l++){
      int mode = (l == 1) ? 1 : ((l & 1) ? 2 : 0);
      k_conv1d<<<256, 256, 0, stream>>>(cin, cb_w + (size_t)l*196608,
                                        cb_b + l*256, cout, accb, mode);
      float* tmp = cin; cin = cout; cout = tmp;
    }
  }
  k_ln_tr<<<512, 256, 0, stream>>>(accb, ln_g, ln_b, hid);
  k_proj<<<1536, 256, 0, stream>>>(hid, wq, wk, wv, xqb, xkb, xvb);
  k_eta<<<8, 256, 0, stream>>>(hid, lr_w, lr_b, eta);
  k_ttt<<<8, 256, 0, stream>>>(xqb, xkb, xvb, eta, tib, tlnw, tlnb,
                               W1, B1, W2, B2, hid2);
  k_head<<<512, 256, 0, stream>>>(hid2, post_g, post_b, wo, ln_g, ln_b,
                                  fc_w, fc_b, fc2_w, fc2_b, fc3_w, fc3_b,
                                  (float*)d_out);
}

// Round 6
// 1892.093 us; speedup vs baseline: 2.0694x; 1.7415x over previous
//
#include <hip/hip_runtime.h>
#include <hip/hip_bf16.h>
#include <math.h>

#define DEV __device__ __forceinline__

DEV float wsum64(float v){
  #pragma unroll
  for (int off = 32; off; off >>= 1) v += __shfl_xor(v, off, 64);
  return v;
}
DEV float geluf(float x){
  return 0.5f*x*(1.f + tanhf(0.7978845608028654f*(x + 0.044715f*x*x*x)));
}
DEV float gelu_bwdf(float x){
  float x2 = x*x;
  float t = tanhf(0.79788456f*x*(1.f + 0.044715f*x2));
  return 0.5f*x*((1.f - t*t)*(0.79788456f + 0.1070322243f*x2)) + 0.5f*(1.f + t);
}
DEV float sigmf(float x){ return 1.f/(1.f + expf(-x)); }

// ---------------------------------------------------------------------------
// Stem s11: x[512,3,96,96] -> conv7x7 s2 p3 -> BN -> ReLU -> pool2 -> xs[512,8,24,24]
__global__ __launch_bounds__(192) void k_s11(const float* __restrict__ x,
    const float* __restrict__ w, const float* __restrict__ bias,
    const float* __restrict__ bn, float* __restrict__ xs){
  __shared__ float st[3*37*2*53];   // 11766 floats
  __shared__ float wl[49*3*8];      // 1176
  int bx = blockIdx.x;
  int bd = bx / 3, g = bx - bd*3;
  int t = threadIdx.x;
  for (int e = t; e < 1176; e += 192){
    int tap = e / 24, r = e - tap*24, ci = r >> 3, c = r & 7;
    wl[e] = w[(c*3 + ci)*49 + tap];
  }
  const float* xb = x + (size_t)bd*3*9216;
  for (int e = t; e < 3*37*102; e += 192){
    int ci = e / 3774, r2 = e - ci*3774;
    int ihl = r2 / 102, pi = r2 - ihl*102;
    int ih = ihl + 32*g - 3, iw = pi - 3;
    float v = 0.f;
    if (ih>=0 && ih<96 && iw>=0 && iw<96) v = xb[(size_t)ci*9216 + ih*96 + iw];
    st[((ci*37 + ihl)*2 + (pi&1))*53 + (pi>>1)] = v;
  }
  __syncthreads();
  int pr = t / 24, pc = t - pr*24;
  float a00[8], a01[8], a10[8], a11[8];
  #pragma unroll
  for (int c=0;c<8;c++){ a00[c]=0.f; a01[c]=0.f; a10[c]=0.f; a11[c]=0.f; }
  for (int ci=0; ci<3; ci++){
    for (int kh=0; kh<7; kh++){
      int rb0 = (ci*37 + 4*pr + kh)*106 + 2*pc;
      int rb1 = rb0 + 212;
      #pragma unroll
      for (int kw=0; kw<7; kw++){
        int off = (kw&1)*53 + (kw>>1);
        float v00 = st[rb0+off], v01 = st[rb0+off+1];
        float v10 = st[rb1+off], v11 = st[rb1+off+1];
        const float4* wp = (const float4*)&wl[((kh*7+kw)*3 + ci)*8];
        float wv[8];
        *(float4*)&wv[0] = wp[0]; *(float4*)&wv[4] = wp[1];
        #pragma unroll
        for (int c=0;c<8;c++){
          a00[c] += v00*wv[c]; a01[c] += v01*wv[c];
          a10[c] += v10*wv[c]; a11[c] += v11*wv[c];
        }
      }
    }
  }
  int pos = (g*8 + pr)*24 + pc;
  #pragma unroll
  for (int c=0;c<8;c++){
    float gg=bn[c], be=bn[8+c], m=bn[16+c], vv=bn[24+c];
    float s = gg*rsqrtf(vv + 1e-5f);
    float bi = bias[c];
    float mx = 0.f;
    mx = fmaxf(mx, (a00[c]+bi-m)*s+be);
    mx = fmaxf(mx, (a01[c]+bi-m)*s+be);
    mx = fmaxf(mx, (a10[c]+bi-m)*s+be);
    mx = fmaxf(mx, (a11[c]+bi-m)*s+be);
    xs[((size_t)bd*8 + c)*576 + pos] = mx;
  }
}

// Stem s12: same structure on frame-diffs (4 groups of 3 channels, diff at staging).
__global__ __launch_bounds__(192) void k_s12(const float* __restrict__ x,
    const float* __restrict__ w, const float* __restrict__ bias,
    const float* __restrict__ bn, float* __restrict__ xd){
  __shared__ float st[3*37*2*53];
  __shared__ float wl[49*12*8];     // 4704
  int bx = blockIdx.x;
  int bd = bx / 3, g = bx - bd*3;
  int b = bd >> 8, dd = bd & 255;
  int t = threadIdx.x;
  for (int e = t; e < 4704; e += 192){
    int tap = e / 96, r = e - tap*96, ci = r >> 3, c = r & 7;
    wl[e] = w[(c*12 + ci)*49 + tap];
  }
  int fa[4], fb[4];
  fa[0] = dd>=2 ? dd-1 : 0;     fb[0] = dd>=2 ? dd-2 : 0;
  fa[1] = dd;                   fb[1] = dd>=1 ? dd-1 : 0;
  fa[2] = dd<=254 ? dd+1 : 255; fb[2] = dd;
  fa[3] = dd<=253 ? dd+2 : 255; fb[3] = dd<=254 ? dd+1 : 255;
  int pr = t / 24, pc = t - pr*24;
  float a00[8], a01[8], a10[8], a11[8];
  #pragma unroll
  for (int c=0;c<8;c++){ a00[c]=0.f; a01[c]=0.f; a10[c]=0.f; a11[c]=0.f; }
  for (int g4=0; g4<4; g4++){
    if (fa[g4] == fb[g4]) continue;   // zero diff, uniform per block
    __syncthreads();
    const float* xa = x + ((size_t)(b*256 + fa[g4]))*3*9216;
    const float* xbp= x + ((size_t)(b*256 + fb[g4]))*3*9216;
    for (int e = t; e < 3*37*102; e += 192){
      int ci = e / 3774, r2 = e - ci*3774;
      int ihl = r2 / 102, pi = r2 - ihl*102;
      int ih = ihl + 32*g - 3, iw = pi - 3;
      float v = 0.f;
      if (ih>=0 && ih<96 && iw>=0 && iw<96){
        size_t off = (size_t)ci*9216 + ih*96 + iw;
        v = xa[off] - xbp[off];
      }
      st[((ci*37 + ihl)*2 + (pi&1))*53 + (pi>>1)] = v;
    }
    __syncthreads();
    for (int ci=0; ci<3; ci++){
      int gch = g4*3 + ci;
      for (int kh=0; kh<7; kh++){
        int rb0 = (ci*37 + 4*pr + kh)*106 + 2*pc;
        int rb1 = rb0 + 212;
        #pragma unroll
        for (int kw=0; kw<7; kw++){
          int off = (kw&1)*53 + (kw>>1);
          float v00 = st[rb0+off], v01 = st[rb0+off+1];
          float v10 = st[rb1+off], v11 = st[rb1+off+1];
          const float4* wp = (const float4*)&wl[((kh*7+kw)*12 + gch)*8];
          float wv[8];
          *(float4*)&wv[0] = wp[0]; *(float4*)&wv[4] = wp[1];
          #pragma unroll
          for (int c=0;c<8;c++){
            a00[c] += v00*wv[c]; a01[c] += v01*wv[c];
            a10[c] += v10*wv[c]; a11[c] += v11*wv[c];
          }
        }
      }
    }
  }
  int pos = (g*8 + pr)*24 + pc;
  #pragma unroll
  for (int c=0;c<8;c++){
    float gg=bn[c], be=bn[8+c], m=bn[16+c], vv=bn[24+c];
    float s = gg*rsqrtf(vv + 1e-5f);
    float bi = bias[c];
    float mx = 0.f;
    mx = fmaxf(mx, (a00[c]+bi-m)*s+be);
    mx = fmaxf(mx, (a01[c]+bi-m)*s+be);
    mx = fmaxf(mx, (a10[c]+bi-m)*s+be);
    mx = fmaxf(mx, (a11[c]+bi-m)*s+be);
    xd[((size_t)bd*8 + c)*576 + pos] = mx;
  }
}

// s21/s22: in = 0.5*(A+B) [512,8,24,24] -> conv7x7 s1 p3 -> BN relu pool -> [512,16,12,12]
__global__ __launch_bounds__(256) void k_s2x(const float* __restrict__ inA,
    const float* __restrict__ inB, const float* __restrict__ w,
    const float* __restrict__ bias, const float* __restrict__ bn,
    float* __restrict__ outp){
  __shared__ float st[8*30*33];     // 7920
  __shared__ float wl[49*8*16];     // 6272
  int bd = blockIdx.x;
  int t = threadIdx.x;
  for (int e = t; e < 6272; e += 256){
    int tap = e >> 7, r = e & 127, ci = r >> 4, c = r & 15;
    wl[e] = w[(c*8 + ci)*49 + tap];
  }
  const float* pa = inA + (size_t)bd*8*576;
  const float* pb = inB + (size_t)bd*8*576;
  for (int e = t; e < 7920; e += 256){
    int ci = e / 990, r2 = e - ci*990;
    int r = r2 / 33, cc = r2 - r*33;
    int ih = r - 3, iw = cc - 3;
    float v = 0.f;
    if (ih>=0 && ih<24 && iw>=0 && iw<24){
      int off = ci*576 + ih*24 + iw;
      v = 0.5f*(pa[off] + pb[off]);
    }
    st[(ci*30 + r)*33 + cc] = v;
  }
  __syncthreads();
  if (t < 144){
    int pr = t / 12, pc = t - pr*12;
    float a00[16], a01[16], a10[16], a11[16];
    #pragma unroll
    for (int c=0;c<16;c++){ a00[c]=0.f; a01[c]=0.f; a10[c]=0.f; a11[c]=0.f; }
    for (int ci=0; ci<8; ci++){
      for (int kh=0; kh<7; kh++){
        int rb = (ci*30 + 2*pr + kh)*33 + 2*pc;
        #pragma unroll
        for (int kw=0; kw<7; kw++){
          float v00 = st[rb+kw],    v01 = st[rb+kw+1];
          float v10 = st[rb+33+kw], v11 = st[rb+34+kw];
          const float4* wp = (const float4*)&wl[((kh*7+kw)*8 + ci)*16];
          float wv[16];
          *(float4*)&wv[0]  = wp[0]; *(float4*)&wv[4]  = wp[1];
          *(float4*)&wv[8]  = wp[2]; *(float4*)&wv[12] = wp[3];
          #pragma unroll
          for (int c=0;c<16;c++){
            a00[c] += v00*wv[c]; a01[c] += v01*wv[c];
            a10[c] += v10*wv[c]; a11[c] += v11*wv[c];
          }
        }
      }
    }
    #pragma unroll
    for (int c=0;c<16;c++){
      float gg=bn[c], be=bn[16+c], m=bn[32+c], vv=bn[48+c];
      float s = gg*rsqrtf(vv + 1e-5f);
      float bi = bias[c];
      float mx = 0.f;
      mx = fmaxf(mx, (a00[c]+bi-m)*s+be);
      mx = fmaxf(mx, (a01[c]+bi-m)*s+be);
      mx = fmaxf(mx, (a10[c]+bi-m)*s+be);
      mx = fmaxf(mx, (a11[c]+bi-m)*s+be);
      outp[((size_t)bd*16 + c)*144 + pr*12 + pc] = mx;
    }
  }
}

// s3 conv3x3 p1 + BN + attention-mask pooled signal. block per bd. -> sig[512,64]
__global__ __launch_bounds__(256) void k_s3(const float* __restrict__ p1,
    const float* __restrict__ p2, const float* __restrict__ w,
    const float* __restrict__ bias, const float* __restrict__ bn,
    float* __restrict__ sig){
  __shared__ float ins[16*14*14];
  __shared__ float wT[144*64];
  __shared__ float redS[64*4];
  __shared__ float redF[64*4];
  int bd = blockIdx.x;
  int t = threadIdx.x;
  for (int i = t; i < 16*196; i += 256){
    int ci = i/196, r = i - ci*196, y = r/14, xx = r - y*14;
    float v = 0.f;
    if (y>=1 && y<=12 && xx>=1 && xx<=12){
      size_t idx = ((size_t)bd*16 + ci)*144 + (y-1)*12 + (xx-1);
      v = 0.5f*(p1[idx] + p2[idx]);
    }
    ins[i] = v;
  }
  for (int i = t; i < 9216; i += 256){
    int c = i & 63, k = i >> 6;
    wT[i] = w[c*144 + k];
  }
  __syncthreads();
  int c = t & 63, pg = t >> 6;
  float acc[36];
  #pragma unroll
  for (int pp=0;pp<36;pp++) acc[pp]=0.f;
  for (int k=0; k<144; k++){
    int ci = k/9, kk = k - ci*9, kh = kk/3, kw = kk - kh*3;
    float wv = wT[k*64 + c];
    const float* ip = &ins[ci*196];
    #pragma unroll
    for (int pp=0;pp<36;pp++){
      int y = pg*3 + pp/12, xx = pp%12;
      acc[pp] += ip[(y+kh)*14 + (xx+kw)] * wv;
    }
  }
  float g=bn[c], be=bn[64+c], m=bn[128+c], vv=bn[192+c];
  float s = g*rsqrtf(vv + 1e-5f);
  float bi = bias[c];
  float sS = 0.f, sF = 0.f;
  #pragma unroll
  for (int pp=0;pp<36;pp++){
    float f = (acc[pp] + bi - m)*s + be;
    float sg = sigmf(f);
    sS += sg; sF += f*sg;
  }
  redS[c*4+pg] = sS; redF[c*4+pg] = sF;
  __syncthreads();
  if (t < 64){
    float S = redS[t*4]+redS[t*4+1]+redS[t*4+2]+redS[t*4+3];
    float F = redF[t*4]+redF[t*4+1]+redF[t*4+2]+redF[t*4+3];
    sig[(size_t)bd*64 + t] = 0.5f*F/S;
  }
}

// c1 1x1 conv: sig[b,t,64] -> h[b,256,256] (channel-major). block=(b,o). grid 512.
__global__ __launch_bounds__(256) void k_c1(const float* __restrict__ sig,
    const float* __restrict__ w, const float* __restrict__ bias,
    float* __restrict__ h){
  int b = blockIdx.x >> 8, o = blockIdx.x & 255, tt = threadIdx.x;
  __shared__ float wl[64];
  if (tt < 64) wl[tt] = w[o*64 + tt];
  __syncthreads();
  const float4* sp = (const float4*)(sig + ((size_t)(b*256 + tt))*64);
  const float4* wp = (const float4*)wl;
  float a = bias[o];
  #pragma unroll
  for (int i=0;i<16;i++){
    float4 s4 = sp[i]; float4 w4 = wp[i];
    a += s4.x*w4.x + s4.y*w4.y + s4.z*w4.z + s4.w*w4.w;
  }
  h[((size_t)b*256 + o)*256 + tt] = fmaxf(a, 0.f);
}

// conv1d 256->256 k3 p1 + relu. mode: 0=none 1=acc:=out 2=acc+=out. grid 256.
__global__ __launch_bounds__(256) void k_conv1d(const float* __restrict__ hin,
    const float* __restrict__ w, const float* __restrict__ bias,
    float* __restrict__ hout, float* __restrict__ accb, int mode){
  __shared__ float ins[256*34];
  __shared__ float ws[16*256*4];   // padded stride-4 taps
  int bx = blockIdx.x;
  int b = bx >> 7;
  int rem = bx & 127;
  int og = rem >> 3;
  int tg = rem & 7;
  int tid = threadIdx.x;
  int t0 = tg*32;
  for (int idx = tid; idx < 256*34; idx += 256){
    int ii = idx/34, jj = idx - ii*34;
    int tglob = t0 - 1 + jj;
    float v = 0.f;
    if (tglob >= 0 && tglob < 256) v = hin[((size_t)b*256 + ii)*256 + tglob];
    ins[idx] = v;
  }
  for (int idx = tid; idx < 12288; idx += 256){
    int q = idx/3;
    ws[q*4 + (idx - q*3)] = w[(size_t)og*12288 + idx];
  }
  __syncthreads();
  int ol = tid >> 5, tl = tid & 31;
  int o1 = og*16 + ol, o2 = o1 + 8;
  float a1 = bias[o1], a2 = bias[o2];
  const float4* w1q = (const float4*)(ws + (size_t)ol*1024);
  const float4* w2q = (const float4*)(ws + (size_t)(ol+8)*1024);
  for (int i=0;i<256;i++){
    float v0 = ins[i*34 + tl];
    float v1 = ins[i*34 + tl + 1];
    float v2 = ins[i*34 + tl + 2];
    float4 wa = w1q[i];
    float4 wb = w2q[i];
    a1 += wa.x*v0 + wa.y*v1 + wa.z*v2;
    a2 += wb.x*v0 + wb.y*v1 + wb.z*v2;
  }
  a1 = fmaxf(a1, 0.f); a2 = fmaxf(a2, 0.f);
  size_t i1 = ((size_t)b*256 + o1)*256 + t0 + tl;
  size_t i2 = ((size_t)b*256 + o2)*256 + t0 + tl;
  hout[i1] = a1; hout[i2] = a2;
  if (mode == 1){ accb[i1] = a1; accb[i2] = a2; }
  else if (mode == 2){ accb[i1] += a1; accb[i2] += a2; }
}

// acc[b,c,t] -> transpose + LN(ln_g,ln_b) -> hid[(b t),c]. grid 512.
__global__ __launch_bounds__(256) void k_ln_tr(const float* __restrict__ acc,
    const float* __restrict__ g, const float* __restrict__ be,
    float* __restrict__ hid){
  int b = blockIdx.x >> 8, tt = blockIdx.x & 255, c = threadIdx.x;
  __shared__ float rs[4];
  __shared__ float rq[4];
  float v = acc[((size_t)b*256 + c)*256 + tt];
  float s1 = wsum64(v), s2 = wsum64(v*v);
  int wv = c >> 6, ln = c & 63;
  if (ln == 0){ rs[wv]=s1; rq[wv]=s2; }
  __syncthreads();
  float mu = (rs[0]+rs[1]+rs[2]+rs[3])*(1.f/256.f);
  float msq = (rq[0]+rq[1]+rq[2]+rq[3])*(1.f/256.f);
  float var = msq - mu*mu;
  hid[(size_t)blockIdx.x*256 + c] = (v-mu)*rsqrtf(var + 1e-5f)*g[c] + be[c];
}

// projections hid @ {wq,wk,wv}. grid 1536.
__global__ __launch_bounds__(256) void k_proj(const float* __restrict__ hid,
    const float* __restrict__ wq, const float* __restrict__ wk,
    const float* __restrict__ wv, float* __restrict__ xq,
    float* __restrict__ xk, float* __restrict__ xv){
  int m = blockIdx.x >> 9, row = blockIdx.x & 511, c = threadIdx.x;
  const float* W = (m==0) ? wq : ((m==1) ? wk : wv);
  float* O = (m==0) ? xq : ((m==1) ? xk : xv);
  __shared__ float hrow[256];
  hrow[c] = hid[(size_t)row*256 + c];
  __syncthreads();
  float a = 0.f;
  for (int k=0;k<256;k++) a += hrow[k]*W[(size_t)k*256 + c];
  O[(size_t)row*256 + c] = a;
}

// eta_lr (scaled): 0.1*sigmoid(hid.lr_w + lr_b)/64. grid 8 (b*4+h).
__global__ __launch_bounds__(256) void k_eta(const float* __restrict__ hid,
    const float* __restrict__ lrw, const float* __restrict__ lrb,
    float* __restrict__ etalr){
  int b = blockIdx.x >> 2, h = blockIdx.x & 3, l = threadIdx.x;
  const float* hp = hid + ((size_t)(b*256 + l))*256;
  float a = lrb[h];
  for (int k=0;k<256;k++) a += hp[k]*lrw[h*256 + k];
  etalr[(size_t)blockIdx.x*256 + l] = 0.1f*sigmf(a)*(1.f/64.f);
}

// TTT-MLP scan. One block per (b,h). LDS-resident weights, bounded unroll (x8)
// on all 64-iter loops to keep VGPR pressure under the spill threshold.
__global__ __launch_bounds__(256) void k_ttt(
    const float* __restrict__ xq, const float* __restrict__ xk,
    const float* __restrict__ xv, const float* __restrict__ etalr,
    const float* __restrict__ tib, const float* __restrict__ lnw,
    const float* __restrict__ lnb, const float* __restrict__ W1g,
    const float* __restrict__ B1g, const float* __restrict__ W2g,
    const float* __restrict__ B2g, float* __restrict__ out){
  __shared__ float W1s[64*256];                // [d][j]
  __shared__ float W2L[256*65];                // [r][c], pitch 65
  __shared__ __align__(16) float k_pk[256];    // [d=64][i=4]
  __shared__ __align__(16) float q_pk[256];
  __shared__ __align__(16) float x2_pk[1024];  // [d=256][i=4]
  __shared__ __align__(16) float x2b_pk[1024];
  __shared__ __align__(16) float gz2_pk[256];  // [c=64][i=4]
  __shared__ float pzs[64*17];                 // partial dots [cl][i*4+iw]
  __shared__ float a2w[64];
  __shared__ __align__(16) float coefs[16];
  __shared__ __align__(16) float coef2s[16];
  __shared__ __align__(16) float els[4];
  __shared__ float toks_s[4];

  int b = blockIdx.x >> 2, h = blockIdx.x & 3;
  int j = threadIdx.x;
  int iw = j >> 6, cl = j & 63;

  const float* W1b = W1g + (size_t)h*16384;
  const float* W2b = W2g + (size_t)h*16384;
  for (int i=j; i<16384; i+=256) W1s[i] = W1b[i];
  for (int i=j; i<16384; i+=256){
    int r = i >> 6, c = i & 63;
    W2L[r*65 + c] = W2b[i];
  }
  float b1r = B1g[h*256 + j];
  float b2r = B2g[h*64 + cl];
  float gr = lnw[h*64 + cl], br = lnb[h*64 + cl];
  if (j < 4) toks_s[j] = fmaxf(1.f/(float)(j+1) + tib[j], 0.f);
  __syncthreads();
  float tok3 = toks_s[3];
  float tik = toks_s[iw];

  const float* xqp = xq + (size_t)b*65536 + h*64;
  const float* xkp = xk + (size_t)b*65536 + h*64;
  const float* xvp = xv + (size_t)b*65536 + h*64;
  const float* ep  = etalr + (size_t)(b*4 + h)*256;

  float qv = xqp[(size_t)iw*256 + cl];
  float kv = xkp[(size_t)iw*256 + cl];
  float vv = xvp[(size_t)iw*256 + cl];
  float elv = (j < 4) ? ep[j] : 0.f;

  for (int n=0; n<64; n++){
    k_pk[cl*4+iw] = kv;
    q_pk[cl*4+iw] = qv;
    if (j < 4) els[j] = elv;
    __syncthreads();                               // A
    // --- A1 row iw (tril coef) ---
    {
      float4 k4a = *(const float4*)&k_pk[cl*4];
      float a0 = wsum64(qv*k4a.x);
      float a1 = wsum64(qv*k4a.y);
      float a2 = wsum64(qv*k4a.z);
      float a3 = wsum64(qv*k4a.w);
      if (cl == 0){
        float4 e4 = *(const float4*)&els[0];
        coefs[iw*4+0] = tik*e4.x*(a0+1.f);
        coefs[iw*4+1] = (iw>=1) ? tik*e4.y*(a1+1.f) : 0.f;
        coefs[iw*4+2] = (iw>=2) ? tik*e4.z*(a2+1.f) : 0.f;
        coefs[iw*4+3] = (iw>=3) ? tik*e4.w*(a3+1.f) : 0.f;
      }
    }
    // --- Z1 = k@W1+b1, qW1 = q@W1+b1 (LDS W1 column, conflict-free) ---
    float z1v0=b1r, z1v1=b1r, z1v2=b1r, z1v3=b1r;
    float qw0=b1r, qw1=b1r, qw2=b1r, qw3=b1r;
    #pragma unroll 8
    for (int d=0; d<64; d++){
      float4 k4 = *(const float4*)&k_pk[d*4];
      float4 q4 = *(const float4*)&q_pk[d*4];
      float w = W1s[d*256 + j];
      z1v0 += k4.x*w; z1v1 += k4.y*w; z1v2 += k4.z*w; z1v3 += k4.w*w;
      qw0  += q4.x*w; qw1  += q4.y*w; qw2  += q4.z*w; qw3  += q4.w*w;
    }
    float x2o0 = geluf(z1v0), x2o1 = geluf(z1v1), x2o2 = geluf(z1v2), x2o3 = geluf(z1v3);
    { float4 t4; t4.x=x2o0; t4.y=x2o1; t4.z=x2o2; t4.w=x2o3;
      *(float4*)&x2_pk[j*4] = t4; }
    __syncthreads();                               // B
    // --- prefetch next step's q/k/v/eta (hidden under compute) ---
    float qn=0.f, kn=0.f, vn=0.f, eln=0.f;
    if (n < 63){
      int l2 = (n+1)*4 + iw;
      qn = xqp[(size_t)l2*256 + cl];
      kn = xkp[(size_t)l2*256 + cl];
      vn = xvp[(size_t)l2*256 + cl];
      if (j < 4) eln = ep[(n+1)*4 + j];
    }
    // --- Z2 partial: thread (iw,cl) covers d in [iw*64, iw*64+64) ---
    {
      float p0=0.f,p1=0.f,p2=0.f,p3=0.f;
      #pragma unroll 8
      for (int dd=0; dd<64; dd++){
        float4 x4 = *(const float4*)&x2_pk[(iw*64+dd)*4];
        float w = W2L[(iw*64+dd)*65 + cl];
        p0 += x4.x*w; p1 += x4.y*w; p2 += x4.z*w; p3 += x4.w*w;
      }
      pzs[cl*17 + 0*4 + iw] = p0;
      pzs[cl*17 + 1*4 + iw] = p1;
      pzs[cl*17 + 2*4 + iw] = p2;
      pzs[cl*17 + 3*4 + iw] = p3;
    }
    __syncthreads();                               // C
    float z2 = b2r + pzs[cl*17+iw*4] + pzs[cl*17+iw*4+1]
                   + pzs[cl*17+iw*4+2] + pzs[cl*17+iw*4+3];
    // --- fused LN-L2 backward (wave = minibatch row iw) ---
    float mu = wsum64(z2)*(1.f/64.f);
    float df = z2 - mu;
    float var = wsum64(df*df)*(1.f/64.f);
    float stdv = sqrtf(var + 1e-6f);
    float xhat = df/stdv;
    float tgt = vv - kv;
    float gxh = (gr*xhat + br - tgt)*gr;
    float sg1 = wsum64(gxh);
    float sg2 = wsum64(gxh*xhat);
    float gz2 = (64.f*gxh - sg1 - xhat*sg2)*(1.f/(64.f*stdv));
    gz2_pk[cl*4+iw] = gz2;
    __syncthreads();                               // D
    // --- gZ1 = (gZ2@W2^T)*gelu'(Z1) via LDS W2 row j (conflict-free) ---
    float gd0=0.f,gd1=0.f,gd2=0.f,gd3=0.f;
    #pragma unroll 8
    for (int c=0; c<64; c++){
      float4 g4 = *(const float4*)&gz2_pk[c*4];
      float w = W2L[j*65 + c];
      gd0 += g4.x*w; gd1 += g4.y*w; gd2 += g4.z*w; gd3 += g4.w*w;
    }
    float gz10 = gd0*gelu_bwdf(z1v0);
    float gz11 = gd1*gelu_bwdf(z1v1);
    float gz12 = gd2*gelu_bwdf(z1v2);
    float gz13 = gd3*gelu_bwdf(z1v3);
    float4 cf0 = *(const float4*)&coefs[0];
    float4 cf1 = *(const float4*)&coefs[4];
    float4 cf2 = *(const float4*)&coefs[8];
    float4 cf3 = *(const float4*)&coefs[12];
    float zb0 = qw0 - (cf0.x*gz10 + cf0.y*gz11 + cf0.z*gz12 + cf0.w*gz13);
    float zb1 = qw1 - (cf1.x*gz10 + cf1.y*gz11 + cf1.z*gz12 + cf1.w*gz13);
    float zb2 = qw2 - (cf2.x*gz10 + cf2.y*gz11 + cf2.z*gz12 + cf2.w*gz13);
    float zb3 = qw3 - (cf3.x*gz10 + cf3.y*gz11 + cf3.z*gz12 + cf3.w*gz13);
    float xb0 = geluf(zb0), xb1 = geluf(zb1), xb2 = geluf(zb2), xb3 = geluf(zb3);
    { float4 t4; t4.x=xb0; t4.y=xb1; t4.z=xb2; t4.w=xb3;
      *(float4*)&x2b_pk[j*4] = t4; }
    // --- A2 (masked r<=i), per-thread products + wave reduce ---
    {
      float s00 = wsum64(xb0*x2o0);
      float s10 = wsum64(xb1*x2o0);
      float s11 = wsum64(xb1*x2o1);
      float s20 = wsum64(xb2*x2o0);
      float s21 = wsum64(xb2*x2o1);
      float s22 = wsum64(xb2*x2o2);
      float s30 = wsum64(xb3*x2o0);
      float s31 = wsum64(xb3*x2o1);
      float s32 = wsum64(xb3*x2o2);
      float s33 = wsum64(xb3*x2o3);
      if (cl == 0){
        a2w[iw*16+0]  = s00;
        a2w[iw*16+4]  = s10; a2w[iw*16+5]  = s11;
        a2w[iw*16+8]  = s20; a2w[iw*16+9]  = s21; a2w[iw*16+10] = s22;
        a2w[iw*16+12] = s30; a2w[iw*16+13] = s31; a2w[iw*16+14] = s32; a2w[iw*16+15] = s33;
      }
    }
    __syncthreads();                               // E
    if (j < 16){
      int i2 = j >> 2, r2 = j & 3;
      float s = a2w[j] + a2w[16+j] + a2w[32+j] + a2w[48+j];
      coef2s[j] = (r2 <= i2) ? toks_s[i2]*els[r2]*(s + 1.f) : 0.f;
    }
    // --- Z2b partial ---
    {
      float p0=0.f,p1=0.f,p2=0.f,p3=0.f;
      #pragma unroll 8
      for (int dd=0; dd<64; dd++){
        float4 x4 = *(const float4*)&x2b_pk[(iw*64+dd)*4];
        float w = W2L[(iw*64+dd)*65 + cl];
        p0 += x4.x*w; p1 += x4.y*w; p2 += x4.z*w; p3 += x4.w*w;
      }
      pzs[cl*17 + 0*4 + iw] = p0;
      pzs[cl*17 + 1*4 + iw] = p1;
      pzs[cl*17 + 2*4 + iw] = p2;
      pzs[cl*17 + 3*4 + iw] = p3;
    }
    __syncthreads();                               // F
    float z2b = b2r + pzs[cl*17+iw*4] + pzs[cl*17+iw*4+1]
                    + pzs[cl*17+iw*4+2] + pzs[cl*17+iw*4+3];
    float4 g4r = *(const float4*)&gz2_pk[cl*4];
    {
      float4 c2 = *(const float4*)&coef2s[iw*4];
      z2b -= c2.x*g4r.x + c2.y*g4r.y + c2.z*g4r.z + c2.w*g4r.w;
    }
    float mu2 = wsum64(z2b)*(1.f/64.f);
    float df2 = z2b - mu2;
    float var2 = wsum64(df2*df2)*(1.f/64.f);
    float lnv = gr*df2*rsqrtf(var2 + 1e-6f) + br;
    out[((size_t)b*256 + n*4 + iw)*256 + h*64 + cl] = qv + lnv;
    // --- state updates (owner-only; all cross-thread reads were pre-F) ---
    float4 e4 = *(const float4*)&els[0];
    float le0 = tok3*e4.x, le1 = tok3*e4.y, le2 = tok3*e4.z, le3 = tok3*e4.w;
    float lg10 = le0*gz10, lg11 = le1*gz11, lg12 = le2*gz12, lg13 = le3*gz13;
    #pragma unroll 8
    for (int d=0; d<64; d++){
      float4 k4 = *(const float4*)&k_pk[d*4];
      W1s[d*256 + j] -= lg10*k4.x + lg11*k4.y + lg12*k4.z + lg13*k4.w;
    }
    b1r -= lg10 + lg11 + lg12 + lg13;
    float lx0 = le0*xb0, lx1 = le1*xb1, lx2 = le2*xb2, lx3 = le3*xb3;
    #pragma unroll 8
    for (int c=0; c<64; c++){
      float4 g4 = *(const float4*)&gz2_pk[c*4];
      W2L[j*65 + c] -= lx0*g4.x + lx1*g4.y + lx2*g4.z + lx3*g4.w;
    }
    b2r -= le0*g4r.x + le1*g4r.y + le2*g4r.z + le3*g4r.w;
    __syncthreads();                               // G
    qv = qn; kv = kn; vv = vn; elv = eln;
  }
}

// Fused head: LN(post) -> @wo -> LN(ln) -> fc1 -> fc2 -> fc3. grid 512 rows.
__global__ __launch_bounds__(256) void k_head(const float* __restrict__ hid2,
    const float* __restrict__ pg, const float* __restrict__ pb,
    const float* __restrict__ wo, const float* __restrict__ lg,
    const float* __restrict__ lb, const float* __restrict__ fcw,
    const float* __restrict__ fcb, const float* __restrict__ fc2w,
    const float* __restrict__ fc2b, const float* __restrict__ fc3w,
    const float* __restrict__ fc3b, float* __restrict__ outp){
  int row = blockIdx.x, c = threadIdx.x;
  __shared__ float t1[256];
  __shared__ float t3[256];
  __shared__ float t4[128];
  __shared__ float t5[64];
  __shared__ float rs[4];
  __shared__ float rq[4];
  int wv = c >> 6, ln = c & 63;
  float v = hid2[(size_t)row*256 + c];
  float s1 = wsum64(v), s2 = wsum64(v*v);
  if (ln == 0){ rs[wv]=s1; rq[wv]=s2; }
  __syncthreads();
  float mu = (rs[0]+rs[1]+rs[2]+rs[3])*(1.f/256.f);
  float msq = (rq[0]+rq[1]+rq[2]+rq[3])*(1.f/256.f);
  float var = msq - mu*mu;
  t1[c] = (v-mu)*rsqrtf(var + 1e-5f)*pg[c] + pb[c];
  __syncthreads();
  float a = 0.f;
  for (int k=0;k<256;k++) a += t1[k]*wo[(size_t)k*256 + c];
  float u1 = wsum64(a), u2 = wsum64(a*a);
  if (ln == 0){ rs[wv]=u1; rq[wv]=u2; }
  __syncthreads();
  mu = (rs[0]+rs[1]+rs[2]+rs[3])*(1.f/256.f);
  msq = (rq[0]+rq[1]+rq[2]+rq[3])*(1.f/256.f);
  var = msq - mu*mu;
  t3[c] = (a-mu)*rsqrtf(var + 1e-5f)*lg[c] + lb[c];
  __syncthreads();
  if (c < 128){
    float s = fcb[c];
    for (int k=0;k<256;k++) s += t3[k]*fcw[(size_t)k*128 + c];
    t4[c] = s;
  }
  __syncthreads();
  if (c < 64){
    float s = fc2b[c];
    for (int k=0;k<128;k++) s += t4[k]*fc2w[(size_t)k*64 + c];
    t5[c] = s;
  }
  __syncthreads();
  if (c < 64){
    float p = t5[c]*fc3w[c];
    p = wsum64(p);
    if (c == 0) outp[row] = p + fc3b[0];
  }
}

extern "C" void kernel_launch(void* const* d_in, const int* in_sizes, int n_in,
                              void* d_out, int out_size, void* d_ws, size_t ws_size,
                              hipStream_t stream){
  (void)in_sizes; (void)n_in; (void)out_size; (void)ws_size;
  const float* x       = (const float*)d_in[0];
  const float* s11_w   = (const float*)d_in[1];
  const float* s11_b   = (const float*)d_in[2];
  const float* bn11    = (const float*)d_in[3];
  const float* s12_w   = (const float*)d_in[4];
  const float* s12_b   = (const float*)d_in[5];
  const float* bn12    = (const float*)d_in[6];
  const float* s21_w   = (const float*)d_in[7];
  const float* s21_b   = (const float*)d_in[8];
  const float* bn21    = (const float*)d_in[9];
  const float* s22_w   = (const float*)d_in[10];
  const float* s22_b   = (const float*)d_in[11];
  const float* bn22    = (const float*)d_in[12];
  const float* s3_w    = (const float*)d_in[13];
  const float* s3_b    = (const float*)d_in[14];
  const float* bn3     = (const float*)d_in[15];
  const float* c1_w    = (const float*)d_in[16];
  const float* c1_b    = (const float*)d_in[17];
  const float* cb_w    = (const float*)d_in[18];
  const float* cb_b    = (const float*)d_in[19];
  const float* ln_g    = (const float*)d_in[20];
  const float* ln_b    = (const float*)d_in[21];
  const float* wq      = (const float*)d_in[22];
  const float* wk      = (const float*)d_in[23];
  const float* wv      = (const float*)d_in[24];
  const float* wo      = (const float*)d_in[25];
  const float* lr_w    = (const float*)d_in[26];
  const float* lr_b    = (const float*)d_in[27];
  const float* tib     = (const float*)d_in[28];
  const float* tlnw    = (const float*)d_in[29];
  const float* tlnb    = (const float*)d_in[30];
  const float* W1      = (const float*)d_in[31];
  const float* B1      = (const float*)d_in[32];
  const float* W2      = (const float*)d_in[33];
  const float* B2      = (const float*)d_in[34];
  const float* post_g  = (const float*)d_in[35];
  const float* post_b  = (const float*)d_in[36];
  const float* fc_w    = (const float*)d_in[37];
  const float* fc_b    = (const float*)d_in[38];
  const float* fc2_w   = (const float*)d_in[39];
  const float* fc2_b   = (const float*)d_in[40];
  const float* fc3_w   = (const float*)d_in[41];
  const float* fc3_b   = (const float*)d_in[42];

  float* ws = (float*)d_ws;
  float* xs   = ws;                       // 2359296
  float* xd   = ws + 2359296;             // 2359296
  float* p1   = ws + 4718592;             // 1179648
  float* p2   = ws + 5898240;             // 1179648
  float* sig  = ws + 7077888;             // 32768
  float* buf0 = ws + 7110656;             // 131072
  float* buf1 = ws + 7241728;             // 131072
  float* accb = ws + 7372800;             // 131072
  float* hid  = ws + 7503872;             // 131072
  float* xqb  = ws + 7634944;             // 131072
  float* xkb  = ws + 7766016;             // 131072
  float* xvb  = ws + 7897088;             // 131072
  float* eta  = ws + 8028160;             // 2048
  float* hid2 = ws + 8030208;             // 131072

  k_s11<<<1536, 192, 0, stream>>>(x, s11_w, s11_b, bn11, xs);
  k_s12<<<1536, 192, 0, stream>>>(x, s12_w, s12_b, bn12, xd);
  k_s2x<<<512, 256, 0, stream>>>(xs, xd, s21_w, s21_b, bn21, p1);
  k_s2x<<<512, 256, 0, stream>>>(xd, xd, s22_w, s22_b, bn22, p2);
  k_s3<<<512, 256, 0, stream>>>(p1, p2, s3_w, s3_b, bn3, sig);
  k_c1<<<512, 256, 0, stream>>>(sig, c1_w, c1_b, buf0);
  {
    float* cin = buf0; float* cout = buf1;
    for (int l=0; l<8; l++){
      int mode = (l == 1) ? 1 : ((l & 1) ? 2 : 0);
      k_conv1d<<<256, 256, 0, stream>>>(cin, cb_w + (size_t)l*196608,
                                        cb_b + l*256, cout, accb, mode);
      float* tmp = cin; cin = cout; cout = tmp;
    }
  }
  k_ln_tr<<<512, 256, 0, stream>>>(accb, ln_g, ln_b, hid);
  k_proj<<<1536, 256, 0, stream>>>(hid, wq, wk, wv, xqb, xkb, xvb);
  k_eta<<<8, 256, 0, stream>>>(hid, lr_w, lr_b, eta);
  k_ttt<<<8, 256, 0, stream>>>(xqb, xkb, xvb, eta, tib, tlnw, tlnb,
                               W1, B1, W2, B2, hid2);
  k_head<<<512, 256, 0, stream>>>(hid2, post_g, post_b, wo, ln_g, ln_b,
                                  fc_w, fc_b, fc2_w, fc2_b, fc3_w, fc3_b,
                                  (float*)d_out);
}

// Round 7
// 1734.919 us; speedup vs baseline: 2.2569x; 1.0906x over previous
//
#include <hip/hip_runtime.h>
#include <hip/hip_bf16.h>
#include <math.h>

#define DEV __device__ __forceinline__

DEV float wsum64(float v){
  #pragma unroll
  for (int off = 32; off; off >>= 1) v += __shfl_xor(v, off, 64);
  return v;
}
DEV float geluf(float x){
  return 0.5f*x*(1.f + tanhf(0.7978845608028654f*(x + 0.044715f*x*x*x)));
}
DEV float gelu_bwdf(float x){
  float x2 = x*x;
  float t = tanhf(0.79788456f*x*(1.f + 0.044715f*x2));
  return 0.5f*x*((1.f - t*t)*(0.79788456f + 0.1070322243f*x2)) + 0.5f*(1.f + t);
}
DEV float sigmf(float x){ return 1.f/(1.f + expf(-x)); }

// ---------------------------------------------------------------------------
// Stem s11: x[512,3,96,96] -> conv7x7 s2 p3 -> BN -> ReLU -> pool2 -> xs[512,8,24,24]
__global__ __launch_bounds__(192) void k_s11(const float* __restrict__ x,
    const float* __restrict__ w, const float* __restrict__ bias,
    const float* __restrict__ bn, float* __restrict__ xs){
  __shared__ float st[3*37*2*53];   // 11766 floats
  __shared__ float wl[49*3*8];      // 1176
  int bx = blockIdx.x;
  int bd = bx / 3, g = bx - bd*3;
  int t = threadIdx.x;
  for (int e = t; e < 1176; e += 192){
    int tap = e / 24, r = e - tap*24, ci = r >> 3, c = r & 7;
    wl[e] = w[(c*3 + ci)*49 + tap];
  }
  const float* xb = x + (size_t)bd*3*9216;
  for (int e = t; e < 3*37*102; e += 192){
    int ci = e / 3774, r2 = e - ci*3774;
    int ihl = r2 / 102, pi = r2 - ihl*102;
    int ih = ihl + 32*g - 3, iw = pi - 3;
    float v = 0.f;
    if (ih>=0 && ih<96 && iw>=0 && iw<96) v = xb[(size_t)ci*9216 + ih*96 + iw];
    st[((ci*37 + ihl)*2 + (pi&1))*53 + (pi>>1)] = v;
  }
  __syncthreads();
  int pr = t / 24, pc = t - pr*24;
  float a00[8], a01[8], a10[8], a11[8];
  #pragma unroll
  for (int c=0;c<8;c++){ a00[c]=0.f; a01[c]=0.f; a10[c]=0.f; a11[c]=0.f; }
  for (int ci=0; ci<3; ci++){
    for (int kh=0; kh<7; kh++){
      int rb0 = (ci*37 + 4*pr + kh)*106 + 2*pc;
      int rb1 = rb0 + 212;
      #pragma unroll
      for (int kw=0; kw<7; kw++){
        int off = (kw&1)*53 + (kw>>1);
        float v00 = st[rb0+off], v01 = st[rb0+off+1];
        float v10 = st[rb1+off], v11 = st[rb1+off+1];
        const float4* wp = (const float4*)&wl[((kh*7+kw)*3 + ci)*8];
        float wv[8];
        *(float4*)&wv[0] = wp[0]; *(float4*)&wv[4] = wp[1];
        #pragma unroll
        for (int c=0;c<8;c++){
          a00[c] += v00*wv[c]; a01[c] += v01*wv[c];
          a10[c] += v10*wv[c]; a11[c] += v11*wv[c];
        }
      }
    }
  }
  int pos = (g*8 + pr)*24 + pc;
  #pragma unroll
  for (int c=0;c<8;c++){
    float gg=bn[c], be=bn[8+c], m=bn[16+c], vv=bn[24+c];
    float s = gg*rsqrtf(vv + 1e-5f);
    float bi = bias[c];
    float mx = 0.f;
    mx = fmaxf(mx, (a00[c]+bi-m)*s+be);
    mx = fmaxf(mx, (a01[c]+bi-m)*s+be);
    mx = fmaxf(mx, (a10[c]+bi-m)*s+be);
    mx = fmaxf(mx, (a11[c]+bi-m)*s+be);
    xs[((size_t)bd*8 + c)*576 + pos] = mx;
  }
}

// Stem s12: same structure on frame-diffs (4 groups of 3 channels, diff at staging).
__global__ __launch_bounds__(192) void k_s12(const float* __restrict__ x,
    const float* __restrict__ w, const float* __restrict__ bias,
    const float* __restrict__ bn, float* __restrict__ xd){
  __shared__ float st[3*37*2*53];
  __shared__ float wl[49*12*8];     // 4704
  int bx = blockIdx.x;
  int bd = bx / 3, g = bx - bd*3;
  int b = bd >> 8, dd = bd & 255;
  int t = threadIdx.x;
  for (int e = t; e < 4704; e += 192){
    int tap = e / 96, r = e - tap*96, ci = r >> 3, c = r & 7;
    wl[e] = w[(c*12 + ci)*49 + tap];
  }
  int fa[4], fb[4];
  fa[0] = dd>=2 ? dd-1 : 0;     fb[0] = dd>=2 ? dd-2 : 0;
  fa[1] = dd;                   fb[1] = dd>=1 ? dd-1 : 0;
  fa[2] = dd<=254 ? dd+1 : 255; fb[2] = dd;
  fa[3] = dd<=253 ? dd+2 : 255; fb[3] = dd<=254 ? dd+1 : 255;
  int pr = t / 24, pc = t - pr*24;
  float a00[8], a01[8], a10[8], a11[8];
  #pragma unroll
  for (int c=0;c<8;c++){ a00[c]=0.f; a01[c]=0.f; a10[c]=0.f; a11[c]=0.f; }
  for (int g4=0; g4<4; g4++){
    if (fa[g4] == fb[g4]) continue;   // zero diff, uniform per block
    __syncthreads();
    const float* xa = x + ((size_t)(b*256 + fa[g4]))*3*9216;
    const float* xbp= x + ((size_t)(b*256 + fb[g4]))*3*9216;
    for (int e = t; e < 3*37*102; e += 192){
      int ci = e / 3774, r2 = e - ci*3774;
      int ihl = r2 / 102, pi = r2 - ihl*102;
      int ih = ihl + 32*g - 3, iw = pi - 3;
      float v = 0.f;
      if (ih>=0 && ih<96 && iw>=0 && iw<96){
        size_t off = (size_t)ci*9216 + ih*96 + iw;
        v = xa[off] - xbp[off];
      }
      st[((ci*37 + ihl)*2 + (pi&1))*53 + (pi>>1)] = v;
    }
    __syncthreads();
    for (int ci=0; ci<3; ci++){
      int gch = g4*3 + ci;
      for (int kh=0; kh<7; kh++){
        int rb0 = (ci*37 + 4*pr + kh)*106 + 2*pc;
        int rb1 = rb0 + 212;
        #pragma unroll
        for (int kw=0; kw<7; kw++){
          int off = (kw&1)*53 + (kw>>1);
          float v00 = st[rb0+off], v01 = st[rb0+off+1];
          float v10 = st[rb1+off], v11 = st[rb1+off+1];
          const float4* wp = (const float4*)&wl[((kh*7+kw)*12 + gch)*8];
          float wv[8];
          *(float4*)&wv[0] = wp[0]; *(float4*)&wv[4] = wp[1];
          #pragma unroll
          for (int c=0;c<8;c++){
            a00[c] += v00*wv[c]; a01[c] += v01*wv[c];
            a10[c] += v10*wv[c]; a11[c] += v11*wv[c];
          }
        }
      }
    }
  }
  int pos = (g*8 + pr)*24 + pc;
  #pragma unroll
  for (int c=0;c<8;c++){
    float gg=bn[c], be=bn[8+c], m=bn[16+c], vv=bn[24+c];
    float s = gg*rsqrtf(vv + 1e-5f);
    float bi = bias[c];
    float mx = 0.f;
    mx = fmaxf(mx, (a00[c]+bi-m)*s+be);
    mx = fmaxf(mx, (a01[c]+bi-m)*s+be);
    mx = fmaxf(mx, (a10[c]+bi-m)*s+be);
    mx = fmaxf(mx, (a11[c]+bi-m)*s+be);
    xd[((size_t)bd*8 + c)*576 + pos] = mx;
  }
}

// s21/s22: in = 0.5*(A+B) [512,8,24,24] -> conv7x7 s1 p3 -> BN relu pool -> [512,16,12,12]
__global__ __launch_bounds__(256) void k_s2x(const float* __restrict__ inA,
    const float* __restrict__ inB, const float* __restrict__ w,
    const float* __restrict__ bias, const float* __restrict__ bn,
    float* __restrict__ outp){
  __shared__ float st[8*30*33];     // 7920
  __shared__ float wl[49*8*16];     // 6272
  int bd = blockIdx.x;
  int t = threadIdx.x;
  for (int e = t; e < 6272; e += 256){
    int tap = e >> 7, r = e & 127, ci = r >> 4, c = r & 15;
    wl[e] = w[(c*8 + ci)*49 + tap];
  }
  const float* pa = inA + (size_t)bd*8*576;
  const float* pb = inB + (size_t)bd*8*576;
  for (int e = t; e < 7920; e += 256){
    int ci = e / 990, r2 = e - ci*990;
    int r = r2 / 33, cc = r2 - r*33;
    int ih = r - 3, iw = cc - 3;
    float v = 0.f;
    if (ih>=0 && ih<24 && iw>=0 && iw<24){
      int off = ci*576 + ih*24 + iw;
      v = 0.5f*(pa[off] + pb[off]);
    }
    st[(ci*30 + r)*33 + cc] = v;
  }
  __syncthreads();
  if (t < 144){
    int pr = t / 12, pc = t - pr*12;
    float a00[16], a01[16], a10[16], a11[16];
    #pragma unroll
    for (int c=0;c<16;c++){ a00[c]=0.f; a01[c]=0.f; a10[c]=0.f; a11[c]=0.f; }
    for (int ci=0; ci<8; ci++){
      for (int kh=0; kh<7; kh++){
        int rb = (ci*30 + 2*pr + kh)*33 + 2*pc;
        #pragma unroll
        for (int kw=0; kw<7; kw++){
          float v00 = st[rb+kw],    v01 = st[rb+kw+1];
          float v10 = st[rb+33+kw], v11 = st[rb+34+kw];
          const float4* wp = (const float4*)&wl[((kh*7+kw)*8 + ci)*16];
          float wv[16];
          *(float4*)&wv[0]  = wp[0]; *(float4*)&wv[4]  = wp[1];
          *(float4*)&wv[8]  = wp[2]; *(float4*)&wv[12] = wp[3];
          #pragma unroll
          for (int c=0;c<16;c++){
            a00[c] += v00*wv[c]; a01[c] += v01*wv[c];
            a10[c] += v10*wv[c]; a11[c] += v11*wv[c];
          }
        }
      }
    }
    #pragma unroll
    for (int c=0;c<16;c++){
      float gg=bn[c], be=bn[16+c], m=bn[32+c], vv=bn[48+c];
      float s = gg*rsqrtf(vv + 1e-5f);
      float bi = bias[c];
      float mx = 0.f;
      mx = fmaxf(mx, (a00[c]+bi-m)*s+be);
      mx = fmaxf(mx, (a01[c]+bi-m)*s+be);
      mx = fmaxf(mx, (a10[c]+bi-m)*s+be);
      mx = fmaxf(mx, (a11[c]+bi-m)*s+be);
      outp[((size_t)bd*16 + c)*144 + pr*12 + pc] = mx;
    }
  }
}

// s3 conv3x3 p1 + BN + attention-mask pooled signal. block per bd. -> sig[512,64]
__global__ __launch_bounds__(256) void k_s3(const float* __restrict__ p1,
    const float* __restrict__ p2, const float* __restrict__ w,
    const float* __restrict__ bias, const float* __restrict__ bn,
    float* __restrict__ sig){
  __shared__ float ins[16*14*14];
  __shared__ float wT[144*64];
  __shared__ float redS[64*4];
  __shared__ float redF[64*4];
  int bd = blockIdx.x;
  int t = threadIdx.x;
  for (int i = t; i < 16*196; i += 256){
    int ci = i/196, r = i - ci*196, y = r/14, xx = r - y*14;
    float v = 0.f;
    if (y>=1 && y<=12 && xx>=1 && xx<=12){
      size_t idx = ((size_t)bd*16 + ci)*144 + (y-1)*12 + (xx-1);
      v = 0.5f*(p1[idx] + p2[idx]);
    }
    ins[i] = v;
  }
  for (int i = t; i < 9216; i += 256){
    int c = i & 63, k = i >> 6;
    wT[i] = w[c*144 + k];
  }
  __syncthreads();
  int c = t & 63, pg = t >> 6;
  float acc[36];
  #pragma unroll
  for (int pp=0;pp<36;pp++) acc[pp]=0.f;
  for (int k=0; k<144; k++){
    int ci = k/9, kk = k - ci*9, kh = kk/3, kw = kk - kh*3;
    float wv = wT[k*64 + c];
    const float* ip = &ins[ci*196];
    #pragma unroll
    for (int pp=0;pp<36;pp++){
      int y = pg*3 + pp/12, xx = pp%12;
      acc[pp] += ip[(y+kh)*14 + (xx+kw)] * wv;
    }
  }
  float g=bn[c], be=bn[64+c], m=bn[128+c], vv=bn[192+c];
  float s = g*rsqrtf(vv + 1e-5f);
  float bi = bias[c];
  float sS = 0.f, sF = 0.f;
  #pragma unroll
  for (int pp=0;pp<36;pp++){
    float f = (acc[pp] + bi - m)*s + be;
    float sg = sigmf(f);
    sS += sg; sF += f*sg;
  }
  redS[c*4+pg] = sS; redF[c*4+pg] = sF;
  __syncthreads();
  if (t < 64){
    float S = redS[t*4]+redS[t*4+1]+redS[t*4+2]+redS[t*4+3];
    float F = redF[t*4]+redF[t*4+1]+redF[t*4+2]+redF[t*4+3];
    sig[(size_t)bd*64 + t] = 0.5f*F/S;
  }
}

// c1 1x1 conv: sig[b,t,64] -> h[b,256,256] (channel-major). block=(b,o). grid 512.
__global__ __launch_bounds__(256) void k_c1(const float* __restrict__ sig,
    const float* __restrict__ w, const float* __restrict__ bias,
    float* __restrict__ h){
  int b = blockIdx.x >> 8, o = blockIdx.x & 255, tt = threadIdx.x;
  __shared__ float wl[64];
  if (tt < 64) wl[tt] = w[o*64 + tt];
  __syncthreads();
  const float4* sp = (const float4*)(sig + ((size_t)(b*256 + tt))*64);
  const float4* wp = (const float4*)wl;
  float a = bias[o];
  #pragma unroll
  for (int i=0;i<16;i++){
    float4 s4 = sp[i]; float4 w4 = wp[i];
    a += s4.x*w4.x + s4.y*w4.y + s4.z*w4.z + s4.w*w4.w;
  }
  h[((size_t)b*256 + o)*256 + tt] = fmaxf(a, 0.f);
}

// conv1d 256->256 k3 p1 + relu. mode: 0=none 1=acc:=out 2=acc+=out. grid 256.
__global__ __launch_bounds__(256) void k_conv1d(const float* __restrict__ hin,
    const float* __restrict__ w, const float* __restrict__ bias,
    float* __restrict__ hout, float* __restrict__ accb, int mode){
  __shared__ float ins[256*34];
  __shared__ float ws[16*256*4];   // padded stride-4 taps
  int bx = blockIdx.x;
  int b = bx >> 7;
  int rem = bx & 127;
  int og = rem >> 3;
  int tg = rem & 7;
  int tid = threadIdx.x;
  int t0 = tg*32;
  for (int idx = tid; idx < 256*34; idx += 256){
    int ii = idx/34, jj = idx - ii*34;
    int tglob = t0 - 1 + jj;
    float v = 0.f;
    if (tglob >= 0 && tglob < 256) v = hin[((size_t)b*256 + ii)*256 + tglob];
    ins[idx] = v;
  }
  for (int idx = tid; idx < 12288; idx += 256){
    int q = idx/3;
    ws[q*4 + (idx - q*3)] = w[(size_t)og*12288 + idx];
  }
  __syncthreads();
  int ol = tid >> 5, tl = tid & 31;
  int o1 = og*16 + ol, o2 = o1 + 8;
  float a1 = bias[o1], a2 = bias[o2];
  const float4* w1q = (const float4*)(ws + (size_t)ol*1024);
  const float4* w2q = (const float4*)(ws + (size_t)(ol+8)*1024);
  for (int i=0;i<256;i++){
    float v0 = ins[i*34 + tl];
    float v1 = ins[i*34 + tl + 1];
    float v2 = ins[i*34 + tl + 2];
    float4 wa = w1q[i];
    float4 wb = w2q[i];
    a1 += wa.x*v0 + wa.y*v1 + wa.z*v2;
    a2 += wb.x*v0 + wb.y*v1 + wb.z*v2;
  }
  a1 = fmaxf(a1, 0.f); a2 = fmaxf(a2, 0.f);
  size_t i1 = ((size_t)b*256 + o1)*256 + t0 + tl;
  size_t i2 = ((size_t)b*256 + o2)*256 + t0 + tl;
  hout[i1] = a1; hout[i2] = a2;
  if (mode == 1){ accb[i1] = a1; accb[i2] = a2; }
  else if (mode == 2){ accb[i1] += a1; accb[i2] += a2; }
}

// acc[b,c,t] -> transpose + LN(ln_g,ln_b) -> hid[(b t),c]. grid 512.
__global__ __launch_bounds__(256) void k_ln_tr(const float* __restrict__ acc,
    const float* __restrict__ g, const float* __restrict__ be,
    float* __restrict__ hid){
  int b = blockIdx.x >> 8, tt = blockIdx.x & 255, c = threadIdx.x;
  __shared__ float rs[4];
  __shared__ float rq[4];
  float v = acc[((size_t)b*256 + c)*256 + tt];
  float s1 = wsum64(v), s2 = wsum64(v*v);
  int wv = c >> 6, ln = c & 63;
  if (ln == 0){ rs[wv]=s1; rq[wv]=s2; }
  __syncthreads();
  float mu = (rs[0]+rs[1]+rs[2]+rs[3])*(1.f/256.f);
  float msq = (rq[0]+rq[1]+rq[2]+rq[3])*(1.f/256.f);
  float var = msq - mu*mu;
  hid[(size_t)blockIdx.x*256 + c] = (v-mu)*rsqrtf(var + 1e-5f)*g[c] + be[c];
}

// projections hid @ {wq,wk,wv}. grid 1536.
__global__ __launch_bounds__(256) void k_proj(const float* __restrict__ hid,
    const float* __restrict__ wq, const float* __restrict__ wk,
    const float* __restrict__ wv, float* __restrict__ xq,
    float* __restrict__ xk, float* __restrict__ xv){
  int m = blockIdx.x >> 9, row = blockIdx.x & 511, c = threadIdx.x;
  const float* W = (m==0) ? wq : ((m==1) ? wk : wv);
  float* O = (m==0) ? xq : ((m==1) ? xk : xv);
  __shared__ float hrow[256];
  hrow[c] = hid[(size_t)row*256 + c];
  __syncthreads();
  float a = 0.f;
  for (int k=0;k<256;k++) a += hrow[k]*W[(size_t)k*256 + c];
  O[(size_t)row*256 + c] = a;
}

// eta_lr (scaled): 0.1*sigmoid(hid.lr_w + lr_b)/64. grid 8 (b*4+h).
__global__ __launch_bounds__(256) void k_eta(const float* __restrict__ hid,
    const float* __restrict__ lrw, const float* __restrict__ lrb,
    float* __restrict__ etalr){
  int b = blockIdx.x >> 2, h = blockIdx.x & 3, l = threadIdx.x;
  const float* hp = hid + ((size_t)(b*256 + l))*256;
  float a = lrb[h];
  for (int k=0;k<256;k++) a += hp[k]*lrw[h*256 + k];
  etalr[(size_t)blockIdx.x*256 + l] = 0.1f*sigmf(a)*(1.f/64.f);
}

// TTT-MLP scan, 512 threads (2 waves/SIMD for latency hiding). One block/(b,h).
// Thread (i2=tid>>8, j=tid&255) owns minibatch rows {i2, i2+2}.
// Packed activation arrays use slot order (row0,row2,row1,row3) so half i2
// reads/writes a contiguous float2 at [idx*4 + i2*2]. pslot(r)=(r&1)*2+(r>>1).
__global__ __launch_bounds__(512) void k_ttt(
    const float* __restrict__ xq, const float* __restrict__ xk,
    const float* __restrict__ xv, const float* __restrict__ etalr,
    const float* __restrict__ tib, const float* __restrict__ lnw,
    const float* __restrict__ lnb, const float* __restrict__ W1g,
    const float* __restrict__ B1g, const float* __restrict__ W2g,
    const float* __restrict__ B2g, float* __restrict__ out){
  __shared__ float W1s[64*256];                 // [d][j]
  __shared__ float W2L[256*65];                 // [r][c] pitch 65
  __shared__ __align__(16) float k_pk[256];     // [d=64][slot4]
  __shared__ __align__(16) float q_pk[256];
  __shared__ __align__(16) float v_pk[256];
  __shared__ __align__(16) float x2_pk[1024];   // [j=256][slot4]
  __shared__ __align__(16) float x2b_pk[1024];
  __shared__ __align__(16) float gz1_pk[1024];
  __shared__ __align__(16) float gz2_pk[256];   // [cl=64][slot4]
  __shared__ float pzs[4*576];                  // [row][cl*9+seg]
  __shared__ float a2w[64];
  __shared__ float coefs[16];                   // row-indexed [i*4+r]
  __shared__ float coef2s[16];
  __shared__ float els[4];
  __shared__ float toks_s[4];

  int b = blockIdx.x >> 2, h = blockIdx.x & 3;
  int tid = threadIdx.x;
  int j = tid & 255;
  int i2 = tid >> 8;
  int iw = j >> 6, cl = j & 63;
  int ps_iw = ((iw & 1) << 1) | (iw >> 1);      // pslot(iw)

  const float* W1b = W1g + (size_t)h*16384;
  const float* W2b = W2g + (size_t)h*16384;
  for (int i = tid; i < 16384; i += 512) W1s[i] = W1b[i];
  for (int i = tid; i < 16384; i += 512){
    int r = i >> 6, c = i & 63;
    W2L[r*65 + c] = W2b[i];
  }
  float b1r = B1g[h*256 + j];
  float b2r = B2g[h*64 + cl];
  float gr = lnw[h*64 + cl], br = lnb[h*64 + cl];
  if (tid < 4) toks_s[tid] = fmaxf(1.f/(float)(tid+1) + tib[tid], 0.f);
  __syncthreads();
  float tok3 = toks_s[3];
  float tik = toks_s[iw];

  const float* xqp = xq + (size_t)b*65536 + h*64;
  const float* xkp = xk + (size_t)b*65536 + h*64;
  const float* xvp = xv + (size_t)b*65536 + h*64;
  const float* ep  = etalr + (size_t)(b*4 + h)*256;

  float qv=0.f, kv=0.f, vv=0.f, elv=0.f;
  if (i2 == 0){ qv = xqp[(size_t)iw*256 + cl]; kv = xkp[(size_t)iw*256 + cl]; }
  else        { vv = xvp[(size_t)iw*256 + cl]; }
  if (tid < 4) elv = ep[tid];

  for (int n=0; n<64; n++){
    // --- stage ---
    if (i2 == 0){ k_pk[cl*4 + ps_iw] = kv; q_pk[cl*4 + ps_iw] = qv; }
    else        { v_pk[cl*4 + ps_iw] = vv; }
    if (tid < 4) els[tid] = elv;
    __syncthreads();                              // A
    // --- A1 (half0 waves; wave iw = row iw) ---
    if (i2 == 0){
      float4 k4a = *(const float4*)&k_pk[cl*4];   // slots = rows 0,2,1,3
      float a0 = wsum64(qv*k4a.x);
      float a1 = wsum64(qv*k4a.y);
      float a2 = wsum64(qv*k4a.z);
      float a3 = wsum64(qv*k4a.w);
      if (cl == 0){
        coefs[iw*4+0] = tik*els[0]*(a0+1.f);
        coefs[iw*4+2] = (iw>=2) ? tik*els[2]*(a1+1.f) : 0.f;
        coefs[iw*4+1] = (iw>=1) ? tik*els[1]*(a2+1.f) : 0.f;
        coefs[iw*4+3] = (iw>=3) ? tik*els[3]*(a3+1.f) : 0.f;
      }
    }
    // --- Z1 rows (i2, i2+2): full d-range ---
    float z10=b1r, z11=b1r, qw0=b1r, qw1=b1r;
    #pragma unroll 8
    for (int d=0; d<64; d++){
      float2 k2 = *(const float2*)&k_pk[d*4 + i2*2];
      float2 q2 = *(const float2*)&q_pk[d*4 + i2*2];
      float w = W1s[d*256 + j];
      z10 += k2.x*w; z11 += k2.y*w; qw0 += q2.x*w; qw1 += q2.y*w;
    }
    float x2o0 = geluf(z10), x2o1 = geluf(z11);
    { float2 t; t.x=x2o0; t.y=x2o1; *(float2*)&x2_pk[j*4 + i2*2] = t; }
    __syncthreads();                              // B
    // --- prefetch next step ---
    float qn=0.f, kn=0.f, vn=0.f, eln=0.f;
    if (n < 63){
      int l2 = (n+1)*4 + iw;
      if (i2 == 0){ qn = xqp[(size_t)l2*256 + cl]; kn = xkp[(size_t)l2*256 + cl]; }
      else        { vn = xvp[(size_t)l2*256 + cl]; }
      if (tid < 4) eln = ep[(n+1)*4 + tid];
    }
    // --- Z2 split-K: seg = iw*2+i2, 32 d's, all 4 rows via slots ---
    {
      int d0 = (iw*2 + i2)*32;
      int seg = iw*2 + i2;
      float p0=0.f,p1=0.f,p2=0.f,p3=0.f;
      #pragma unroll 8
      for (int dd=0; dd<32; dd++){
        float4 x4 = *(const float4*)&x2_pk[(d0+dd)*4];
        float w = W2L[(d0+dd)*65 + cl];
        p0 += x4.x*w; p1 += x4.y*w; p2 += x4.z*w; p3 += x4.w*w;
      }
      pzs[0*576 + cl*9 + seg] = p0;   // slot0 = row0
      pzs[2*576 + cl*9 + seg] = p1;   // slot1 = row2
      pzs[1*576 + cl*9 + seg] = p2;   // slot2 = row1
      pzs[3*576 + cl*9 + seg] = p3;   // slot3 = row3
    }
    __syncthreads();                              // C
    // --- fused LN-L2 backward (half0 wave iw = row iw) ---
    if (i2 == 0){
      float z2 = b2r;
      #pragma unroll
      for (int sg=0; sg<8; sg++) z2 += pzs[iw*576 + cl*9 + sg];
      float mu = wsum64(z2)*(1.f/64.f);
      float df = z2 - mu;
      float var = wsum64(df*df)*(1.f/64.f);
      float stdv = sqrtf(var + 1e-6f);
      float xhat = df/stdv;
      float tgt = v_pk[cl*4 + ps_iw] - kv;
      float gxh = (gr*xhat + br - tgt)*gr;
      float sg1 = wsum64(gxh);
      float sg2 = wsum64(gxh*xhat);
      float gz2 = (64.f*gxh - sg1 - xhat*sg2)*(1.f/(64.f*stdv));
      gz2_pk[cl*4 + ps_iw] = gz2;
    }
    __syncthreads();                              // D
    // --- gZ1 rows (i2, i2+2) ---
    float gd0=0.f, gd1=0.f;
    #pragma unroll 8
    for (int c=0; c<64; c++){
      float2 g2 = *(const float2*)&gz2_pk[c*4 + i2*2];
      float w = W2L[j*65 + c];
      gd0 += g2.x*w; gd1 += g2.y*w;
    }
    float gz1a = gd0*gelu_bwdf(z10);
    float gz1b = gd1*gelu_bwdf(z11);
    { float2 t; t.x=gz1a; t.y=gz1b; *(float2*)&gz1_pk[j*4 + i2*2] = t; }
    __syncthreads();                              // D2
    float4 gz14 = *(const float4*)&gz1_pk[j*4];   // slots 0,2,1,3
    // --- Z1b/X2b rows (i2, i2+2) ---
    int R0 = i2, R1 = i2 + 2;
    float zb0 = qw0 - (coefs[R0*4+0]*gz14.x + coefs[R0*4+2]*gz14.y
                     + coefs[R0*4+1]*gz14.z + coefs[R0*4+3]*gz14.w);
    float zb1 = qw1 - (coefs[R1*4+0]*gz14.x + coefs[R1*4+2]*gz14.y
                     + coefs[R1*4+1]*gz14.z + coefs[R1*4+3]*gz14.w);
    float xb0 = geluf(zb0), xb1 = geluf(zb1);
    { float2 t; t.x=xb0; t.y=xb1; *(float2*)&x2b_pk[j*4 + i2*2] = t; }
    // --- A2 masked products, split 4/6 across halves (x2_pk is stable) ---
    if (i2 == 0){
      float xo1 = x2_pk[j*4 + 2];                 // row1
      float s00 = wsum64(xb0*x2o0);               // (0,0)
      float s20 = wsum64(xb1*x2o0);               // (2,0)
      float s22 = wsum64(xb1*x2o1);               // (2,2)
      float s21 = wsum64(xb1*xo1);                // (2,1)
      if (cl == 0){
        a2w[iw*16+0]  = s00;
        a2w[iw*16+8]  = s20;
        a2w[iw*16+10] = s22;
        a2w[iw*16+9]  = s21;
      }
    } else {
      float2 xo02 = *(const float2*)&x2_pk[j*4];  // rows 0,2
      float s11 = wsum64(xb0*x2o0);               // (1,1)
      float s10 = wsum64(xb0*xo02.x);             // (1,0)
      float s31 = wsum64(xb1*x2o0);               // (3,1)
      float s33 = wsum64(xb1*x2o1);               // (3,3)
      float s30 = wsum64(xb1*xo02.x);             // (3,0)
      float s32 = wsum64(xb1*xo02.y);             // (3,2)
      if (cl == 0){
        a2w[iw*16+5]  = s11;
        a2w[iw*16+4]  = s10;
        a2w[iw*16+13] = s31;
        a2w[iw*16+15] = s33;
        a2w[iw*16+12] = s30;
        a2w[iw*16+14] = s32;
      }
    }
    __syncthreads();                              // E
    if (tid < 16){
      int ii = tid >> 2, rr = tid & 3;
      float s = a2w[tid] + a2w[16+tid] + a2w[32+tid] + a2w[48+tid];
      coef2s[tid] = (rr <= ii) ? toks_s[ii]*els[rr]*(s + 1.f) : 0.f;
    }
    // --- Z2b split-K ---
    {
      int d0 = (iw*2 + i2)*32;
      int seg = iw*2 + i2;
      float p0=0.f,p1=0.f,p2=0.f,p3=0.f;
      #pragma unroll 8
      for (int dd=0; dd<32; dd++){
        float4 x4 = *(const float4*)&x2b_pk[(d0+dd)*4];
        float w = W2L[(d0+dd)*65 + cl];
        p0 += x4.x*w; p1 += x4.y*w; p2 += x4.z*w; p3 += x4.w*w;
      }
      pzs[0*576 + cl*9 + seg] = p0;
      pzs[2*576 + cl*9 + seg] = p1;
      pzs[1*576 + cl*9 + seg] = p2;
      pzs[3*576 + cl*9 + seg] = p3;
    }
    __syncthreads();                              // F
    // --- ln_fwd + output + b2 update (half0) ---
    if (i2 == 0){
      float z2b = b2r;
      #pragma unroll
      for (int sg=0; sg<8; sg++) z2b += pzs[iw*576 + cl*9 + sg];
      float4 g4r = *(const float4*)&gz2_pk[cl*4];
      z2b -= coef2s[iw*4+0]*g4r.x + coef2s[iw*4+2]*g4r.y
           + coef2s[iw*4+1]*g4r.z + coef2s[iw*4+3]*g4r.w;
      float mu2 = wsum64(z2b)*(1.f/64.f);
      float df2 = z2b - mu2;
      float var2 = wsum64(df2*df2)*(1.f/64.f);
      float lnv = gr*df2*rsqrtf(var2 + 1e-6f) + br;
      out[((size_t)b*256 + n*4 + iw)*256 + h*64 + cl] = qv + lnv;
      float le0 = tok3*els[0], le1 = tok3*els[2], le2 = tok3*els[1], le3 = tok3*els[3];
      b2r -= le0*g4r.x + le1*g4r.y + le2*g4r.z + le3*g4r.w;
    }
    // --- state updates (both halves; split rows/cols by i2) ---
    float le_s0 = tok3*els[0], le_s1 = tok3*els[2], le_s2 = tok3*els[1], le_s3 = tok3*els[3];
    float lg0 = le_s0*gz14.x, lg1v = le_s1*gz14.y, lg2 = le_s2*gz14.z, lg3 = le_s3*gz14.w;
    {
      int d0 = i2*32;
      #pragma unroll 8
      for (int dd=0; dd<32; dd++){
        float4 k4 = *(const float4*)&k_pk[(d0+dd)*4];
        W1s[(d0+dd)*256 + j] -= lg0*k4.x + lg1v*k4.y + lg2*k4.z + lg3*k4.w;
      }
    }
    b1r -= lg0 + lg1v + lg2 + lg3;
    float4 xb4 = *(const float4*)&x2b_pk[j*4];    // slots
    float lx0 = le_s0*xb4.x, lx1 = le_s1*xb4.y, lx2 = le_s2*xb4.z, lx3 = le_s3*xb4.w;
    {
      int c0 = i2*32;
      #pragma unroll 8
      for (int cc=0; cc<32; cc++){
        float4 g4 = *(const float4*)&gz2_pk[(c0+cc)*4];
        W2L[j*65 + c0+cc] -= lx0*g4.x + lx1*g4.y + lx2*g4.z + lx3*g4.w;
      }
    }
    __syncthreads();                              // G
    qv = qn; kv = kn; vv = vn; elv = eln;
  }
}

// Fused head: LN(post) -> @wo -> LN(ln) -> fc1 -> fc2 -> fc3. grid 512 rows.
__global__ __launch_bounds__(256) void k_head(const float* __restrict__ hid2,
    const float* __restrict__ pg, const float* __restrict__ pb,
    const float* __restrict__ wo, const float* __restrict__ lg,
    const float* __restrict__ lb, const float* __restrict__ fcw,
    const float* __restrict__ fcb, const float* __restrict__ fc2w,
    const float* __restrict__ fc2b, const float* __restrict__ fc3w,
    const float* __restrict__ fc3b, float* __restrict__ outp){
  int row = blockIdx.x, c = threadIdx.x;
  __shared__ float t1[256];
  __shared__ float t3[256];
  __shared__ float t4[128];
  __shared__ float t5[64];
  __shared__ float rs[4];
  __shared__ float rq[4];
  int wv = c >> 6, ln = c & 63;
  float v = hid2[(size_t)row*256 + c];
  float s1 = wsum64(v), s2 = wsum64(v*v);
  if (ln == 0){ rs[wv]=s1; rq[wv]=s2; }
  __syncthreads();
  float mu = (rs[0]+rs[1]+rs[2]+rs[3])*(1.f/256.f);
  float msq = (rq[0]+rq[1]+rq[2]+rq[3])*(1.f/256.f);
  float var = msq - mu*mu;
  t1[c] = (v-mu)*rsqrtf(var + 1e-5f)*pg[c] + pb[c];
  __syncthreads();
  float a = 0.f;
  for (int k=0;k<256;k++) a += t1[k]*wo[(size_t)k*256 + c];
  float u1 = wsum64(a), u2 = wsum64(a*a);
  if (ln == 0){ rs[wv]=u1; rq[wv]=u2; }
  __syncthreads();
  mu = (rs[0]+rs[1]+rs[2]+rs[3])*(1.f/256.f);
  msq = (rq[0]+rq[1]+rq[2]+rq[3])*(1.f/256.f);
  var = msq - mu*mu;
  t3[c] = (a-mu)*rsqrtf(var + 1e-5f)*lg[c] + lb[c];
  __syncthreads();
  if (c < 128){
    float s = fcb[c];
    for (int k=0;k<256;k++) s += t3[k]*fcw[(size_t)k*128 + c];
    t4[c] = s;
  }
  __syncthreads();
  if (c < 64){
    float s = fc2b[c];
    for (int k=0;k<128;k++) s += t4[k]*fc2w[(size_t)k*64 + c];
    t5[c] = s;
  }
  __syncthreads();
  if (c < 64){
    float p = t5[c]*fc3w[c];
    p = wsum64(p);
    if (c == 0) outp[row] = p + fc3b[0];
  }
}

extern "C" void kernel_launch(void* const* d_in, const int* in_sizes, int n_in,
                              void* d_out, int out_size, void* d_ws, size_t ws_size,
                              hipStream_t stream){
  (void)in_sizes; (void)n_in; (void)out_size; (void)ws_size;
  const float* x       = (const float*)d_in[0];
  const float* s11_w   = (const float*)d_in[1];
  const float* s11_b   = (const float*)d_in[2];
  const float* bn11    = (const float*)d_in[3];
  const float* s12_w   = (const float*)d_in[4];
  const float* s12_b   = (const float*)d_in[5];
  const float* bn12    = (const float*)d_in[6];
  const float* s21_w   = (const float*)d_in[7];
  const float* s21_b   = (const float*)d_in[8];
  const float* bn21    = (const float*)d_in[9];
  const float* s22_w   = (const float*)d_in[10];
  const float* s22_b   = (const float*)d_in[11];
  const float* bn22    = (const float*)d_in[12];
  const float* s3_w    = (const float*)d_in[13];
  const float* s3_b    = (const float*)d_in[14];
  const float* bn3     = (const float*)d_in[15];
  const float* c1_w    = (const float*)d_in[16];
  const float* c1_b    = (const float*)d_in[17];
  const float* cb_w    = (const float*)d_in[18];
  const float* cb_b    = (const float*)d_in[19];
  const float* ln_g    = (const float*)d_in[20];
  const float* ln_b    = (const float*)d_in[21];
  const float* wq      = (const float*)d_in[22];
  const float* wk      = (const float*)d_in[23];
  const float* wv      = (const float*)d_in[24];
  const float* wo      = (const float*)d_in[25];
  const float* lr_w    = (const float*)d_in[26];
  const float* lr_b    = (const float*)d_in[27];
  const float* tib     = (const float*)d_in[28];
  const float* tlnw    = (const float*)d_in[29];
  const float* tlnb    = (const float*)d_in[30];
  const float* W1      = (const float*)d_in[31];
  const float* B1      = (const float*)d_in[32];
  const float* W2      = (const float*)d_in[33];
  const float* B2      = (const float*)d_in[34];
  const float* post_g  = (const float*)d_in[35];
  const float* post_b  = (const float*)d_in[36];
  const float* fc_w    = (const float*)d_in[37];
  const float* fc_b    = (const float*)d_in[38];
  const float* fc2_w   = (const float*)d_in[39];
  const float* fc2_b   = (const float*)d_in[40];
  const float* fc3_w   = (const float*)d_in[41];
  const float* fc3_b   = (const float*)d_in[42];

  float* ws = (float*)d_ws;
  float* xs   = ws;                       // 2359296
  float* xd   = ws + 2359296;             // 2359296
  float* p1   = ws + 4718592;             // 1179648
  float* p2   = ws + 5898240;             // 1179648
  float* sig  = ws + 7077888;             // 32768
  float* buf0 = ws + 7110656;             // 131072
  float* buf1 = ws + 7241728;             // 131072
  float* accb = ws + 7372800;             // 131072
  float* hid  = ws + 7503872;             // 131072
  float* xqb  = ws + 7634944;             // 131072
  float* xkb  = ws + 7766016;             // 131072
  float* xvb  = ws + 7897088;             // 131072
  float* eta  = ws + 8028160;             // 2048
  float* hid2 = ws + 8030208;             // 131072

  k_s11<<<1536, 192, 0, stream>>>(x, s11_w, s11_b, bn11, xs);
  k_s12<<<1536, 192, 0, stream>>>(x, s12_w, s12_b, bn12, xd);
  k_s2x<<<512, 256, 0, stream>>>(xs, xd, s21_w, s21_b, bn21, p1);
  k_s2x<<<512, 256, 0, stream>>>(xd, xd, s22_w, s22_b, bn22, p2);
  k_s3<<<512, 256, 0, stream>>>(p1, p2, s3_w, s3_b, bn3, sig);
  k_c1<<<512, 256, 0, stream>>>(sig, c1_w, c1_b, buf0);
  {
    float* cin = buf0; float* cout = buf1;
    for (int l=0; l<8; l++){
      int mode = (l == 1) ? 1 : ((l & 1) ? 2 : 0);
      k_conv1d<<<256, 256, 0, stream>>>(cin, cb_w + (size_t)l*196608,
                                        cb_b + l*256, cout, accb, mode);
      float* tmp = cin; cin = cout; cout = tmp;
    }
  }
  k_ln_tr<<<512, 256, 0, stream>>>(accb, ln_g, ln_b, hid);
  k_proj<<<1536, 256, 0, stream>>>(hid, wq, wk, wv, xqb, xkb, xvb);
  k_eta<<<8, 256, 0, stream>>>(hid, lr_w, lr_b, eta);
  k_ttt<<<8, 512, 0, stream>>>(xqb, xkb, xvb, eta, tib, tlnw, tlnb,
                               W1, B1, W2, B2, hid2);
  k_head<<<512, 256, 0, stream>>>(hid2, post_g, post_b, wo, ln_g, ln_b,
                                  fc_w, fc_b, fc2_w, fc2_b, fc3_w, fc3_b,
                                  (float*)d_out);
}